// Round 5
// baseline (938.621 us; speedup 1.0000x reference)
//
#include <hip/hip_runtime.h>
#include <hip/hip_bf16.h>
#include <math.h>

typedef unsigned short u16;
typedef __bf16 bf16x8 __attribute__((ext_vector_type(8)));
typedef float f32x4 __attribute__((ext_vector_type(4)));

__device__ __forceinline__ float b2f(u16 u) {
  union { unsigned int i; float f; } v; v.i = ((unsigned int)u) << 16; return v.f;
}
__device__ __forceinline__ u16 f2b(float f) {
  union { float f; unsigned int i; } v; v.f = f;
  unsigned int x = v.i;
  return (u16)((x + 0x7fffu + ((x >> 16) & 1u)) >> 16);
}
// dual-dtype scalar load: isf=1 -> f32, isf=0 -> bf16
__device__ __forceinline__ float ldx(const void* p, size_t i, int isf) {
  return isf ? ((const float*)p)[i] : b2f(((const u16*)p)[i]);
}

// ---------------- kernel 0: dtype detect (f32 vs bf16) ----------------
__global__ void k_detect(const void* __restrict__ query, int* __restrict__ flag) {
  int t = threadIdx.x;  // 64 threads
  float v = ((const float*)query)[t];
  int ok = (v == v && fabsf(v) < 100.f && fabsf(v) > 1e-4f) ? 1 : 0;
  unsigned long long m = __ballot(ok);
  if (t == 0) flag[0] = (__popcll(m) >= 32) ? 1 : 0;
}

// ---------------- kernel 1: W_in (512x512) -> bf16 WT[j][c], LDS-tiled ----------------
__global__ __launch_bounds__(256) void k_transpose(const void* __restrict__ Win,
                                                   u16* __restrict__ WT,
                                                   const int* __restrict__ flag) {
  int isf = flag[0];
  int t = threadIdx.x;
  int bx = blockIdx.x & 7, by = blockIdx.x >> 3;   // 8x8 tiles of 64x64
  int c0 = bx * 64, j0 = by * 64;
  __shared__ float tile[64][65];                    // +1 pad: conflict-free transpose
  #pragma unroll
  for (int k = 0; k < 16; k++) {
    int idx = t + 256 * k;
    int cl = idx >> 6, jl = idx & 63;
    tile[cl][jl] = ldx(Win, (size_t)(c0 + cl) * 512 + (j0 + jl), isf);
  }
  __syncthreads();
  #pragma unroll
  for (int k = 0; k < 16; k++) {
    int idx = t + 256 * k;
    int jl = idx >> 6, cl = idx & 63;
    WT[(size_t)(j0 + jl) * 512 + (c0 + cl)] = f2b(tile[cl][jl]);
  }
}

// ---------------- kernel 2: P1[j]=sum_c g_in[c]*Wv[c][j], P2[j]=sum_c be_in[c]*Wv[c][j] ----------------
__global__ __launch_bounds__(512) void k_prep2(const void* __restrict__ Wkv,
                                               const void* __restrict__ g_in,
                                               const void* __restrict__ be_in,
                                               float* __restrict__ P1, float* __restrict__ P2,
                                               const int* __restrict__ flag) {
  int isf = flag[0];
  int blk = blockIdx.x;            // 16 blocks x 32 j
  int t = threadIdx.x;
  int jj = t & 31, cg = t >> 5;    // 16 c-groups of 32
  int j = blk * 32 + jj;
  float p1 = 0.f, p2 = 0.f;
  for (int cc = 0; cc < 32; cc++) {
    int c = cg * 32 + cc;
    float wv = ldx(Wkv, (size_t)c * 1024 + 512 + j, isf);
    p1 += ldx(g_in, c, isf) * wv;
    p2 += ldx(be_in, c, isf) * wv;
  }
  __shared__ float red[1024];
  red[t * 2] = p1; red[t * 2 + 1] = p2;
  __syncthreads();
  if (t < 32) {
    float s1 = 0.f, s2 = 0.f;
    for (int g2 = 0; g2 < 16; g2++) { s1 += red[(g2 * 32 + t) * 2]; s2 += red[(g2 * 32 + t) * 2 + 1]; }
    P1[blk * 32 + t] = s1;
    P2[blk * 32 + t] = s2;
  }
}

// ---------------- kernel 3a: qr = LN(query) @ Wq + bq ----------------
__global__ __launch_bounds__(256) void k_qprep_a(
    const void* __restrict__ query, const void* __restrict__ Wq, const void* __restrict__ bq,
    const void* __restrict__ g_q, const void* __restrict__ be_q,
    float* __restrict__ qr_ws, const int* __restrict__ flag) {
  int isf = flag[0];
  int b = blockIdx.x, jq = blockIdx.y, t = threadIdx.x;
  __shared__ float qf[512];
  __shared__ float red[8];
  __shared__ float stats[2];

  float s = 0.f, ss = 0.f;
  for (int k = 0; k < 2; k++) {
    int c = t + 256 * k;
    float v = ldx(query, (size_t)b * 512 + c, isf);
    qf[c] = v; s += v; ss += v * v;
  }
  for (int off = 32; off; off >>= 1) { s += __shfl_xor(s, off); ss += __shfl_xor(ss, off); }
  int wid = t >> 6, lane = t & 63;
  if (lane == 0) { red[wid * 2] = s; red[wid * 2 + 1] = ss; }
  __syncthreads();
  if (t == 0) {
    float S = 0.f, SS = 0.f;
    for (int w = 0; w < 4; w++) { S += red[w * 2]; SS += red[w * 2 + 1]; }
    float mu = S / 512.f;
    float var = SS / 512.f - mu * mu;
    stats[0] = mu; stats[1] = rsqrtf(var + 1e-5f);
  }
  __syncthreads();
  float mu = stats[0], rstd = stats[1];
  for (int k = 0; k < 2; k++) {
    int c = t + 256 * k;
    qf[c] = (qf[c] - mu) * rstd * ldx(g_q, c, isf) + ldx(be_q, c, isf);
  }
  __syncthreads();
  int jl = t >> 1, half = t & 1;
  int j = jq * 128 + jl;
  const float* qh = qf + half * 256;
  float a0 = 0.f, a1 = 0.f, a2 = 0.f, a3 = 0.f;
  if (isf) {
    const float* wp = (const float*)Wq + (size_t)(half * 256) * 512 + j;
    #pragma unroll 2
    for (int cc = 0; cc < 256; cc += 4) {
      a0 += qh[cc]     * wp[(size_t)cc * 512];
      a1 += qh[cc + 1] * wp[(size_t)(cc + 1) * 512];
      a2 += qh[cc + 2] * wp[(size_t)(cc + 2) * 512];
      a3 += qh[cc + 3] * wp[(size_t)(cc + 3) * 512];
    }
  } else {
    const u16* wp = (const u16*)Wq + (size_t)(half * 256) * 512 + j;
    #pragma unroll 2
    for (int cc = 0; cc < 256; cc += 4) {
      a0 += qh[cc]     * b2f(wp[(size_t)cc * 512]);
      a1 += qh[cc + 1] * b2f(wp[(size_t)(cc + 1) * 512]);
      a2 += qh[cc + 2] * b2f(wp[(size_t)(cc + 2) * 512]);
      a3 += qh[cc + 3] * b2f(wp[(size_t)(cc + 3) * 512]);
    }
  }
  float acc = (a0 + a1) + (a2 + a3);
  acc += __shfl_xor(acc, 1);
  if (half == 0) qr_ws[(size_t)b * 512 + j] = acc + ldx(bq, j, isf);
}

// ---------------- kernel 3b: u -> guT (bf16 [b][16][512]), Gsum, S0 (=BeU + c0) ----------------
__global__ __launch_bounds__(256) void k_qprep_b(
    const float* __restrict__ qr_ws, const void* __restrict__ Wkv, const void* __restrict__ bkv,
    const void* __restrict__ g_in, const void* __restrict__ be_in,
    u16* __restrict__ guT, float* __restrict__ Gsum_g, float* __restrict__ S0_g,
    const int* __restrict__ flag) {
  int isf = flag[0];
  int b = blockIdx.x, cq = blockIdx.y, t = threadIdx.x;   // cq: 4 c-quarters of 128
  __shared__ float qrl[512];
  __shared__ float ul[128 * 8];
  qrl[t] = qr_ws[(size_t)b * 512 + t];
  qrl[t + 256] = qr_ws[(size_t)b * 512 + t + 256];
  __syncthreads();
  #pragma unroll
  for (int e4 = 0; e4 < 4; e4++) {
    int e = t + 256 * e4;
    int cl = e >> 3, n = e & 7;
    int c = cq * 128 + cl;
    const float* qp = qrl + n * 64;
    float acc = 0.f;
    if (isf) {
      const float* wp = (const float*)Wkv + (size_t)c * 1024 + n * 64;
      #pragma unroll 8
      for (int d = 0; d < 64; d++) acc += wp[d] * qp[d];
    } else {
      const u16* wp = (const u16*)Wkv + (size_t)c * 1024 + n * 64;
      #pragma unroll 8
      for (int d = 0; d < 64; d++) acc += b2f(wp[d]) * qp[d];
    }
    ul[cl * 8 + n] = acc;
  }
  __syncthreads();
  #pragma unroll
  for (int e4 = 0; e4 < 4; e4++) {
    int e = t + 256 * e4;
    int cl = e >> 3, n = e & 7;
    int c = cq * 128 + cl;
    guT[((size_t)b * 16 + n) * 512 + c] = f2b(ldx(g_in, c, isf) * ul[cl * 8 + n]);
    guT[((size_t)b * 16 + 8 + n) * 512 + c] = 0;
  }
  if (t < 64) {
    int n = t >> 3, seg = t & 7;
    float gs = 0.f, s0 = 0.f;
    for (int k = 0; k < 16; k++) {
      int cl = seg * 16 + k;
      int c = cq * 128 + cl;
      float uu = ul[cl * 8 + n];
      gs += ldx(g_in, c, isf) * uu;
      s0 += ldx(be_in, c, isf) * uu;
    }
    gs += __shfl_xor(gs, 1); s0 += __shfl_xor(s0, 1);
    gs += __shfl_xor(gs, 2); s0 += __shfl_xor(s0, 2);
    gs += __shfl_xor(gs, 4); s0 += __shfl_xor(s0, 4);
    if (seg == 0) {
      atomicAdd(Gsum_g + b * 8 + n, gs);
      atomicAdd(S0_g + b * 8 + n, s0);
    }
  }
  if (cq == 0 && t < 8) {
    float acc = 0.f;
    for (int d = 0; d < 64; d++) acc += ldx(bkv, t * 64 + d, isf) * qrl[t * 64 + d];
    atomicAdd(S0_g + b * 8 + t, acc);
  }
}

// ---------------- kernel 4: fused m-GEMM + relu + LN-stats + MFMA-scores + R accumulation ----------------
// v5 = v4 + T14 async A-prefetch: the next K-step's A global load issues right after
// the "staged ready" barrier, so its ~900cy HBM latency hides under the current step's
// ds_read+MFMA (and under the epilogue at tile boundaries). B (L2-hot WT) stays
// late-loaded. gfrags reloaded per tile (frees 8 VGPR) to keep VGPR<=128 (2 blocks/CU).
#define LDA 40
#define LDB 40
__global__ __launch_bounds__(512) void k_main(
    const void* __restrict__ mem, const u16* __restrict__ WT, const void* __restrict__ b_in,
    const void* __restrict__ ior, const u16* __restrict__ guT,
    const float* __restrict__ Gsum_g, const float* __restrict__ S0_g,
    float* __restrict__ R_g, float* __restrict__ A_g, float* __restrict__ M_g,
    const int* __restrict__ flag) {
  int isf = flag[0];
  int blk = blockIdx.x;           // 0..15 (4 row-tiles each)
  int b   = blockIdx.y;           // 0..31
  int t = threadIdx.x;
  int w = t >> 6, lane = t & 63;
  int l15 = lane & 15, q = lane >> 4;

  __shared__ __align__(16) char smem[68096];
  u16*   Ab      = (u16*)smem;
  u16*   Bb      = (u16*)(smem + 5120);
  float* rowred  = (float*)smem;
  float* mu_rstd = (float*)(smem + 65536);
  float* a_lds   = (float*)(smem + 66048);
  char*  ymine   = smem + w * 8192;

  float binv[4];
  #pragma unroll
  for (int j = 0; j < 4; j++) binv[j] = ldx(b_in, w * 64 + j * 16 + l15, isf);
  float Gs  = Gsum_g[b * 8 + (t & 7)];
  float S0v = S0_g[b * 8 + (t & 7)];

  float am_acc = 0.f, mm_acc = 0.f;

  // A-prefetch lane geometry
  int pr_f = (t * 4) >> 5, pc_f = (t * 4) & 31;   // f32 path: all 512 thr, float4
  int pr_b = t >> 2,       pc_b = (t & 3) * 8;    // bf16 path: t<256, uint4 (8 bf16)
  float4 pA_f;
  uint4  pA_b;
  {
    size_t mb0 = ((size_t)b * 4096 + blk * 4 * 64) * 512;
    if (isf) pA_f = *(const float4*)((const float*)mem + mb0 + (size_t)pr_f * 512 + pc_f);
    else if (t < 256) pA_b = *(const uint4*)((const u16*)mem + mb0 + (size_t)pr_b * 512 + pc_b);
  }

  for (int tile = 0; tile < 4; tile++) {
    int row0 = (blk * 4 + tile) * 64;

    f32x4 acc[4][4];
    #pragma unroll
    for (int i = 0; i < 4; i++)
      #pragma unroll
      for (int j = 0; j < 4; j++) { acc[i][j][0]=0.f; acc[i][j][1]=0.f; acc[i][j][2]=0.f; acc[i][j][3]=0.f; }

    for (int kk = 0; kk < 512; kk += 32) {
      __syncthreads();   // staging buffers free (prev reads / epilogue done)
      // B stage: issue loads first, then A write (independent), then B writes
      uint4 bv[4];
      #pragma unroll
      for (int s2 = 0; s2 < 4; s2++) {
        int e = t + 512 * s2;
        int j = e >> 2, ch = e & 3;
        bv[s2] = *(const uint4*)(WT + (size_t)j * 512 + kk + ch * 8);
      }
      if (isf) {         // A write from prefetched regs
        union { u16 h[4]; uint2 u; } pk;
        pk.h[0] = f2b(pA_f.x); pk.h[1] = f2b(pA_f.y); pk.h[2] = f2b(pA_f.z); pk.h[3] = f2b(pA_f.w);
        *(uint2*)(Ab + pr_f * LDA + pc_f) = pk.u;
      } else if (t < 256) {
        *(uint4*)(Ab + pr_b * LDA + pc_b) = pA_b;
      }
      #pragma unroll
      for (int s2 = 0; s2 < 4; s2++) {
        int e = t + 512 * s2;
        int j = e >> 2, ch = e & 3;
        *(uint4*)(Bb + j * LDB + ch * 8) = bv[s2];
      }
      __syncthreads();   // staged ready
      // issue NEXT A prefetch (next kk, or next tile's kk=0; clamped at the very end)
      {
        int nkk = kk + 32, ntile = tile;
        if (nkk == 512) { nkk = 0; ntile = (tile < 3) ? tile + 1 : 3; }
        size_t mbn = ((size_t)b * 4096 + (blk * 4 + ntile) * 64) * 512;
        if (isf) pA_f = *(const float4*)((const float*)mem + mbn + (size_t)pr_f * 512 + nkk + pc_f);
        else if (t < 256) pA_b = *(const uint4*)((const u16*)mem + mbn + (size_t)pr_b * 512 + nkk + pc_b);
      }
      bf16x8 aF[4], bF[4];
      #pragma unroll
      for (int i = 0; i < 4; i++)
        aF[i] = *(const bf16x8*)(Ab + (i * 16 + l15) * LDA + q * 8);
      #pragma unroll
      for (int j = 0; j < 4; j++)
        bF[j] = *(const bf16x8*)(Bb + (w * 64 + j * 16 + l15) * LDB + q * 8);
      #pragma unroll
      for (int i = 0; i < 4; i++)
        #pragma unroll
        for (int j = 0; j < 4; j++)
          acc[i][j] = __builtin_amdgcn_mfma_f32_16x16x32_bf16(aF[i], bF[j], acc[i][j], 0, 0, 0);
    }
    __syncthreads();   // staging buffers dead; epilogue overlays begin

    // bias + relu (acc stays PRE-LN y)
    #pragma unroll
    for (int i = 0; i < 4; i++)
      #pragma unroll
      for (int j = 0; j < 4; j++)
        #pragma unroll
        for (int r = 0; r < 4; r++) {
          float v = acc[i][j][r] + binv[j];
          acc[i][j][r] = v > 0.f ? v : 0.f;
        }
    // LN stats partials
    #pragma unroll
    for (int i = 0; i < 4; i++)
      #pragma unroll
      for (int r = 0; r < 4; r++) {
        float s  = acc[i][0][r] + acc[i][1][r] + acc[i][2][r] + acc[i][3][r];
        float ss = acc[i][0][r]*acc[i][0][r] + acc[i][1][r]*acc[i][1][r]
                 + acc[i][2][r]*acc[i][2][r] + acc[i][3][r]*acc[i][3][r];
        #pragma unroll
        for (int m = 1; m < 16; m <<= 1) { s += __shfl_xor(s, m); ss += __shfl_xor(ss, m); }
        if (l15 == 0) {
          int row = i * 16 + q * 4 + r;
          rowred[(w * 64 + row) * 2]     = s;
          rowred[(w * 64 + row) * 2 + 1] = ss;
        }
      }
    __syncthreads();
    if (t < 64) {
      float S = 0.f, SS = 0.f;
      for (int w2 = 0; w2 < 8; w2++) { S += rowred[(w2 * 64 + t) * 2]; SS += rowred[(w2 * 64 + t) * 2 + 1]; }
      float mu = S / 512.f;
      float var = SS / 512.f - mu * mu;
      mu_rstd[t * 2] = mu;
      mu_rstd[t * 2 + 1] = rsqrtf(var + 1e-5f);
    }
    __syncthreads();   // rowred consumed; y writes may overwrite [0,65536)

    // write this wave's y-slice [64][64] bf16, XOR-swizzled
    #pragma unroll
    for (int i = 0; i < 4; i++)
      #pragma unroll
      for (int j = 0; j < 4; j++)
        #pragma unroll
        for (int r = 0; r < 4; r++) {
          int row = i * 16 + q * 4 + r;
          int byo = (row * 128 + j * 32 + l15 * 2) ^ ((row & 7) << 4);
          *(u16*)(ymine + byo) = f2b(acc[i][j][r]);
        }
    __syncthreads();

    // scores: T_partial = y_slice @ gu  (8 MFMAs per wave; gfrags reloaded per tile)
    bf16x8 gfrag0 = *(const bf16x8*)(guT + ((size_t)b * 16 + l15) * 512 + w * 64 + q * 8);
    bf16x8 gfrag1 = *(const bf16x8*)(guT + ((size_t)b * 16 + l15) * 512 + w * 64 + 32 + q * 8);
    f32x4 Tacc[4];
    #pragma unroll
    for (int rt = 0; rt < 4; rt++) { Tacc[rt][0]=0.f; Tacc[rt][1]=0.f; Tacc[rt][2]=0.f; Tacc[rt][3]=0.f; }
    #pragma unroll
    for (int rt = 0; rt < 4; rt++) {
      int row = rt * 16 + l15;
      int sw = (row & 7) << 4;
      bf16x8 ay0 = *(const bf16x8*)(ymine + ((row * 128 + q * 16) ^ sw));
      Tacc[rt] = __builtin_amdgcn_mfma_f32_16x16x32_bf16(ay0, gfrag0, Tacc[rt], 0, 0, 0);
      bf16x8 ay1 = *(const bf16x8*)(ymine + ((row * 128 + 64 + q * 16) ^ sw));
      Tacc[rt] = __builtin_amdgcn_mfma_f32_16x16x32_bf16(ay1, gfrag1, Tacc[rt], 0, 0, 0);
    }
    {
      float* tp = (float*)ymine;
      if (l15 < 8) {
        #pragma unroll
        for (int rt = 0; rt < 4; rt++)
          #pragma unroll
          for (int r = 0; r < 4; r++)
            tp[(rt * 16 + q * 4 + r) * 8 + l15] = Tacc[rt][r];
      }
    }
    __syncthreads();   // T_parts visible

    // a-phase
    {
      int row = t >> 3, n = t & 7;
      float Tsum = 0.f;
      #pragma unroll
      for (int w2 = 0; w2 < 8; w2++)
        Tsum += ((const float*)(smem + w2 * 8192))[row * 8 + n];
      float mu = mu_rstd[row * 2], rstd = mu_rstd[row * 2 + 1];
      float spre = rstd * (Tsum - mu * Gs) + S0v;
      float aval = spre * 0.125f * ldx(ior, ((size_t)b * 8 + n) * 4096 + row0 + row, isf);
      am_acc += aval;
      mm_acc += aval * mu * rstd;
      a_lds[row * 8 + n] = aval * rstd;
    }
    __syncthreads();   // a_lds ready

    // R[n][col] contribution of this tile (per-tile flush)
    float rv[4][8];
    #pragma unroll
    for (int j = 0; j < 4; j++)
      #pragma unroll
      for (int n = 0; n < 8; n++) rv[j][n] = 0.f;
    #pragma unroll
    for (int i = 0; i < 4; i++)
      #pragma unroll
      for (int r = 0; r < 4; r++) {
        int row = i * 16 + q * 4 + r;
        const float* ap = a_lds + row * 8;
        float a0=ap[0],a1=ap[1],a2=ap[2],a3=ap[3],a4=ap[4],a5=ap[5],a6=ap[6],a7=ap[7];
        #pragma unroll
        for (int j = 0; j < 4; j++) {
          float m = acc[i][j][r];
          rv[j][0] += m*a0; rv[j][1] += m*a1; rv[j][2] += m*a2; rv[j][3] += m*a3;
          rv[j][4] += m*a4; rv[j][5] += m*a5; rv[j][6] += m*a6; rv[j][7] += m*a7;
        }
      }
    #pragma unroll
    for (int j = 0; j < 4; j++)
      #pragma unroll
      for (int n = 0; n < 8; n++) {
        float v = rv[j][n];
        v += __shfl_xor(v, 16);
        v += __shfl_xor(v, 32);
        rv[j][n] = v;
      }
    if (q == 0) {
      #pragma unroll
      for (int j = 0; j < 4; j++)
        #pragma unroll
        for (int n = 0; n < 8; n++)
          atomicAdd(R_g + ((size_t)b * 8 + n) * 512 + (w * 64 + j * 16 + l15), rv[j][n]);
    }
  }

  // ---- A/M flush ----
  am_acc += __shfl_xor(am_acc, 8);
  am_acc += __shfl_xor(am_acc, 16);
  am_acc += __shfl_xor(am_acc, 32);
  mm_acc += __shfl_xor(mm_acc, 8);
  mm_acc += __shfl_xor(mm_acc, 16);
  mm_acc += __shfl_xor(mm_acc, 32);
  if (lane < 8) {
    atomicAdd(A_g + b * 8 + lane, am_acc);
    atomicAdd(M_g + b * 8 + lane, mm_acc);
  }
}

// ---------------- kernel 5: x = r@Wv + A*bv + query ; LN -> xln ----------------
__global__ __launch_bounds__(512) void k_mid(
    const float* __restrict__ R_g, const float* __restrict__ A_g, const float* __restrict__ M_g,
    const float* __restrict__ P1, const float* __restrict__ P2,
    const void* __restrict__ Wkv, const void* __restrict__ bkv, const void* __restrict__ g_in,
    const void* __restrict__ query, const void* __restrict__ g_f, const void* __restrict__ be_f,
    float* __restrict__ xrow_ws, float* __restrict__ xln_ws,
    const int* __restrict__ flag) {
  int isf = flag[0];
  int b = blockIdx.x, t = threadIdx.x;
  __shared__ float Rl[4096];    // g[c]*R[b][n][c]
  __shared__ float red[16];
  __shared__ float stats[2];
  #pragma unroll
  for (int k = 0; k < 8; k++) {
    int e = t + 512 * k;
    Rl[e] = R_g[(size_t)b * 4096 + e] * ldx(g_in, e & 511, isf);
  }
  __syncthreads();
  int j = t, n = t >> 6;
  float Av = A_g[b * 8 + n], Mv = M_g[b * 8 + n];
  float base = Av * ldx(bkv, 512 + j, isf) - Mv * P1[j] + Av * P2[j];
  const float* rl = Rl + n * 512;
  float a0 = 0.f, a1 = 0.f, a2 = 0.f, a3 = 0.f;
  if (isf) {
    const float* wv = (const float*)Wkv + 512 + j;
    #pragma unroll 2
    for (int c = 0; c < 512; c += 4) {
      a0 += rl[c]     * wv[(size_t)c * 1024];
      a1 += rl[c + 1] * wv[(size_t)(c + 1) * 1024];
      a2 += rl[c + 2] * wv[(size_t)(c + 2) * 1024];
      a3 += rl[c + 3] * wv[(size_t)(c + 3) * 1024];
    }
  } else {
    const u16* wv = (const u16*)Wkv + 512 + j;
    #pragma unroll 2
    for (int c = 0; c < 512; c += 4) {
      a0 += rl[c]     * b2f(wv[(size_t)c * 1024]);
      a1 += rl[c + 1] * b2f(wv[(size_t)(c + 1) * 1024]);
      a2 += rl[c + 2] * b2f(wv[(size_t)(c + 2) * 1024]);
      a3 += rl[c + 3] * b2f(wv[(size_t)(c + 3) * 1024]);
    }
  }
  float v = base + (a0 + a1) + (a2 + a3) + ldx(query, (size_t)b * 512 + t, isf);
  xrow_ws[(size_t)b * 512 + t] = v;
  float s1 = v, s2 = v * v;
  for (int off = 32; off; off >>= 1) { s1 += __shfl_xor(s1, off); s2 += __shfl_xor(s2, off); }
  int wid = t >> 6, lane = t & 63;
  if (lane == 0) { red[wid * 2] = s1; red[wid * 2 + 1] = s2; }
  __syncthreads();
  if (t == 0) {
    float S = 0.f, SS = 0.f;
    for (int w = 0; w < 8; w++) { S += red[w * 2]; SS += red[w * 2 + 1]; }
    float mu = S / 512.f;
    float var = SS / 512.f - mu * mu;
    stats[0] = mu; stats[1] = rsqrtf(var + 1e-5f);
  }
  __syncthreads();
  xln_ws[(size_t)b * 512 + t] = (v - stats[0]) * stats[1] * ldx(g_f, t, isf) + ldx(be_f, t, isf);
}

// ---------------- kernel 6: hdn[b][2048] = gelu(xln @ W1 + b1), W1 read ONCE ----------------
// grid 32: block g owns cols [g*64, g*64+64). Wave w computes 4 batches (b = w*4+bi) for
// its 64 cols; xln accessed at wave-uniform addresses -> compiler scalarizes (SGPR stream).
__global__ __launch_bounds__(512) void k_f1(
    const float* __restrict__ xln_ws, const void* __restrict__ W1, const void* __restrict__ b1,
    float* __restrict__ hdn_ws, const int* __restrict__ flag) {
  int isf = flag[0];
  int g = blockIdx.x, t = threadIdx.x;
  int jl = t & 63;
  int b0 = __builtin_amdgcn_readfirstlane(t >> 6) * 4;   // wave-uniform batch base
  int j = g * 64 + jl;
  float b1v = ldx(b1, j, isf);
  float acc0 = b1v, acc1 = b1v, acc2 = b1v, acc3 = b1v;
  const float* x0 = xln_ws + (size_t)b0 * 512;
  for (int c = 0; c < 512; c++) {
    float wv = ldx(W1, (size_t)c * 2048 + j, isf);
    acc0 += x0[c]        * wv;
    acc1 += x0[512 + c]  * wv;
    acc2 += x0[1024 + c] * wv;
    acc3 += x0[1536 + c] * wv;
  }
  hdn_ws[(size_t)(b0 + 0) * 2048 + j] = 0.5f * acc0 * (1.0f + erff(acc0 * 0.70710678118654752f));
  hdn_ws[(size_t)(b0 + 1) * 2048 + j] = 0.5f * acc1 * (1.0f + erff(acc1 * 0.70710678118654752f));
  hdn_ws[(size_t)(b0 + 2) * 2048 + j] = 0.5f * acc2 * (1.0f + erff(acc2 * 0.70710678118654752f));
  hdn_ws[(size_t)(b0 + 3) * 2048 + j] = 0.5f * acc3 * (1.0f + erff(acc3 * 0.70710678118654752f));
}

// ---------------- kernel 7: y_part[g] = hdn[:, Kslice] @ W2[Kslice, :], W2 read ONCE ----------------
// grid 16: block g owns K in [g*128, g*128+128). Each thread: one j, acc[32] (all b),
// hdn accessed at uniform addresses (loop vars only) -> SGPR stream.
__global__ __launch_bounds__(512) void k_f2(
    const float* __restrict__ hdn_ws, const void* __restrict__ W2,
    float* __restrict__ y_part, const int* __restrict__ flag) {
  int isf = flag[0];
  int g = blockIdx.x, t = threadIdx.x;
  float acc[32];
  #pragma unroll
  for (int b = 0; b < 32; b++) acc[b] = 0.f;
  int k0 = g * 128;
  #pragma unroll 4
  for (int k = 0; k < 128; k++) {
    float wv = ldx(W2, (size_t)(k0 + k) * 512 + t, isf);
    #pragma unroll
    for (int b = 0; b < 32; b++)
      acc[b] += hdn_ws[(size_t)b * 2048 + k0 + k] * wv;
  }
  #pragma unroll
  for (int b = 0; b < 32; b++)
    y_part[(size_t)g * 16384 + (size_t)b * 512 + t] = acc[b];
}

// ---------------- kernel 8: out = cast(sum_g y_part + b2 + xrow) ----------------
__global__ __launch_bounds__(512) void k_final(
    const float* __restrict__ y_part, const void* __restrict__ b2v,
    const float* __restrict__ xrow_ws, void* __restrict__ out,
    const int* __restrict__ flag) {
  int isf = flag[0];
  int b = blockIdx.x, t = threadIdx.x;
  float v = ldx(b2v, t, isf) + xrow_ws[(size_t)b * 512 + t];
  #pragma unroll
  for (int g = 0; g < 16; g++)
    v += y_part[(size_t)g * 16384 + (size_t)b * 512 + t];
  if (isf) ((float*)out)[b * 512 + t] = v;
  else     ((u16*)out)[b * 512 + t] = f2b(v);
}

extern "C" void kernel_launch(void* const* d_in, const int* in_sizes, int n_in,
                              void* d_out, int out_size, void* d_ws, size_t ws_size,
                              hipStream_t stream) {
  const void* query = d_in[0];
  const void* mem   = d_in[1];
  const void* ior   = d_in[2];
  const void* W_in  = d_in[3];
  const void* b_in  = d_in[4];
  const void* g_in  = d_in[5];
  const void* be_in = d_in[6];
  const void* Wq    = d_in[7];
  const void* bq    = d_in[8];
  const void* Wkv   = d_in[9];
  const void* bkv   = d_in[10];
  const void* W1    = d_in[11];
  const void* b1    = d_in[12];
  const void* W2    = d_in[13];
  const void* b2v   = d_in[14];
  const void* g_q   = d_in[15];
  const void* be_q  = d_in[16];
  const void* g_f   = d_in[17];
  const void* be_f  = d_in[18];

  // ws layout (total 1,970,432 B). Time-shared overlays:
  //   guT [528640,1052928) (k_qprep_b -> k_main) overlays {hdn, xrow, xln, y_part-head},
  //     all written only after k_main completes.
  //   y_part [921856,1970432) also overlays WT/P1/P2/qr, all dead before k_f2 writes it
  //     (WT: k_main only; P1/P2: consumed by k_mid; qr: consumed by k_qprep_b).
  char* ws = (char*)d_ws;
  int*   flag   = (int*)ws;                      // [0,256)
  float* S0_g   = (float*)(ws + 256);            // 1024
  float* Gsum_g = (float*)(ws + 1280);           // 1024
  float* A_g    = (float*)(ws + 2304);           // 1024
  float* M_g    = (float*)(ws + 3328);           // 1024
  float* R_g    = (float*)(ws + 4352);           // 524288
  u16*   guT    = (u16*)(ws + 528640);           // 524288 (overlay)
  float* hdn_ws = (float*)(ws + 528640);         // 262144
  float* xrow_ws= (float*)(ws + 790784);         // 65536
  float* xln_ws = (float*)(ws + 856320);         // 65536
  float* y_part = (float*)(ws + 921856);         // 1048576 (overlay onto WT/P1/P2/qr)
  u16*   WT     = (u16*)(ws + 1052928);          // 524288
  float* P1     = (float*)(ws + 1577216);        // 2048
  float* P2     = (float*)(ws + 1579264);        // 2048
  float* qr_ws  = (float*)(ws + 1581312);        // 65536

  hipMemsetAsync(ws + 256, 0, 528384, stream);   // zero S0, Gsum, A, M, R
  k_detect<<<dim3(1), dim3(64), 0, stream>>>(query, flag);
  k_transpose<<<dim3(64), dim3(256), 0, stream>>>(W_in, WT, flag);
  k_prep2<<<dim3(16), dim3(512), 0, stream>>>(Wkv, g_in, be_in, P1, P2, flag);
  k_qprep_a<<<dim3(32, 4), dim3(256), 0, stream>>>(query, Wq, bq, g_q, be_q, qr_ws, flag);
  k_qprep_b<<<dim3(32, 4), dim3(256), 0, stream>>>(qr_ws, Wkv, bkv, g_in, be_in,
                                                   guT, Gsum_g, S0_g, flag);
  k_main<<<dim3(16, 32), dim3(512), 0, stream>>>(mem, WT, b_in, ior, guT, Gsum_g, S0_g,
                                                 R_g, A_g, M_g, flag);
  k_mid<<<dim3(32), dim3(512), 0, stream>>>(R_g, A_g, M_g, P1, P2, Wkv, bkv, g_in,
                                            query, g_f, be_f, xrow_ws, xln_ws, flag);
  k_f1<<<dim3(32), dim3(512), 0, stream>>>(xln_ws, W1, b1, hdn_ws, flag);
  k_f2<<<dim3(16), dim3(512), 0, stream>>>(hdn_ws, W2, y_part, flag);
  k_final<<<dim3(32), dim3(512), 0, stream>>>(y_part, b2v, xrow_ws, d_out, flag);
}

// Round 6
// 811.177 us; speedup vs baseline: 1.1571x; 1.1571x over previous
//
#include <hip/hip_runtime.h>
#include <hip/hip_bf16.h>
#include <math.h>

typedef unsigned short u16;
typedef __bf16 bf16x8 __attribute__((ext_vector_type(8)));
typedef float f32x4 __attribute__((ext_vector_type(4)));

__device__ __forceinline__ float b2f(u16 u) {
  union { unsigned int i; float f; } v; v.i = ((unsigned int)u) << 16; return v.f;
}
__device__ __forceinline__ u16 f2b(float f) {
  union { float f; unsigned int i; } v; v.f = f;
  unsigned int x = v.i;
  return (u16)((x + 0x7fffu + ((x >> 16) & 1u)) >> 16);
}
// dual-dtype scalar load: isf=1 -> f32, isf=0 -> bf16
__device__ __forceinline__ float ldx(const void* p, size_t i, int isf) {
  return isf ? ((const float*)p)[i] : b2f(((const u16*)p)[i]);
}

// ---------------- kernel 0: dtype detect (f32 vs bf16) ----------------
__global__ void k_detect(const void* __restrict__ query, int* __restrict__ flag) {
  int t = threadIdx.x;  // 64 threads
  float v = ((const float*)query)[t];
  int ok = (v == v && fabsf(v) < 100.f && fabsf(v) > 1e-4f) ? 1 : 0;
  unsigned long long m = __ballot(ok);
  if (t == 0) flag[0] = (__popcll(m) >= 32) ? 1 : 0;
}

// ---------------- kernel 1: W_in (512x512) -> WTf, MFMA-FRAGMENT order ----------------
// WTf u16 index: ((jb*16 + ks)*16 + l)*32 + q*8 + r   (jb=j>>4, l=j&15, ks=k>>5,
// q=(k>>3)&3, r=k&7; j=output col, k=mem_dim). A wave's B-fragment load for (jb,ks)
// is then 64 lanes x 16B CONTIGUOUS (1KB) -> perfectly coalesced L2 hit; no LDS needed.
__global__ __launch_bounds__(256) void k_makeB(const void* __restrict__ Win,
                                               u16* __restrict__ WTf,
                                               const int* __restrict__ flag) {
  int isf = flag[0];
  int t = threadIdx.x;
  int bx = blockIdx.x & 7, by = blockIdx.x >> 3;   // bx: k-tile (64 k), by: j-tile (64 j)
  int k0 = bx * 64, j0 = by * 64;
  __shared__ float tile[64][65];                    // [k_local][j_local], +1 pad
  #pragma unroll
  for (int kx = 0; kx < 16; kx++) {
    int idx = t + 256 * kx;
    int kl = idx >> 6, jl = idx & 63;               // coalesced over jl
    tile[kl][jl] = ldx(Win, (size_t)(k0 + kl) * 512 + (j0 + jl), isf);
  }
  __syncthreads();
  #pragma unroll
  for (int i = 0; i < 2; i++) {
    int chunk = i * 256 + t;                        // consecutive lanes -> consecutive dst
    int q  = chunk & 3;
    int l  = (chunk >> 2) & 15;
    int ksL = (chunk >> 6) & 1;
    int jbL = (chunk >> 7) & 3;
    int j_local = jbL * 16 + l;
    int k_local = ksL * 32 + q * 8;
    union { u16 h[8]; uint4 u; } pk;
    #pragma unroll
    for (int r = 0; r < 8; r++) pk.h[r] = f2b(tile[k_local + r][j_local]);
    int jb = by * 4 + jbL, ks = bx * 2 + ksL;
    *(uint4*)(WTf + ((size_t)(jb * 16 + ks) * 16 + l) * 32 + q * 8) = pk.u;
  }
}

// ---------------- kernel 2: P1[j]=sum_c g_in[c]*Wv[c][j], P2[j]=sum_c be_in[c]*Wv[c][j] ----------------
__global__ __launch_bounds__(512) void k_prep2(const void* __restrict__ Wkv,
                                               const void* __restrict__ g_in,
                                               const void* __restrict__ be_in,
                                               float* __restrict__ P1, float* __restrict__ P2,
                                               const int* __restrict__ flag) {
  int isf = flag[0];
  int blk = blockIdx.x;            // 16 blocks x 32 j
  int t = threadIdx.x;
  int jj = t & 31, cg = t >> 5;    // 16 c-groups of 32
  int j = blk * 32 + jj;
  float p1 = 0.f, p2 = 0.f;
  for (int cc = 0; cc < 32; cc++) {
    int c = cg * 32 + cc;
    float wv = ldx(Wkv, (size_t)c * 1024 + 512 + j, isf);
    p1 += ldx(g_in, c, isf) * wv;
    p2 += ldx(be_in, c, isf) * wv;
  }
  __shared__ float red[1024];
  red[t * 2] = p1; red[t * 2 + 1] = p2;
  __syncthreads();
  if (t < 32) {
    float s1 = 0.f, s2 = 0.f;
    for (int g2 = 0; g2 < 16; g2++) { s1 += red[(g2 * 32 + t) * 2]; s2 += red[(g2 * 32 + t) * 2 + 1]; }
    P1[blk * 32 + t] = s1;
    P2[blk * 32 + t] = s2;
  }
}

// ---------------- kernel 3a: qr = LN(query) @ Wq + bq ----------------
__global__ __launch_bounds__(256) void k_qprep_a(
    const void* __restrict__ query, const void* __restrict__ Wq, const void* __restrict__ bq,
    const void* __restrict__ g_q, const void* __restrict__ be_q,
    float* __restrict__ qr_ws, const int* __restrict__ flag) {
  int isf = flag[0];
  int b = blockIdx.x, jq = blockIdx.y, t = threadIdx.x;
  __shared__ float qf[512];
  __shared__ float red[8];
  __shared__ float stats[2];

  float s = 0.f, ss = 0.f;
  for (int k = 0; k < 2; k++) {
    int c = t + 256 * k;
    float v = ldx(query, (size_t)b * 512 + c, isf);
    qf[c] = v; s += v; ss += v * v;
  }
  for (int off = 32; off; off >>= 1) { s += __shfl_xor(s, off); ss += __shfl_xor(ss, off); }
  int wid = t >> 6, lane = t & 63;
  if (lane == 0) { red[wid * 2] = s; red[wid * 2 + 1] = ss; }
  __syncthreads();
  if (t == 0) {
    float S = 0.f, SS = 0.f;
    for (int w = 0; w < 4; w++) { S += red[w * 2]; SS += red[w * 2 + 1]; }
    float mu = S / 512.f;
    float var = SS / 512.f - mu * mu;
    stats[0] = mu; stats[1] = rsqrtf(var + 1e-5f);
  }
  __syncthreads();
  float mu = stats[0], rstd = stats[1];
  for (int k = 0; k < 2; k++) {
    int c = t + 256 * k;
    qf[c] = (qf[c] - mu) * rstd * ldx(g_q, c, isf) + ldx(be_q, c, isf);
  }
  __syncthreads();
  int jl = t >> 1, half = t & 1;
  int j = jq * 128 + jl;
  const float* qh = qf + half * 256;
  float a0 = 0.f, a1 = 0.f, a2 = 0.f, a3 = 0.f;
  if (isf) {
    const float* wp = (const float*)Wq + (size_t)(half * 256) * 512 + j;
    #pragma unroll 2
    for (int cc = 0; cc < 256; cc += 4) {
      a0 += qh[cc]     * wp[(size_t)cc * 512];
      a1 += qh[cc + 1] * wp[(size_t)(cc + 1) * 512];
      a2 += qh[cc + 2] * wp[(size_t)(cc + 2) * 512];
      a3 += qh[cc + 3] * wp[(size_t)(cc + 3) * 512];
    }
  } else {
    const u16* wp = (const u16*)Wq + (size_t)(half * 256) * 512 + j;
    #pragma unroll 2
    for (int cc = 0; cc < 256; cc += 4) {
      a0 += qh[cc]     * b2f(wp[(size_t)cc * 512]);
      a1 += qh[cc + 1] * b2f(wp[(size_t)(cc + 1) * 512]);
      a2 += qh[cc + 2] * b2f(wp[(size_t)(cc + 2) * 512]);
      a3 += qh[cc + 3] * b2f(wp[(size_t)(cc + 3) * 512]);
    }
  }
  float acc = (a0 + a1) + (a2 + a3);
  acc += __shfl_xor(acc, 1);
  if (half == 0) qr_ws[(size_t)b * 512 + j] = acc + ldx(bq, j, isf);
}

// ---------------- kernel 3b: u -> guT (bf16 [b][16][512]), Gsum, S0 (=BeU + c0) ----------------
__global__ __launch_bounds__(256) void k_qprep_b(
    const float* __restrict__ qr_ws, const void* __restrict__ Wkv, const void* __restrict__ bkv,
    const void* __restrict__ g_in, const void* __restrict__ be_in,
    u16* __restrict__ guT, float* __restrict__ Gsum_g, float* __restrict__ S0_g,
    const int* __restrict__ flag) {
  int isf = flag[0];
  int b = blockIdx.x, cq = blockIdx.y, t = threadIdx.x;   // cq: 4 c-quarters of 128
  __shared__ float qrl[512];
  __shared__ float ul[128 * 8];
  qrl[t] = qr_ws[(size_t)b * 512 + t];
  qrl[t + 256] = qr_ws[(size_t)b * 512 + t + 256];
  __syncthreads();
  #pragma unroll
  for (int e4 = 0; e4 < 4; e4++) {
    int e = t + 256 * e4;
    int cl = e >> 3, n = e & 7;
    int c = cq * 128 + cl;
    const float* qp = qrl + n * 64;
    float acc = 0.f;
    if (isf) {
      const float* wp = (const float*)Wkv + (size_t)c * 1024 + n * 64;
      #pragma unroll 8
      for (int d = 0; d < 64; d++) acc += wp[d] * qp[d];
    } else {
      const u16* wp = (const u16*)Wkv + (size_t)c * 1024 + n * 64;
      #pragma unroll 8
      for (int d = 0; d < 64; d++) acc += b2f(wp[d]) * qp[d];
    }
    ul[cl * 8 + n] = acc;
  }
  __syncthreads();
  #pragma unroll
  for (int e4 = 0; e4 < 4; e4++) {
    int e = t + 256 * e4;
    int cl = e >> 3, n = e & 7;
    int c = cq * 128 + cl;
    guT[((size_t)b * 16 + n) * 512 + c] = f2b(ldx(g_in, c, isf) * ul[cl * 8 + n]);
    guT[((size_t)b * 16 + 8 + n) * 512 + c] = 0;
  }
  if (t < 64) {
    int n = t >> 3, seg = t & 7;
    float gs = 0.f, s0 = 0.f;
    for (int k = 0; k < 16; k++) {
      int cl = seg * 16 + k;
      int c = cq * 128 + cl;
      float uu = ul[cl * 8 + n];
      gs += ldx(g_in, c, isf) * uu;
      s0 += ldx(be_in, c, isf) * uu;
    }
    gs += __shfl_xor(gs, 1); s0 += __shfl_xor(s0, 1);
    gs += __shfl_xor(gs, 2); s0 += __shfl_xor(s0, 2);
    gs += __shfl_xor(gs, 4); s0 += __shfl_xor(s0, 4);
    if (seg == 0) {
      atomicAdd(Gsum_g + b * 8 + n, gs);
      atomicAdd(S0_g + b * 8 + n, s0);
    }
  }
  if (cq == 0 && t < 8) {
    float acc = 0.f;
    for (int d = 0; d < 64; d++) acc += ldx(bkv, t * 64 + d, isf) * qrl[t * 64 + d];
    atomicAdd(S0_g + b * 8 + t, acc);
  }
}

// ---------------- kernel 4: fused m-GEMM + relu + LN-stats + MFMA-scores + R accumulation ----------------
// v6 = round-4 verified structure with ONE change: Bb LDS staging deleted. Each B row
// was read by exactly one wave (zero sharing), so staging it through LDS moved
// 64KB/K-step through the LDS pipe for nothing. B fragments now come straight from
// fragment-ordered WTf (L2-resident, 1KB coalesced per wave-load). Removes ~90% of
// per-step LDS traffic, the Bb bank conflicts, and 16 VGPR of bv staging.
#define LDA 40
__global__ __launch_bounds__(512) void k_main(
    const void* __restrict__ mem, const u16* __restrict__ WTf, const void* __restrict__ b_in,
    const void* __restrict__ ior, const u16* __restrict__ guT,
    const float* __restrict__ Gsum_g, const float* __restrict__ S0_g,
    float* __restrict__ R_g, float* __restrict__ A_g, float* __restrict__ M_g,
    const int* __restrict__ flag) {
  int isf = flag[0];
  int blk = blockIdx.x;           // 0..15 (4 row-tiles each)
  int b   = blockIdx.y;           // 0..31
  int t = threadIdx.x;
  int w = t >> 6, lane = t & 63;
  int l15 = lane & 15, q = lane >> 4;

  // LDS map (68096 B):
  //   K-loop:   Ab [0,5120) 64x40 bf16  (Bb is GONE)
  //   epilogue (overlays): rowred [0,4096), y slices (wave w at w*8192, [64][64] bf16
  //             XOR-swizzled; T_part overlays first 2KB), mu_rstd [65536,66048),
  //             a_lds [66048,68096)
  __shared__ __align__(16) char smem[68096];
  u16*   Ab      = (u16*)smem;
  float* rowred  = (float*)smem;
  float* mu_rstd = (float*)(smem + 65536);
  float* a_lds   = (float*)(smem + 66048);
  char*  ymine   = smem + w * 8192;

  float binv[4];
  #pragma unroll
  for (int j = 0; j < 4; j++) binv[j] = ldx(b_in, w * 64 + j * 16 + l15, isf);
  // gu B-fragments for the score MFMA (tile-invariant)
  bf16x8 gfrag0 = *(const bf16x8*)(guT + ((size_t)b * 16 + l15) * 512 + w * 64 + q * 8);
  bf16x8 gfrag1 = *(const bf16x8*)(guT + ((size_t)b * 16 + l15) * 512 + w * 64 + 32 + q * 8);
  float Gs  = Gsum_g[b * 8 + (t & 7)];
  float S0v = S0_g[b * 8 + (t & 7)];
  // B fragment base: wave w owns jb = w*4..w*4+3; frag (j,ks) at wb + j*8192 + ks*512
  const u16* wb = WTf + (size_t)w * 32768 + l15 * 32 + q * 8;

  float am_acc = 0.f, mm_acc = 0.f;

  for (int tile = 0; tile < 4; tile++) {
    int row0 = (blk * 4 + tile) * 64;
    size_t memBase = ((size_t)b * 4096 + row0) * 512;

    f32x4 acc[4][4];
    #pragma unroll
    for (int i = 0; i < 4; i++)
      #pragma unroll
      for (int j = 0; j < 4; j++) { acc[i][j][0]=0.f; acc[i][j][1]=0.f; acc[i][j][2]=0.f; acc[i][j][3]=0.f; }

    for (int kk = 0; kk < 512; kk += 32) {
      __syncthreads();   // prev-step Ab reads done
      if (isf) {         // A tile 64x32 f32: 512 thr x 4 floats
        int e = t * 4;
        int r = e >> 5, c = e & 31;
        float4 v = *(const float4*)((const float*)mem + memBase + (size_t)r * 512 + kk + c);
        union { u16 h[4]; uint2 u; } pk;
        pk.h[0] = f2b(v.x); pk.h[1] = f2b(v.y); pk.h[2] = f2b(v.z); pk.h[3] = f2b(v.w);
        *(uint2*)(Ab + r * LDA + c) = pk.u;
      } else if (t < 256) {  // A tile 64x32 bf16: 256 thr x 8
        int r = t >> 2, ch = t & 3;
        uint4 v = *(const uint4*)((const u16*)mem + memBase + (size_t)r * 512 + kk + ch * 8);
        *(uint4*)(Ab + r * LDA + ch * 8) = v;
      }
      __syncthreads();   // Ab ready
      int ks = kk >> 5;
      bf16x8 aF[4], bF[4];
      #pragma unroll
      for (int j = 0; j < 4; j++)
        bF[j] = *(const bf16x8*)(wb + j * 8192 + ks * 512);
      #pragma unroll
      for (int i = 0; i < 4; i++)
        aF[i] = *(const bf16x8*)(Ab + (i * 16 + l15) * LDA + q * 8);
      #pragma unroll
      for (int i = 0; i < 4; i++)
        #pragma unroll
        for (int j = 0; j < 4; j++)
          acc[i][j] = __builtin_amdgcn_mfma_f32_16x16x32_bf16(aF[i], bF[j], acc[i][j], 0, 0, 0);
    }
    __syncthreads();   // staging dead; epilogue overlays begin

    // bias + relu (acc stays PRE-LN y)
    #pragma unroll
    for (int i = 0; i < 4; i++)
      #pragma unroll
      for (int j = 0; j < 4; j++)
        #pragma unroll
        for (int r = 0; r < 4; r++) {
          float v = acc[i][j][r] + binv[j];
          acc[i][j][r] = v > 0.f ? v : 0.f;
        }
    // LN stats partials (per-wave 64-col slices)
    #pragma unroll
    for (int i = 0; i < 4; i++)
      #pragma unroll
      for (int r = 0; r < 4; r++) {
        float s  = acc[i][0][r] + acc[i][1][r] + acc[i][2][r] + acc[i][3][r];
        float ss = acc[i][0][r]*acc[i][0][r] + acc[i][1][r]*acc[i][1][r]
                 + acc[i][2][r]*acc[i][2][r] + acc[i][3][r]*acc[i][3][r];
        #pragma unroll
        for (int m = 1; m < 16; m <<= 1) { s += __shfl_xor(s, m); ss += __shfl_xor(ss, m); }
        if (l15 == 0) {
          int row = i * 16 + q * 4 + r;
          rowred[(w * 64 + row) * 2]     = s;
          rowred[(w * 64 + row) * 2 + 1] = ss;
        }
      }
    __syncthreads();
    if (t < 64) {
      float S = 0.f, SS = 0.f;
      for (int w2 = 0; w2 < 8; w2++) { S += rowred[(w2 * 64 + t) * 2]; SS += rowred[(w2 * 64 + t) * 2 + 1]; }
      float mu = S / 512.f;
      float var = SS / 512.f - mu * mu;
      mu_rstd[t * 2] = mu;
      mu_rstd[t * 2 + 1] = rsqrtf(var + 1e-5f);
    }
    __syncthreads();   // rowred consumed; y writes may overwrite [0,65536)

    // write this wave's y-slice [64][64] bf16, XOR-swizzled
    #pragma unroll
    for (int i = 0; i < 4; i++)
      #pragma unroll
      for (int j = 0; j < 4; j++)
        #pragma unroll
        for (int r = 0; r < 4; r++) {
          int row = i * 16 + q * 4 + r;
          int byo = (row * 128 + j * 32 + l15 * 2) ^ ((row & 7) << 4);
          *(u16*)(ymine + byo) = f2b(acc[i][j][r]);
        }
    __syncthreads();

    // scores: T_partial = y_slice @ gu  (8 MFMAs per wave, K = own 64 cols)
    f32x4 Tacc[4];
    #pragma unroll
    for (int rt = 0; rt < 4; rt++) { Tacc[rt][0]=0.f; Tacc[rt][1]=0.f; Tacc[rt][2]=0.f; Tacc[rt][3]=0.f; }
    #pragma unroll
    for (int rt = 0; rt < 4; rt++) {
      int row = rt * 16 + l15;
      int sw = (row & 7) << 4;
      bf16x8 ay0 = *(const bf16x8*)(ymine + ((row * 128 + q * 16) ^ sw));
      Tacc[rt] = __builtin_amdgcn_mfma_f32_16x16x32_bf16(ay0, gfrag0, Tacc[rt], 0, 0, 0);
      bf16x8 ay1 = *(const bf16x8*)(ymine + ((row * 128 + 64 + q * 16) ^ sw));
      Tacc[rt] = __builtin_amdgcn_mfma_f32_16x16x32_bf16(ay1, gfrag1, Tacc[rt], 0, 0, 0);
    }
    // T_part [64][8] f32 overlays own slice's first 2KB (own y already consumed)
    {
      float* tp = (float*)ymine;
      if (l15 < 8) {
        #pragma unroll
        for (int rt = 0; rt < 4; rt++)
          #pragma unroll
          for (int r = 0; r < 4; r++)
            tp[(rt * 16 + q * 4 + r) * 8 + l15] = Tacc[rt][r];
      }
    }
    __syncthreads();   // T_parts visible

    // a-phase: combine wave partials, deferred-LN affine, *scale*ior; accumulate A/M
    {
      int row = t >> 3, n = t & 7;
      float Tsum = 0.f;
      #pragma unroll
      for (int w2 = 0; w2 < 8; w2++)
        Tsum += ((const float*)(smem + w2 * 8192))[row * 8 + n];
      float mu = mu_rstd[row * 2], rstd = mu_rstd[row * 2 + 1];
      float spre = rstd * (Tsum - mu * Gs) + S0v;
      float aval = spre * 0.125f * ldx(ior, ((size_t)b * 8 + n) * 4096 + row0 + row, isf);
      am_acc += aval;
      mm_acc += aval * mu * rstd;
      a_lds[row * 8 + n] = aval * rstd;   // a' = a*rstd for the R contraction
    }
    __syncthreads();   // a_lds ready

    // R[n][col] contribution of this tile (per-tile flush)
    float rv[4][8];
    #pragma unroll
    for (int j = 0; j < 4; j++)
      #pragma unroll
      for (int n = 0; n < 8; n++) rv[j][n] = 0.f;
    #pragma unroll
    for (int i = 0; i < 4; i++)
      #pragma unroll
      for (int r = 0; r < 4; r++) {
        int row = i * 16 + q * 4 + r;
        const float* ap = a_lds + row * 8;
        float a0=ap[0],a1=ap[1],a2=ap[2],a3=ap[3],a4=ap[4],a5=ap[5],a6=ap[6],a7=ap[7];
        #pragma unroll
        for (int j = 0; j < 4; j++) {
          float m = acc[i][j][r];
          rv[j][0] += m*a0; rv[j][1] += m*a1; rv[j][2] += m*a2; rv[j][3] += m*a3;
          rv[j][4] += m*a4; rv[j][5] += m*a5; rv[j][6] += m*a6; rv[j][7] += m*a7;
        }
      }
    #pragma unroll
    for (int j = 0; j < 4; j++)
      #pragma unroll
      for (int n = 0; n < 8; n++) {
        float v = rv[j][n];
        v += __shfl_xor(v, 16);
        v += __shfl_xor(v, 32);
        rv[j][n] = v;
      }
    if (q == 0) {
      #pragma unroll
      for (int j = 0; j < 4; j++)
        #pragma unroll
        for (int n = 0; n < 8; n++)
          atomicAdd(R_g + ((size_t)b * 8 + n) * 512 + (w * 64 + j * 16 + l15), rv[j][n]);
    }
  }

  // ---- A/M flush (accumulated across tiles) ----
  am_acc += __shfl_xor(am_acc, 8);
  am_acc += __shfl_xor(am_acc, 16);
  am_acc += __shfl_xor(am_acc, 32);
  mm_acc += __shfl_xor(mm_acc, 8);
  mm_acc += __shfl_xor(mm_acc, 16);
  mm_acc += __shfl_xor(mm_acc, 32);
  if (lane < 8) {
    atomicAdd(A_g + b * 8 + lane, am_acc);
    atomicAdd(M_g + b * 8 + lane, mm_acc);
  }
}

// ---------------- kernel 5: x = r@Wv + A*bv + query ; LN -> xln ; zero y_acc ----------------
__global__ __launch_bounds__(512) void k_mid(
    const float* __restrict__ R_g, const float* __restrict__ A_g, const float* __restrict__ M_g,
    const float* __restrict__ P1, const float* __restrict__ P2,
    const void* __restrict__ Wkv, const void* __restrict__ bkv, const void* __restrict__ g_in,
    const void* __restrict__ query, const void* __restrict__ g_f, const void* __restrict__ be_f,
    float* __restrict__ xrow_ws, float* __restrict__ xln_ws, float* __restrict__ y_acc,
    const int* __restrict__ flag) {
  int isf = flag[0];
  int b = blockIdx.x, t = threadIdx.x;
  __shared__ float Rl[4096];    // g[c]*R[b][n][c]
  __shared__ float red[16];
  __shared__ float stats[2];
  #pragma unroll
  for (int k = 0; k < 8; k++) {
    int e = t + 512 * k;
    Rl[e] = R_g[(size_t)b * 4096 + e] * ldx(g_in, e & 511, isf);
  }
  __syncthreads();
  int j = t, n = t >> 6;
  float Av = A_g[b * 8 + n], Mv = M_g[b * 8 + n];
  float base = Av * ldx(bkv, 512 + j, isf) - Mv * P1[j] + Av * P2[j];
  const float* rl = Rl + n * 512;
  float a0 = 0.f, a1 = 0.f, a2 = 0.f, a3 = 0.f;
  if (isf) {
    const float* wv = (const float*)Wkv + 512 + j;
    #pragma unroll 2
    for (int c = 0; c < 512; c += 4) {
      a0 += rl[c]     * wv[(size_t)c * 1024];
      a1 += rl[c + 1] * wv[(size_t)(c + 1) * 1024];
      a2 += rl[c + 2] * wv[(size_t)(c + 2) * 1024];
      a3 += rl[c + 3] * wv[(size_t)(c + 3) * 1024];
    }
  } else {
    const u16* wv = (const u16*)Wkv + 512 + j;
    #pragma unroll 2
    for (int c = 0; c < 512; c += 4) {
      a0 += rl[c]     * b2f(wv[(size_t)c * 1024]);
      a1 += rl[c + 1] * b2f(wv[(size_t)(c + 1) * 1024]);
      a2 += rl[c + 2] * b2f(wv[(size_t)(c + 2) * 1024]);
      a3 += rl[c + 3] * b2f(wv[(size_t)(c + 3) * 1024]);
    }
  }
  float v = base + (a0 + a1) + (a2 + a3) + ldx(query, (size_t)b * 512 + t, isf);
  xrow_ws[(size_t)b * 512 + t] = v;
  y_acc[(size_t)b * 512 + t] = 0.f;   // zero here (region was overlaid by guT earlier)
  float s1 = v, s2 = v * v;
  for (int off = 32; off; off >>= 1) { s1 += __shfl_xor(s1, off); s2 += __shfl_xor(s2, off); }
  int wid = t >> 6, lane = t & 63;
  if (lane == 0) { red[wid * 2] = s1; red[wid * 2 + 1] = s2; }
  __syncthreads();
  if (t == 0) {
    float S = 0.f, SS = 0.f;
    for (int w = 0; w < 8; w++) { S += red[w * 2]; SS += red[w * 2 + 1]; }
    float mu = S / 512.f;
    float var = SS / 512.f - mu * mu;
    stats[0] = mu; stats[1] = rsqrtf(var + 1e-5f);
  }
  __syncthreads();
  xln_ws[(size_t)b * 512 + t] = (v - stats[0]) * stats[1] * ldx(g_f, t, isf) + ldx(be_f, t, isf);
}

// ---------------- kernel 6: fused FFN: hdn = gelu(xln@W1+b1) in LDS; y_acc += hdn@W2 ----------------
__global__ __launch_bounds__(512) void k_ffn12(
    const float* __restrict__ xln_ws, const void* __restrict__ W1, const void* __restrict__ b1,
    const void* __restrict__ W2, float* __restrict__ y_acc, const int* __restrict__ flag) {
  int isf = flag[0];
  int jb = blockIdx.x, b = blockIdx.y, t = threadIdx.x;
  __shared__ float xl[512];
  __shared__ float hl[512];
  xl[t] = xln_ws[(size_t)b * 512 + t];
  __syncthreads();
  int j = jb * 512 + t;
  float a0 = 0.f, a1 = 0.f, a2 = 0.f, a3 = 0.f;
  if (isf) {
    const float* wp = (const float*)W1 + j;
    #pragma unroll 2
    for (int c = 0; c < 512; c += 4) {
      a0 += xl[c]     * wp[(size_t)c * 2048];
      a1 += xl[c + 1] * wp[(size_t)(c + 1) * 2048];
      a2 += xl[c + 2] * wp[(size_t)(c + 2) * 2048];
      a3 += xl[c + 3] * wp[(size_t)(c + 3) * 2048];
    }
  } else {
    const u16* wp = (const u16*)W1 + j;
    #pragma unroll 2
    for (int c = 0; c < 512; c += 4) {
      a0 += xl[c]     * b2f(wp[(size_t)c * 2048]);
      a1 += xl[c + 1] * b2f(wp[(size_t)(c + 1) * 2048]);
      a2 += xl[c + 2] * b2f(wp[(size_t)(c + 2) * 2048]);
      a3 += xl[c + 3] * b2f(wp[(size_t)(c + 3) * 2048]);
    }
  }
  float acc = (a0 + a1) + (a2 + a3) + ldx(b1, j, isf);
  hl[t] = 0.5f * acc * (1.0f + erff(acc * 0.70710678118654752f));
  __syncthreads();
  float s0 = 0.f, s1 = 0.f, s2 = 0.f, s3 = 0.f;
  if (isf) {
    const float* wp = (const float*)W2 + (size_t)jb * 512 * 512 + t;
    #pragma unroll 2
    for (int c = 0; c < 512; c += 4) {
      s0 += hl[c]     * wp[(size_t)c * 512];
      s1 += hl[c + 1] * wp[(size_t)(c + 1) * 512];
      s2 += hl[c + 2] * wp[(size_t)(c + 2) * 512];
      s3 += hl[c + 3] * wp[(size_t)(c + 3) * 512];
    }
  } else {
    const u16* wp = (const u16*)W2 + (size_t)jb * 512 * 512 + t;
    #pragma unroll 2
    for (int c = 0; c < 512; c += 4) {
      s0 += hl[c]     * b2f(wp[(size_t)c * 512]);
      s1 += hl[c + 1] * b2f(wp[(size_t)(c + 1) * 512]);
      s2 += hl[c + 2] * b2f(wp[(size_t)(c + 2) * 512]);
      s3 += hl[c + 3] * b2f(wp[(size_t)(c + 3) * 512]);
    }
  }
  atomicAdd(y_acc + (size_t)b * 512 + t, (s0 + s1) + (s2 + s3));
}

// ---------------- kernel 7: out = cast(y_acc + b2 + xrow) ----------------
__global__ __launch_bounds__(512) void k_final(
    const float* __restrict__ y_acc, const void* __restrict__ b2v,
    const float* __restrict__ xrow_ws, void* __restrict__ out,
    const int* __restrict__ flag) {
  int isf = flag[0];
  int b = blockIdx.x, t = threadIdx.x;
  float v = y_acc[(size_t)b * 512 + t] + ldx(b2v, t, isf) + xrow_ws[(size_t)b * 512 + t];
  if (isf) ((float*)out)[b * 512 + t] = v;
  else     ((u16*)out)[b * 512 + t] = f2b(v);
}

extern "C" void kernel_launch(void* const* d_in, const int* in_sizes, int n_in,
                              void* d_out, int out_size, void* d_ws, size_t ws_size,
                              hipStream_t stream) {
  const void* query = d_in[0];
  const void* mem   = d_in[1];
  const void* ior   = d_in[2];
  const void* W_in  = d_in[3];
  const void* b_in  = d_in[4];
  const void* g_in  = d_in[5];
  const void* be_in = d_in[6];
  const void* Wq    = d_in[7];
  const void* bq    = d_in[8];
  const void* Wkv   = d_in[9];
  const void* bkv   = d_in[10];
  const void* W1    = d_in[11];
  const void* b1    = d_in[12];
  const void* W2    = d_in[13];
  const void* b2v   = d_in[14];
  const void* g_q   = d_in[15];
  const void* be_q  = d_in[16];
  const void* g_f   = d_in[17];
  const void* be_f  = d_in[18];

  // ws layout (total 1,646,848 B). Region [528640,1052928) is time-shared:
  //   guT (k_qprep_b -> k_main) overlays {y_acc, xrow, xln} which are written only
  //   after k_main completes (y_acc zeroed inside k_mid).
  char* ws = (char*)d_ws;
  int*   flag   = (int*)ws;                      // [0,256)
  float* S0_g   = (float*)(ws + 256);            // 1024
  float* Gsum_g = (float*)(ws + 1280);           // 1024
  float* A_g    = (float*)(ws + 2304);           // 1024
  float* M_g    = (float*)(ws + 3328);           // 1024
  float* R_g    = (float*)(ws + 4352);           // 524288
  u16*   guT    = (u16*)(ws + 528640);           // 524288 (overlay)
  float* y_acc  = (float*)(ws + 528640);         // 65536
  float* xrow_ws= (float*)(ws + 594176);         // 65536
  float* xln_ws = (float*)(ws + 659712);         // 65536
  u16*   WTf    = (u16*)(ws + 1052928);          // 524288 (fragment-ordered B)
  float* P1     = (float*)(ws + 1577216);        // 2048
  float* P2     = (float*)(ws + 1579264);        // 2048
  float* qr_ws  = (float*)(ws + 1581312);        // 65536

  hipMemsetAsync(ws + 256, 0, 528384, stream);   // zero S0, Gsum, A, M, R
  k_detect<<<dim3(1), dim3(64), 0, stream>>>(query, flag);
  k_makeB<<<dim3(64), dim3(256), 0, stream>>>(W_in, WTf, flag);
  k_prep2<<<dim3(16), dim3(512), 0, stream>>>(Wkv, g_in, be_in, P1, P2, flag);
  k_qprep_a<<<dim3(32, 4), dim3(256), 0, stream>>>(query, Wq, bq, g_q, be_q, qr_ws, flag);
  k_qprep_b<<<dim3(32, 4), dim3(256), 0, stream>>>(qr_ws, Wkv, bkv, g_in, be_in,
                                                   guT, Gsum_g, S0_g, flag);
  k_main<<<dim3(16, 32), dim3(512), 0, stream>>>(mem, WTf, b_in, ior, guT, Gsum_g, S0_g,
                                                 R_g, A_g, M_g, flag);
  k_mid<<<dim3(32), dim3(512), 0, stream>>>(R_g, A_g, M_g, P1, P2, Wkv, bkv, g_in,
                                            query, g_f, be_f, xrow_ws, xln_ws, y_acc, flag);
  k_ffn12<<<dim3(4, 32), dim3(512), 0, stream>>>(xln_ws, W1, b1, W2, y_acc, flag);
  k_final<<<dim3(32), dim3(512), 0, stream>>>(y_acc, b2v, xrow_ws, d_out, flag);
}

// Round 7
// 761.731 us; speedup vs baseline: 1.2322x; 1.0649x over previous
//
#include <hip/hip_runtime.h>
#include <hip/hip_bf16.h>
#include <math.h>

typedef unsigned short u16;
typedef __bf16 bf16x8 __attribute__((ext_vector_type(8)));
typedef float f32x4 __attribute__((ext_vector_type(4)));

__device__ __forceinline__ float b2f(u16 u) {
  union { unsigned int i; float f; } v; v.i = ((unsigned int)u) << 16; return v.f;
}
__device__ __forceinline__ u16 f2b(float f) {
  union { float f; unsigned int i; } v; v.f = f;
  unsigned int x = v.i;
  return (u16)((x + 0x7fffu + ((x >> 16) & 1u)) >> 16);
}
// dual-dtype scalar load: isf=1 -> f32, isf=0 -> bf16
__device__ __forceinline__ float ldx(const void* p, size_t i, int isf) {
  return isf ? ((const float*)p)[i] : b2f(((const u16*)p)[i]);
}

// ---------------- kernel 0: dtype detect (f32 vs bf16) ----------------
__global__ void k_detect(const void* __restrict__ query, int* __restrict__ flag) {
  int t = threadIdx.x;  // 64 threads
  float v = ((const float*)query)[t];
  int ok = (v == v && fabsf(v) < 100.f && fabsf(v) > 1e-4f) ? 1 : 0;
  unsigned long long m = __ballot(ok);
  if (t == 0) flag[0] = (__popcll(m) >= 32) ? 1 : 0;
}

// ---------------- kernel 1: W_in (512x512) -> WTf, MFMA-FRAGMENT order ----------------
// WTf u16 index: ((jb*16 + ks)*16 + l)*32 + q*8 + r   (jb=j>>4, l=j&15, ks=k>>5,
// q=(k>>3)&3, r=k&7). A wave's B-fragment load for (jb,ks) is 64 lanes x 16B
// CONTIGUOUS (1KB) -> perfectly coalesced L2 hit; no LDS staging needed.
__global__ __launch_bounds__(256) void k_makeB(const void* __restrict__ Win,
                                               u16* __restrict__ WTf,
                                               const int* __restrict__ flag) {
  int isf = flag[0];
  int t = threadIdx.x;
  int bx = blockIdx.x & 7, by = blockIdx.x >> 3;   // bx: k-tile (64 k), by: j-tile (64 j)
  int k0 = bx * 64, j0 = by * 64;
  __shared__ float tile[64][65];                    // [k_local][j_local], +1 pad
  #pragma unroll
  for (int kx = 0; kx < 16; kx++) {
    int idx = t + 256 * kx;
    int kl = idx >> 6, jl = idx & 63;               // coalesced over jl
    tile[kl][jl] = ldx(Win, (size_t)(k0 + kl) * 512 + (j0 + jl), isf);
  }
  __syncthreads();
  #pragma unroll
  for (int i = 0; i < 2; i++) {
    int chunk = i * 256 + t;                        // consecutive lanes -> consecutive dst
    int q  = chunk & 3;
    int l  = (chunk >> 2) & 15;
    int ksL = (chunk >> 6) & 1;
    int jbL = (chunk >> 7) & 3;
    int j_local = jbL * 16 + l;
    int k_local = ksL * 32 + q * 8;
    union { u16 h[8]; uint4 u; } pk;
    #pragma unroll
    for (int r = 0; r < 8; r++) pk.h[r] = f2b(tile[k_local + r][j_local]);
    int jb = by * 4 + jbL, ks = bx * 2 + ksL;
    *(uint4*)(WTf + ((size_t)(jb * 16 + ks) * 16 + l) * 32 + q * 8) = pk.u;
  }
}

// ---------------- kernel 2: P1[j]=sum_c g_in[c]*Wv[c][j], P2[j]=sum_c be_in[c]*Wv[c][j] ----------------
__global__ __launch_bounds__(512) void k_prep2(const void* __restrict__ Wkv,
                                               const void* __restrict__ g_in,
                                               const void* __restrict__ be_in,
                                               float* __restrict__ P1, float* __restrict__ P2,
                                               const int* __restrict__ flag) {
  int isf = flag[0];
  int blk = blockIdx.x;            // 16 blocks x 32 j
  int t = threadIdx.x;
  int jj = t & 31, cg = t >> 5;    // 16 c-groups of 32
  int j = blk * 32 + jj;
  float p1 = 0.f, p2 = 0.f;
  for (int cc = 0; cc < 32; cc++) {
    int c = cg * 32 + cc;
    float wv = ldx(Wkv, (size_t)c * 1024 + 512 + j, isf);
    p1 += ldx(g_in, c, isf) * wv;
    p2 += ldx(be_in, c, isf) * wv;
  }
  __shared__ float red[1024];
  red[t * 2] = p1; red[t * 2 + 1] = p2;
  __syncthreads();
  if (t < 32) {
    float s1 = 0.f, s2 = 0.f;
    for (int g2 = 0; g2 < 16; g2++) { s1 += red[(g2 * 32 + t) * 2]; s2 += red[(g2 * 32 + t) * 2 + 1]; }
    P1[blk * 32 + t] = s1;
    P2[blk * 32 + t] = s2;
  }
}

// ---------------- kernel 3a: qr = LN(query) @ Wq + bq ----------------
__global__ __launch_bounds__(256) void k_qprep_a(
    const void* __restrict__ query, const void* __restrict__ Wq, const void* __restrict__ bq,
    const void* __restrict__ g_q, const void* __restrict__ be_q,
    float* __restrict__ qr_ws, const int* __restrict__ flag) {
  int isf = flag[0];
  int b = blockIdx.x, jq = blockIdx.y, t = threadIdx.x;
  __shared__ float qf[512];
  __shared__ float red[8];
  __shared__ float stats[2];

  float s = 0.f, ss = 0.f;
  for (int k = 0; k < 2; k++) {
    int c = t + 256 * k;
    float v = ldx(query, (size_t)b * 512 + c, isf);
    qf[c] = v; s += v; ss += v * v;
  }
  for (int off = 32; off; off >>= 1) { s += __shfl_xor(s, off); ss += __shfl_xor(ss, off); }
  int wid = t >> 6, lane = t & 63;
  if (lane == 0) { red[wid * 2] = s; red[wid * 2 + 1] = ss; }
  __syncthreads();
  if (t == 0) {
    float S = 0.f, SS = 0.f;
    for (int w = 0; w < 4; w++) { S += red[w * 2]; SS += red[w * 2 + 1]; }
    float mu = S / 512.f;
    float var = SS / 512.f - mu * mu;
    stats[0] = mu; stats[1] = rsqrtf(var + 1e-5f);
  }
  __syncthreads();
  float mu = stats[0], rstd = stats[1];
  for (int k = 0; k < 2; k++) {
    int c = t + 256 * k;
    qf[c] = (qf[c] - mu) * rstd * ldx(g_q, c, isf) + ldx(be_q, c, isf);
  }
  __syncthreads();
  int jl = t >> 1, half = t & 1;
  int j = jq * 128 + jl;
  const float* qh = qf + half * 256;
  float a0 = 0.f, a1 = 0.f, a2 = 0.f, a3 = 0.f;
  if (isf) {
    const float* wp = (const float*)Wq + (size_t)(half * 256) * 512 + j;
    #pragma unroll 2
    for (int cc = 0; cc < 256; cc += 4) {
      a0 += qh[cc]     * wp[(size_t)cc * 512];
      a1 += qh[cc + 1] * wp[(size_t)(cc + 1) * 512];
      a2 += qh[cc + 2] * wp[(size_t)(cc + 2) * 512];
      a3 += qh[cc + 3] * wp[(size_t)(cc + 3) * 512];
    }
  } else {
    const u16* wp = (const u16*)Wq + (size_t)(half * 256) * 512 + j;
    #pragma unroll 2
    for (int cc = 0; cc < 256; cc += 4) {
      a0 += qh[cc]     * b2f(wp[(size_t)cc * 512]);
      a1 += qh[cc + 1] * b2f(wp[(size_t)(cc + 1) * 512]);
      a2 += qh[cc + 2] * b2f(wp[(size_t)(cc + 2) * 512]);
      a3 += qh[cc + 3] * b2f(wp[(size_t)(cc + 3) * 512]);
    }
  }
  float acc = (a0 + a1) + (a2 + a3);
  acc += __shfl_xor(acc, 1);
  if (half == 0) qr_ws[(size_t)b * 512 + j] = acc + ldx(bq, j, isf);
}

// ---------------- kernel 3b: u -> guT (bf16 [b][16][512]), Gsum, S0 (=BeU + c0) ----------------
__global__ __launch_bounds__(256) void k_qprep_b(
    const float* __restrict__ qr_ws, const void* __restrict__ Wkv, const void* __restrict__ bkv,
    const void* __restrict__ g_in, const void* __restrict__ be_in,
    u16* __restrict__ guT, float* __restrict__ Gsum_g, float* __restrict__ S0_g,
    const int* __restrict__ flag) {
  int isf = flag[0];
  int b = blockIdx.x, cq = blockIdx.y, t = threadIdx.x;   // cq: 4 c-quarters of 128
  __shared__ float qrl[512];
  __shared__ float ul[128 * 8];
  qrl[t] = qr_ws[(size_t)b * 512 + t];
  qrl[t + 256] = qr_ws[(size_t)b * 512 + t + 256];
  __syncthreads();
  #pragma unroll
  for (int e4 = 0; e4 < 4; e4++) {
    int e = t + 256 * e4;
    int cl = e >> 3, n = e & 7;
    int c = cq * 128 + cl;
    const float* qp = qrl + n * 64;
    float acc = 0.f;
    if (isf) {
      const float* wp = (const float*)Wkv + (size_t)c * 1024 + n * 64;
      #pragma unroll 8
      for (int d = 0; d < 64; d++) acc += wp[d] * qp[d];
    } else {
      const u16* wp = (const u16*)Wkv + (size_t)c * 1024 + n * 64;
      #pragma unroll 8
      for (int d = 0; d < 64; d++) acc += b2f(wp[d]) * qp[d];
    }
    ul[cl * 8 + n] = acc;
  }
  __syncthreads();
  #pragma unroll
  for (int e4 = 0; e4 < 4; e4++) {
    int e = t + 256 * e4;
    int cl = e >> 3, n = e & 7;
    int c = cq * 128 + cl;
    guT[((size_t)b * 16 + n) * 512 + c] = f2b(ldx(g_in, c, isf) * ul[cl * 8 + n]);
    guT[((size_t)b * 16 + 8 + n) * 512 + c] = 0;
  }
  if (t < 64) {
    int n = t >> 3, seg = t & 7;
    float gs = 0.f, s0 = 0.f;
    for (int k = 0; k < 16; k++) {
      int cl = seg * 16 + k;
      int c = cq * 128 + cl;
      float uu = ul[cl * 8 + n];
      gs += ldx(g_in, c, isf) * uu;
      s0 += ldx(be_in, c, isf) * uu;
    }
    gs += __shfl_xor(gs, 1); s0 += __shfl_xor(s0, 1);
    gs += __shfl_xor(gs, 2); s0 += __shfl_xor(s0, 2);
    gs += __shfl_xor(gs, 4); s0 += __shfl_xor(s0, 4);
    if (seg == 0) {
      atomicAdd(Gsum_g + b * 8 + n, gs);
      atomicAdd(S0_g + b * 8 + n, s0);
    }
  }
  if (cq == 0 && t < 8) {
    float acc = 0.f;
    for (int d = 0; d < 64; d++) acc += ldx(bkv, t * 64 + d, isf) * qrl[t * 64 + d];
    atomicAdd(S0_g + b * 8 + t, acc);
  }
}

// ---------------- kernel 4: fused m-GEMM + relu + LN-stats + MFMA-scores + R accumulation ----------------
// v7 = round-6 epilogue + whole-tile A staging + BARRIER-FREE K-loop:
//   - A (64x512) staged once per tile: bulk coalesced burst -> XOR-swizzled bf16 LDS
//     (structure verified correct in round 3). HBM latency paid once per tile, not 16x.
//   - B fragments from fragment-ordered WTf (round-6 verified): 4 coalesced 1KB
//     wave-loads per K-step, straight to registers.
//   - K-loop: ZERO barriers (A_lds read-only, B in regs) -> waves drift, TLP hides
//     B L2 latency. Barriers: ~39/tile-loop -> 8/tile.
#define LDSWZ(row, byte_in_row) ((((row) << 10) + (byte_in_row)) ^ (((row) & 7) << 4))
__global__ __launch_bounds__(512) void k_main(
    const void* __restrict__ mem, const u16* __restrict__ WTf, const void* __restrict__ b_in,
    const void* __restrict__ ior, const u16* __restrict__ guT,
    const float* __restrict__ Gsum_g, const float* __restrict__ S0_g,
    float* __restrict__ R_g, float* __restrict__ A_g, float* __restrict__ M_g,
    const int* __restrict__ flag) {
  int isf = flag[0];
  int blk = blockIdx.x;           // 0..15 (4 row-tiles each)
  int b   = blockIdx.y;           // 0..31
  int t = threadIdx.x;
  int w = t >> 6, lane = t & 63;
  int l15 = lane & 15, q = lane >> 4;

  // LDS map (68096 B):
  //   K-loop:   A_lds [0,65536) = [64 rows][512 k] bf16, XOR-swizzled rows
  //   epilogue (overlays A_lds): rowred [0,4096) (consumed before y), y slices
  //             (wave w at w*8192, [64][64] bf16 swizzled; T_part overlays first 2KB)
  //   persistent: mu_rstd [65536,66048), a_lds [66048,68096)
  __shared__ __align__(16) char smem[68096];
  float* rowred  = (float*)smem;
  float* mu_rstd = (float*)(smem + 65536);
  float* a_lds   = (float*)(smem + 66048);
  char*  ymine   = smem + w * 8192;

  float binv[4];
  #pragma unroll
  for (int j = 0; j < 4; j++) binv[j] = ldx(b_in, w * 64 + j * 16 + l15, isf);
  // gu B-fragments for the score MFMA (tile-invariant)
  bf16x8 gfrag0 = *(const bf16x8*)(guT + ((size_t)b * 16 + l15) * 512 + w * 64 + q * 8);
  bf16x8 gfrag1 = *(const bf16x8*)(guT + ((size_t)b * 16 + l15) * 512 + w * 64 + 32 + q * 8);
  float Gs  = Gsum_g[b * 8 + (t & 7)];
  float S0v = S0_g[b * 8 + (t & 7)];
  // B fragment base: wave w owns jb = w*4..w*4+3; frag (j,ks) at wb + j*8192 + ks*512
  const u16* wb = WTf + (size_t)w * 32768 + l15 * 32 + q * 8;

  float am_acc = 0.f, mm_acc = 0.f;

  for (int tile = 0; tile < 4; tile++) {
    int row0 = (blk * 4 + tile) * 64;
    size_t memBase = ((size_t)b * 4096 + row0) * 512;

    // ---- A burst: 64x512 global -> swizzled bf16 LDS (coalesced; 2 batches f32) ----
    if (isf) {
      #pragma unroll
      for (int h = 0; h < 2; h++) {
        float4 va[8];
        #pragma unroll
        for (int p = 0; p < 8; p++) {
          int i16 = (h * 8 + p) * 512 + t;
          va[p] = *(const float4*)((const float*)mem + memBase + (size_t)i16 * 4);
        }
        #pragma unroll
        for (int p = 0; p < 8; p++) {
          int i16 = (h * 8 + p) * 512 + t;
          int row = i16 >> 7;
          union { u16 hh[4]; uint2 u; } pk;
          pk.hh[0] = f2b(va[p].x); pk.hh[1] = f2b(va[p].y);
          pk.hh[2] = f2b(va[p].z); pk.hh[3] = f2b(va[p].w);
          *(uint2*)(smem + LDSWZ(row, (i16 & 127) << 3)) = pk.u;
        }
      }
    } else {
      uint4 vb[8];
      #pragma unroll
      for (int p = 0; p < 8; p++) {
        int i16 = p * 512 + t;
        vb[p] = *(const uint4*)((const u16*)mem + memBase + (size_t)i16 * 8);
      }
      #pragma unroll
      for (int p = 0; p < 8; p++) {
        int i16 = p * 512 + t;
        int row = i16 >> 6;
        *(uint4*)(smem + LDSWZ(row, (i16 & 63) << 4)) = vb[p];
      }
    }
    __syncthreads();   // B1: A_lds ready

    f32x4 acc[4][4];
    #pragma unroll
    for (int i = 0; i < 4; i++)
      #pragma unroll
      for (int j = 0; j < 4; j++) { acc[i][j][0]=0.f; acc[i][j][1]=0.f; acc[i][j][2]=0.f; acc[i][j][3]=0.f; }

    // ---- barrier-free K-loop: A from swizzled LDS, B coalesced from WTf (L2) ----
    #pragma unroll 4
    for (int ks = 0; ks < 16; ks++) {
      bf16x8 aF[4], bF[4];
      #pragma unroll
      for (int j = 0; j < 4; j++)
        bF[j] = *(const bf16x8*)(wb + j * 8192 + ks * 512);
      #pragma unroll
      for (int i = 0; i < 4; i++) {
        int row = i * 16 + l15;
        aF[i] = *(const bf16x8*)(smem + LDSWZ(row, (ks << 6) + (q << 4)));
      }
      #pragma unroll
      for (int i = 0; i < 4; i++)
        #pragma unroll
        for (int j = 0; j < 4; j++)
          acc[i][j] = __builtin_amdgcn_mfma_f32_16x16x32_bf16(aF[i], bF[j], acc[i][j], 0, 0, 0);
    }
    __syncthreads();   // B2: all A_lds reads done; epilogue overlay allowed

    // bias + relu (acc stays PRE-LN y)
    #pragma unroll
    for (int i = 0; i < 4; i++)
      #pragma unroll
      for (int j = 0; j < 4; j++)
        #pragma unroll
        for (int r = 0; r < 4; r++) {
          float v = acc[i][j][r] + binv[j];
          acc[i][j][r] = v > 0.f ? v : 0.f;
        }
    // LN stats partials (per-wave 64-col slices)
    #pragma unroll
    for (int i = 0; i < 4; i++)
      #pragma unroll
      for (int r = 0; r < 4; r++) {
        float s  = acc[i][0][r] + acc[i][1][r] + acc[i][2][r] + acc[i][3][r];
        float ss = acc[i][0][r]*acc[i][0][r] + acc[i][1][r]*acc[i][1][r]
                 + acc[i][2][r]*acc[i][2][r] + acc[i][3][r]*acc[i][3][r];
        #pragma unroll
        for (int m = 1; m < 16; m <<= 1) { s += __shfl_xor(s, m); ss += __shfl_xor(ss, m); }
        if (l15 == 0) {
          int row = i * 16 + q * 4 + r;
          rowred[(w * 64 + row) * 2]     = s;
          rowred[(w * 64 + row) * 2 + 1] = ss;
        }
      }
    __syncthreads();   // B3
    if (t < 64) {
      float S = 0.f, SS = 0.f;
      for (int w2 = 0; w2 < 8; w2++) { S += rowred[(w2 * 64 + t) * 2]; SS += rowred[(w2 * 64 + t) * 2 + 1]; }
      float mu = S / 512.f;
      float var = SS / 512.f - mu * mu;
      mu_rstd[t * 2] = mu;
      mu_rstd[t * 2 + 1] = rsqrtf(var + 1e-5f);
    }
    __syncthreads();   // B4: rowred consumed; y writes may overwrite [0,65536)

    // write this wave's y-slice [64][64] bf16, XOR-swizzled
    #pragma unroll
    for (int i = 0; i < 4; i++)
      #pragma unroll
      for (int j = 0; j < 4; j++)
        #pragma unroll
        for (int r = 0; r < 4; r++) {
          int row = i * 16 + q * 4 + r;
          int byo = (row * 128 + j * 32 + l15 * 2) ^ ((row & 7) << 4);
          *(u16*)(ymine + byo) = f2b(acc[i][j][r]);
        }
    __syncthreads();   // B5

    // scores: T_partial = y_slice @ gu  (8 MFMAs per wave, K = own 64 cols)
    f32x4 Tacc[4];
    #pragma unroll
    for (int rt = 0; rt < 4; rt++) { Tacc[rt][0]=0.f; Tacc[rt][1]=0.f; Tacc[rt][2]=0.f; Tacc[rt][3]=0.f; }
    #pragma unroll
    for (int rt = 0; rt < 4; rt++) {
      int row = rt * 16 + l15;
      int sw = (row & 7) << 4;
      bf16x8 ay0 = *(const bf16x8*)(ymine + ((row * 128 + q * 16) ^ sw));
      Tacc[rt] = __builtin_amdgcn_mfma_f32_16x16x32_bf16(ay0, gfrag0, Tacc[rt], 0, 0, 0);
      bf16x8 ay1 = *(const bf16x8*)(ymine + ((row * 128 + 64 + q * 16) ^ sw));
      Tacc[rt] = __builtin_amdgcn_mfma_f32_16x16x32_bf16(ay1, gfrag1, Tacc[rt], 0, 0, 0);
    }
    // T_part [64][8] f32 overlays own slice's first 2KB (own y already consumed)
    {
      float* tp = (float*)ymine;
      if (l15 < 8) {
        #pragma unroll
        for (int rt = 0; rt < 4; rt++)
          #pragma unroll
          for (int r = 0; r < 4; r++)
            tp[(rt * 16 + q * 4 + r) * 8 + l15] = Tacc[rt][r];
      }
    }
    __syncthreads();   // B6: T_parts visible

    // a-phase: combine wave partials, deferred-LN affine, *scale*ior; accumulate A/M
    {
      int row = t >> 3, n = t & 7;
      float Tsum = 0.f;
      #pragma unroll
      for (int w2 = 0; w2 < 8; w2++)
        Tsum += ((const float*)(smem + w2 * 8192))[row * 8 + n];
      float mu = mu_rstd[row * 2], rstd = mu_rstd[row * 2 + 1];
      float spre = rstd * (Tsum - mu * Gs) + S0v;
      float aval = spre * 0.125f * ldx(ior, ((size_t)b * 8 + n) * 4096 + row0 + row, isf);
      am_acc += aval;
      mm_acc += aval * mu * rstd;
      a_lds[row * 8 + n] = aval * rstd;   // a' = a*rstd for the R contraction
    }
    __syncthreads();   // B7: a_lds ready (y region no longer read after this)

    // R[n][col] contribution of this tile (per-tile flush)
    float rv[4][8];
    #pragma unroll
    for (int j = 0; j < 4; j++)
      #pragma unroll
      for (int n = 0; n < 8; n++) rv[j][n] = 0.f;
    #pragma unroll
    for (int i = 0; i < 4; i++)
      #pragma unroll
      for (int r = 0; r < 4; r++) {
        int row = i * 16 + q * 4 + r;
        const float* ap = a_lds + row * 8;
        float a0=ap[0],a1=ap[1],a2=ap[2],a3=ap[3],a4=ap[4],a5=ap[5],a6=ap[6],a7=ap[7];
        #pragma unroll
        for (int j = 0; j < 4; j++) {
          float m = acc[i][j][r];
          rv[j][0] += m*a0; rv[j][1] += m*a1; rv[j][2] += m*a2; rv[j][3] += m*a3;
          rv[j][4] += m*a4; rv[j][5] += m*a5; rv[j][6] += m*a6; rv[j][7] += m*a7;
        }
      }
    #pragma unroll
    for (int j = 0; j < 4; j++)
      #pragma unroll
      for (int n = 0; n < 8; n++) {
        float v = rv[j][n];
        v += __shfl_xor(v, 16);
        v += __shfl_xor(v, 32);
        rv[j][n] = v;
      }
    if (q == 0) {
      #pragma unroll
      for (int j = 0; j < 4; j++)
        #pragma unroll
        for (int n = 0; n < 8; n++)
          atomicAdd(R_g + ((size_t)b * 8 + n) * 512 + (w * 64 + j * 16 + l15), rv[j][n]);
    }
    // next tile's burst writes [0,65536): y region last read before B7; a_lds not
    // touched by burst -> no extra barrier needed (barrier B1 follows the burst).
  }

  // ---- A/M flush (accumulated across tiles) ----
  am_acc += __shfl_xor(am_acc, 8);
  am_acc += __shfl_xor(am_acc, 16);
  am_acc += __shfl_xor(am_acc, 32);
  mm_acc += __shfl_xor(mm_acc, 8);
  mm_acc += __shfl_xor(mm_acc, 16);
  mm_acc += __shfl_xor(mm_acc, 32);
  if (lane < 8) {
    atomicAdd(A_g + b * 8 + lane, am_acc);
    atomicAdd(M_g + b * 8 + lane, mm_acc);
  }
}

// ---------------- kernel 5: x = r@Wv + A*bv + query ; LN -> xln ; zero y_acc ----------------
__global__ __launch_bounds__(512) void k_mid(
    const float* __restrict__ R_g, const float* __restrict__ A_g, const float* __restrict__ M_g,
    const float* __restrict__ P1, const float* __restrict__ P2,
    const void* __restrict__ Wkv, const void* __restrict__ bkv, const void* __restrict__ g_in,
    const void* __restrict__ query, const void* __restrict__ g_f, const void* __restrict__ be_f,
    float* __restrict__ xrow_ws, float* __restrict__ xln_ws, float* __restrict__ y_acc,
    const int* __restrict__ flag) {
  int isf = flag[0];
  int b = blockIdx.x, t = threadIdx.x;
  __shared__ float Rl[4096];    // g[c]*R[b][n][c]
  __shared__ float red[16];
  __shared__ float stats[2];
  #pragma unroll
  for (int k = 0; k < 8; k++) {
    int e = t + 512 * k;
    Rl[e] = R_g[(size_t)b * 4096 + e] * ldx(g_in, e & 511, isf);
  }
  __syncthreads();
  int j = t, n = t >> 6;
  float Av = A_g[b * 8 + n], Mv = M_g[b * 8 + n];
  float base = Av * ldx(bkv, 512 + j, isf) - Mv * P1[j] + Av * P2[j];
  const float* rl = Rl + n * 512;
  float a0 = 0.f, a1 = 0.f, a2 = 0.f, a3 = 0.f;
  if (isf) {
    const float* wv = (const float*)Wkv + 512 + j;
    #pragma unroll 2
    for (int c = 0; c < 512; c += 4) {
      a0 += rl[c]     * wv[(size_t)c * 1024];
      a1 += rl[c + 1] * wv[(size_t)(c + 1) * 1024];
      a2 += rl[c + 2] * wv[(size_t)(c + 2) * 1024];
      a3 += rl[c + 3] * wv[(size_t)(c + 3) * 1024];
    }
  } else {
    const u16* wv = (const u16*)Wkv + 512 + j;
    #pragma unroll 2
    for (int c = 0; c < 512; c += 4) {
      a0 += rl[c]     * b2f(wv[(size_t)c * 1024]);
      a1 += rl[c + 1] * b2f(wv[(size_t)(c + 1) * 1024]);
      a2 += rl[c + 2] * b2f(wv[(size_t)(c + 2) * 1024]);
      a3 += rl[c + 3] * b2f(wv[(size_t)(c + 3) * 1024]);
    }
  }
  float v = base + (a0 + a1) + (a2 + a3) + ldx(query, (size_t)b * 512 + t, isf);
  xrow_ws[(size_t)b * 512 + t] = v;
  y_acc[(size_t)b * 512 + t] = 0.f;   // zero here (region was overlaid by guT earlier)
  float s1 = v, s2 = v * v;
  for (int off = 32; off; off >>= 1) { s1 += __shfl_xor(s1, off); s2 += __shfl_xor(s2, off); }
  int wid = t >> 6, lane = t & 63;
  if (lane == 0) { red[wid * 2] = s1; red[wid * 2 + 1] = s2; }
  __syncthreads();
  if (t == 0) {
    float S = 0.f, SS = 0.f;
    for (int w = 0; w < 8; w++) { S += red[w * 2]; SS += red[w * 2 + 1]; }
    float mu = S / 512.f;
    float var = SS / 512.f - mu * mu;
    stats[0] = mu; stats[1] = rsqrtf(var + 1e-5f);
  }
  __syncthreads();
  xln_ws[(size_t)b * 512 + t] = (v - stats[0]) * stats[1] * ldx(g_f, t, isf) + ldx(be_f, t, isf);
}

// ---------------- kernel 6: fused FFN: hdn = gelu(xln@W1+b1) in LDS; y_acc += hdn@W2 ----------------
__global__ __launch_bounds__(512) void k_ffn12(
    const float* __restrict__ xln_ws, const void* __restrict__ W1, const void* __restrict__ b1,
    const void* __restrict__ W2, float* __restrict__ y_acc, const int* __restrict__ flag) {
  int isf = flag[0];
  int jb = blockIdx.x, b = blockIdx.y, t = threadIdx.x;
  __shared__ float xl[512];
  __shared__ float hl[512];
  xl[t] = xln_ws[(size_t)b * 512 + t];
  __syncthreads();
  int j = jb * 512 + t;
  float a0 = 0.f, a1 = 0.f, a2 = 0.f, a3 = 0.f;
  if (isf) {
    const float* wp = (const float*)W1 + j;
    #pragma unroll 2
    for (int c = 0; c < 512; c += 4) {
      a0 += xl[c]     * wp[(size_t)c * 2048];
      a1 += xl[c + 1] * wp[(size_t)(c + 1) * 2048];
      a2 += xl[c + 2] * wp[(size_t)(c + 2) * 2048];
      a3 += xl[c + 3] * wp[(size_t)(c + 3) * 2048];
    }
  } else {
    const u16* wp = (const u16*)W1 + j;
    #pragma unroll 2
    for (int c = 0; c < 512; c += 4) {
      a0 += xl[c]     * b2f(wp[(size_t)c * 2048]);
      a1 += xl[c + 1] * b2f(wp[(size_t)(c + 1) * 2048]);
      a2 += xl[c + 2] * b2f(wp[(size_t)(c + 2) * 2048]);
      a3 += xl[c + 3] * b2f(wp[(size_t)(c + 3) * 2048]);
    }
  }
  float acc = (a0 + a1) + (a2 + a3) + ldx(b1, j, isf);
  hl[t] = 0.5f * acc * (1.0f + erff(acc * 0.70710678118654752f));
  __syncthreads();
  float s0 = 0.f, s1 = 0.f, s2 = 0.f, s3 = 0.f;
  if (isf) {
    const float* wp = (const float*)W2 + (size_t)jb * 512 * 512 + t;
    #pragma unroll 2
    for (int c = 0; c < 512; c += 4) {
      s0 += hl[c]     * wp[(size_t)c * 512];
      s1 += hl[c + 1] * wp[(size_t)(c + 1) * 512];
      s2 += hl[c + 2] * wp[(size_t)(c + 2) * 512];
      s3 += hl[c + 3] * wp[(size_t)(c + 3) * 512];
    }
  } else {
    const u16* wp = (const u16*)W2 + (size_t)jb * 512 * 512 + t;
    #pragma unroll 2
    for (int c = 0; c < 512; c += 4) {
      s0 += hl[c]     * b2f(wp[(size_t)c * 512]);
      s1 += hl[c + 1] * b2f(wp[(size_t)(c + 1) * 512]);
      s2 += hl[c + 2] * b2f(wp[(size_t)(c + 2) * 512]);
      s3 += hl[c + 3] * b2f(wp[(size_t)(c + 3) * 512]);
    }
  }
  atomicAdd(y_acc + (size_t)b * 512 + t, (s0 + s1) + (s2 + s3));
}

// ---------------- kernel 7: out = cast(y_acc + b2 + xrow) ----------------
__global__ __launch_bounds__(512) void k_final(
    const float* __restrict__ y_acc, const void* __restrict__ b2v,
    const float* __restrict__ xrow_ws, void* __restrict__ out,
    const int* __restrict__ flag) {
  int isf = flag[0];
  int b = blockIdx.x, t = threadIdx.x;
  float v = y_acc[(size_t)b * 512 + t] + ldx(b2v, t, isf) + xrow_ws[(size_t)b * 512 + t];
  if (isf) ((float*)out)[b * 512 + t] = v;
  else     ((u16*)out)[b * 512 + t] = f2b(v);
}

extern "C" void kernel_launch(void* const* d_in, const int* in_sizes, int n_in,
                              void* d_out, int out_size, void* d_ws, size_t ws_size,
                              hipStream_t stream) {
  const void* query = d_in[0];
  const void* mem   = d_in[1];
  const void* ior   = d_in[2];
  const void* W_in  = d_in[3];
  const void* b_in  = d_in[4];
  const void* g_in  = d_in[5];
  const void* be_in = d_in[6];
  const void* Wq    = d_in[7];
  const void* bq    = d_in[8];
  const void* Wkv   = d_in[9];
  const void* bkv   = d_in[10];
  const void* W1    = d_in[11];
  const void* b1    = d_in[12];
  const void* W2    = d_in[13];
  const void* b2v   = d_in[14];
  const void* g_q   = d_in[15];
  const void* be_q  = d_in[16];
  const void* g_f   = d_in[17];
  const void* be_f  = d_in[18];

  // ws layout (total 1,646,848 B). Region [528640,1052928) is time-shared:
  //   guT (k_qprep_b -> k_main) overlays {y_acc, xrow, xln} which are written only
  //   after k_main completes (y_acc zeroed inside k_mid).
  char* ws = (char*)d_ws;
  int*   flag   = (int*)ws;                      // [0,256)
  float* S0_g   = (float*)(ws + 256);            // 1024
  float* Gsum_g = (float*)(ws + 1280);           // 1024
  float* A_g    = (float*)(ws + 2304);           // 1024
  float* M_g    = (float*)(ws + 3328);           // 1024
  float* R_g    = (float*)(ws + 4352);           // 524288
  u16*   guT    = (u16*)(ws + 528640);           // 524288 (overlay)
  float* y_acc  = (float*)(ws + 528640);         // 65536
  float* xrow_ws= (float*)(ws + 594176);         // 65536
  float* xln_ws = (float*)(ws + 659712);         // 65536
  u16*   WTf    = (u16*)(ws + 1052928);          // 524288 (fragment-ordered B)
  float* P1     = (float*)(ws + 1577216);        // 2048
  float* P2     = (float*)(ws + 1579264);        // 2048
  float* qr_ws  = (float*)(ws + 1581312);        // 65536

  hipMemsetAsync(ws + 256, 0, 528384, stream);   // zero S0, Gsum, A, M, R
  k_detect<<<dim3(1), dim3(64), 0, stream>>>(query, flag);
  k_makeB<<<dim3(64), dim3(256), 0, stream>>>(W_in, WTf, flag);
  k_prep2<<<dim3(16), dim3(512), 0, stream>>>(Wkv, g_in, be_in, P1, P2, flag);
  k_qprep_a<<<dim3(32, 4), dim3(256), 0, stream>>>(query, Wq, bq, g_q, be_q, qr_ws, flag);
  k_qprep_b<<<dim3(32, 4), dim3(256), 0, stream>>>(qr_ws, Wkv, bkv, g_in, be_in,
                                                   guT, Gsum_g, S0_g, flag);
  k_main<<<dim3(16, 32), dim3(512), 0, stream>>>(mem, WTf, b_in, ior, guT, Gsum_g, S0_g,
                                                 R_g, A_g, M_g, flag);
  k_mid<<<dim3(32), dim3(512), 0, stream>>>(R_g, A_g, M_g, P1, P2, Wkv, bkv, g_in,
                                            query, g_f, be_f, xrow_ws, xln_ws, y_acc, flag);
  k_ffn12<<<dim3(4, 32), dim3(512), 0, stream>>>(xln_ws, W1, b1, W2, y_acc, flag);
  k_final<<<dim3(32), dim3(512), 0, stream>>>(y_acc, b2v, xrow_ws, d_out, flag);
}

// Round 11
// 723.799 us; speedup vs baseline: 1.2968x; 1.0524x over previous
//
#include <hip/hip_runtime.h>
#include <hip/hip_bf16.h>
#include <math.h>

typedef unsigned short u16;
typedef __bf16 bf16x8 __attribute__((ext_vector_type(8)));
typedef float f32x4 __attribute__((ext_vector_type(4)));

__device__ __forceinline__ float b2f(u16 u) {
  union { unsigned int i; float f; } v; v.i = ((unsigned int)u) << 16; return v.f;
}
__device__ __forceinline__ u16 f2b(float f) {
  union { float f; unsigned int i; } v; v.f = f;
  unsigned int x = v.i;
  return (u16)((x + 0x7fffu + ((x >> 16) & 1u)) >> 16);
}
// dual-dtype scalar load: isf=1 -> f32, isf=0 -> bf16
__device__ __forceinline__ float ldx(const void* p, size_t i, int isf) {
  return isf ? ((const float*)p)[i] : b2f(((const u16*)p)[i]);
}

// ---------------- kernel 0: dtype detect (f32 vs bf16) ----------------
__global__ void k_detect(const void* __restrict__ query, int* __restrict__ flag) {
  int t = threadIdx.x;  // 64 threads
  float v = ((const float*)query)[t];
  int ok = (v == v && fabsf(v) < 100.f && fabsf(v) > 1e-4f) ? 1 : 0;
  unsigned long long m = __ballot(ok);
  if (t == 0) flag[0] = (__popcll(m) >= 32) ? 1 : 0;
}

// ---------------- kernel 1: W_in (512x512) -> WTf, MFMA-FRAGMENT order ----------------
// WTf u16 index: ((jb*16 + ks)*16 + l)*32 + q*8 + r   (jb=j>>4, l=j&15, ks=k>>5,
// q=(k>>3)&3, r=k&7). A wave's B-fragment load for (jb,ks) is 64 lanes x 16B
// CONTIGUOUS (1KB) -> perfectly coalesced L2 hit; no LDS staging needed.
__global__ __launch_bounds__(256) void k_makeB(const void* __restrict__ Win,
                                               u16* __restrict__ WTf,
                                               const int* __restrict__ flag) {
  int isf = flag[0];
  int t = threadIdx.x;
  int bx = blockIdx.x & 7, by = blockIdx.x >> 3;   // bx: k-tile (64 k), by: j-tile (64 j)
  int k0 = bx * 64, j0 = by * 64;
  __shared__ float tile[64][65];                    // [k_local][j_local], +1 pad
  #pragma unroll
  for (int kx = 0; kx < 16; kx++) {
    int idx = t + 256 * kx;
    int kl = idx >> 6, jl = idx & 63;               // coalesced over jl
    tile[kl][jl] = ldx(Win, (size_t)(k0 + kl) * 512 + (j0 + jl), isf);
  }
  __syncthreads();
  #pragma unroll
  for (int i = 0; i < 2; i++) {
    int chunk = i * 256 + t;                        // consecutive lanes -> consecutive dst
    int q  = chunk & 3;
    int l  = (chunk >> 2) & 15;
    int ksL = (chunk >> 6) & 1;
    int jbL = (chunk >> 7) & 3;
    int j_local = jbL * 16 + l;
    int k_local = ksL * 32 + q * 8;
    union { u16 h[8]; uint4 u; } pk;
    #pragma unroll
    for (int r = 0; r < 8; r++) pk.h[r] = f2b(tile[k_local + r][j_local]);
    int jb = by * 4 + jbL, ks = bx * 2 + ksL;
    *(uint4*)(WTf + ((size_t)(jb * 16 + ks) * 16 + l) * 32 + q * 8) = pk.u;
  }
}

// ---------------- kernel 2: P1[j]=sum_c g_in[c]*Wv[c][j], P2[j]=sum_c be_in[c]*Wv[c][j] ----------------
__global__ __launch_bounds__(512) void k_prep2(const void* __restrict__ Wkv,
                                               const void* __restrict__ g_in,
                                               const void* __restrict__ be_in,
                                               float* __restrict__ P1, float* __restrict__ P2,
                                               const int* __restrict__ flag) {
  int isf = flag[0];
  int blk = blockIdx.x;            // 16 blocks x 32 j
  int t = threadIdx.x;
  int jj = t & 31, cg = t >> 5;    // 16 c-groups of 32
  int j = blk * 32 + jj;
  float p1 = 0.f, p2 = 0.f;
  for (int cc = 0; cc < 32; cc++) {
    int c = cg * 32 + cc;
    float wv = ldx(Wkv, (size_t)c * 1024 + 512 + j, isf);
    p1 += ldx(g_in, c, isf) * wv;
    p2 += ldx(be_in, c, isf) * wv;
  }
  __shared__ float red[1024];
  red[t * 2] = p1; red[t * 2 + 1] = p2;
  __syncthreads();
  if (t < 32) {
    float s1 = 0.f, s2 = 0.f;
    for (int g2 = 0; g2 < 16; g2++) { s1 += red[(g2 * 32 + t) * 2]; s2 += red[(g2 * 32 + t) * 2 + 1]; }
    P1[blk * 32 + t] = s1;
    P2[blk * 32 + t] = s2;
  }
}

// ---------------- kernel 3a: qr = LN(query) @ Wq + bq ----------------
__global__ __launch_bounds__(256) void k_qprep_a(
    const void* __restrict__ query, const void* __restrict__ Wq, const void* __restrict__ bq,
    const void* __restrict__ g_q, const void* __restrict__ be_q,
    float* __restrict__ qr_ws, const int* __restrict__ flag) {
  int isf = flag[0];
  int b = blockIdx.x, jq = blockIdx.y, t = threadIdx.x;
  __shared__ float qf[512];
  __shared__ float red[8];
  __shared__ float stats[2];

  float s = 0.f, ss = 0.f;
  for (int k = 0; k < 2; k++) {
    int c = t + 256 * k;
    float v = ldx(query, (size_t)b * 512 + c, isf);
    qf[c] = v; s += v; ss += v * v;
  }
  for (int off = 32; off; off >>= 1) { s += __shfl_xor(s, off); ss += __shfl_xor(ss, off); }
  int wid = t >> 6, lane = t & 63;
  if (lane == 0) { red[wid * 2] = s; red[wid * 2 + 1] = ss; }
  __syncthreads();
  if (t == 0) {
    float S = 0.f, SS = 0.f;
    for (int w = 0; w < 4; w++) { S += red[w * 2]; SS += red[w * 2 + 1]; }
    float mu = S / 512.f;
    float var = SS / 512.f - mu * mu;
    stats[0] = mu; stats[1] = rsqrtf(var + 1e-5f);
  }
  __syncthreads();
  float mu = stats[0], rstd = stats[1];
  for (int k = 0; k < 2; k++) {
    int c = t + 256 * k;
    qf[c] = (qf[c] - mu) * rstd * ldx(g_q, c, isf) + ldx(be_q, c, isf);
  }
  __syncthreads();
  int jl = t >> 1, half = t & 1;
  int j = jq * 128 + jl;
  const float* qh = qf + half * 256;
  float a0 = 0.f, a1 = 0.f, a2 = 0.f, a3 = 0.f;
  if (isf) {
    const float* wp = (const float*)Wq + (size_t)(half * 256) * 512 + j;
    #pragma unroll 2
    for (int cc = 0; cc < 256; cc += 4) {
      a0 += qh[cc]     * wp[(size_t)cc * 512];
      a1 += qh[cc + 1] * wp[(size_t)(cc + 1) * 512];
      a2 += qh[cc + 2] * wp[(size_t)(cc + 2) * 512];
      a3 += qh[cc + 3] * wp[(size_t)(cc + 3) * 512];
    }
  } else {
    const u16* wp = (const u16*)Wq + (size_t)(half * 256) * 512 + j;
    #pragma unroll 2
    for (int cc = 0; cc < 256; cc += 4) {
      a0 += qh[cc]     * b2f(wp[(size_t)cc * 512]);
      a1 += qh[cc + 1] * b2f(wp[(size_t)(cc + 1) * 512]);
      a2 += qh[cc + 2] * b2f(wp[(size_t)(cc + 2) * 512]);
      a3 += qh[cc + 3] * b2f(wp[(size_t)(cc + 3) * 512]);
    }
  }
  float acc = (a0 + a1) + (a2 + a3);
  acc += __shfl_xor(acc, 1);
  if (half == 0) qr_ws[(size_t)b * 512 + j] = acc + ldx(bq, j, isf);
}

// ---------------- kernel 3b: u -> guT (bf16 [b][16][512]), Gsum, S0 (=BeU + c0) ----------------
__global__ __launch_bounds__(256) void k_qprep_b(
    const float* __restrict__ qr_ws, const void* __restrict__ Wkv, const void* __restrict__ bkv,
    const void* __restrict__ g_in, const void* __restrict__ be_in,
    u16* __restrict__ guT, float* __restrict__ Gsum_g, float* __restrict__ S0_g,
    const int* __restrict__ flag) {
  int isf = flag[0];
  int b = blockIdx.x, cq = blockIdx.y, t = threadIdx.x;   // cq: 4 c-quarters of 128
  __shared__ float qrl[512];
  __shared__ float ul[128 * 8];
  qrl[t] = qr_ws[(size_t)b * 512 + t];
  qrl[t + 256] = qr_ws[(size_t)b * 512 + t + 256];
  __syncthreads();
  #pragma unroll
  for (int e4 = 0; e4 < 4; e4++) {
    int e = t + 256 * e4;
    int cl = e >> 3, n = e & 7;
    int c = cq * 128 + cl;
    const float* qp = qrl + n * 64;
    float acc = 0.f;
    if (isf) {
      const float* wp = (const float*)Wkv + (size_t)c * 1024 + n * 64;
      #pragma unroll 8
      for (int d = 0; d < 64; d++) acc += wp[d] * qp[d];
    } else {
      const u16* wp = (const u16*)Wkv + (size_t)c * 1024 + n * 64;
      #pragma unroll 8
      for (int d = 0; d < 64; d++) acc += b2f(wp[d]) * qp[d];
    }
    ul[cl * 8 + n] = acc;
  }
  __syncthreads();
  #pragma unroll
  for (int e4 = 0; e4 < 4; e4++) {
    int e = t + 256 * e4;
    int cl = e >> 3, n = e & 7;
    int c = cq * 128 + cl;
    guT[((size_t)b * 16 + n) * 512 + c] = f2b(ldx(g_in, c, isf) * ul[cl * 8 + n]);
    guT[((size_t)b * 16 + 8 + n) * 512 + c] = 0;
  }
  if (t < 64) {
    int n = t >> 3, seg = t & 7;
    float gs = 0.f, s0 = 0.f;
    for (int k = 0; k < 16; k++) {
      int cl = seg * 16 + k;
      int c = cq * 128 + cl;
      float uu = ul[cl * 8 + n];
      gs += ldx(g_in, c, isf) * uu;
      s0 += ldx(be_in, c, isf) * uu;
    }
    gs += __shfl_xor(gs, 1); s0 += __shfl_xor(s0, 1);
    gs += __shfl_xor(gs, 2); s0 += __shfl_xor(s0, 2);
    gs += __shfl_xor(gs, 4); s0 += __shfl_xor(s0, 4);
    if (seg == 0) {
      atomicAdd(Gsum_g + b * 8 + n, gs);
      atomicAdd(S0_g + b * 8 + n, s0);
    }
  }
  if (cq == 0 && t < 8) {
    float acc = 0.f;
    for (int d = 0; d < 64; d++) acc += ldx(bkv, t * 64 + d, isf) * qrl[t * 64 + d];
    atomicAdd(S0_g + b * 8 + t, acc);
  }
}

// ---------------- kernel 4: fused m-GEMM + relu + LN-stats + MFMA-scores + R accumulation ----------------
// v8 (third resubmit; rounds 8-10 all failed with GPU-acquisition timeouts —
// the kernel has never run on hardware):
// ONE structural change vs v7: grid (16,32)->(64,32), ONE 64-row tile per block
// (tile loop deleted). The 4-tile loop phase-serialized burst->K->epilogue within a
// block; with only 2 resident blocks/CU (LDS-capped) there was no concurrent work to
// fill each phase's stalls. As 4 independent blocks, tile i's epilogue overlaps
// tile i+1's burst/K-loop via the CU scheduler. Also: ior prefetched at block start
// (was an HBM load on the B6->B7 critical path).
#define LDSWZ(row, byte_in_row) ((((row) << 10) + (byte_in_row)) ^ (((row) & 7) << 4))
__global__ __launch_bounds__(512) void k_main(
    const void* __restrict__ mem, const u16* __restrict__ WTf, const void* __restrict__ b_in,
    const void* __restrict__ ior, const u16* __restrict__ guT,
    const float* __restrict__ Gsum_g, const float* __restrict__ S0_g,
    float* __restrict__ R_g, float* __restrict__ A_g, float* __restrict__ M_g,
    const int* __restrict__ flag) {
  int isf = flag[0];
  int blk = blockIdx.x;           // 0..63: this block's single 64-row tile
  int b   = blockIdx.y;           // 0..31
  int t = threadIdx.x;
  int w = t >> 6, lane = t & 63;
  int l15 = lane & 15, q = lane >> 4;
  int row0 = blk * 64;

  // LDS map (68096 B):
  //   K-loop:   A_lds [0,65536) = [64 rows][512 k] bf16, XOR-swizzled rows
  //   epilogue (overlays A_lds): rowred [0,4096) (consumed before y), y slices
  //             (wave w at w*8192, [64][64] bf16 swizzled; T_part overlays first 2KB)
  //   persistent: mu_rstd [65536,66048), a_lds [66048,68096)
  __shared__ __align__(16) char smem[68096];
  float* rowred  = (float*)smem;
  float* mu_rstd = (float*)(smem + 65536);
  float* a_lds   = (float*)(smem + 66048);
  char*  ymine   = smem + w * 8192;

  float binv[4];
  #pragma unroll
  for (int j = 0; j < 4; j++) binv[j] = ldx(b_in, w * 64 + j * 16 + l15, isf);
  // gu B-fragments for the score MFMA
  bf16x8 gfrag0 = *(const bf16x8*)(guT + ((size_t)b * 16 + l15) * 512 + w * 64 + q * 8);
  bf16x8 gfrag1 = *(const bf16x8*)(guT + ((size_t)b * 16 + l15) * 512 + w * 64 + 32 + q * 8);
  float Gs  = Gsum_g[b * 8 + (t & 7)];
  float S0v = S0_g[b * 8 + (t & 7)];
  // ior prefetch for the a-phase (hidden under the A burst + K-loop)
  float iorv = ldx(ior, ((size_t)b * 8 + (t & 7)) * 4096 + row0 + (t >> 3), isf);
  // B fragment base: wave w owns jb = w*4..w*4+3; frag (j,ks) at wb + j*8192 + ks*512
  const u16* wb = WTf + (size_t)w * 32768 + l15 * 32 + q * 8;

  size_t memBase = ((size_t)b * 4096 + row0) * 512;

  // ---- A burst: 64x512 global -> swizzled bf16 LDS (coalesced; 2 batches f32) ----
  if (isf) {
    #pragma unroll
    for (int h = 0; h < 2; h++) {
      float4 va[8];
      #pragma unroll
      for (int p = 0; p < 8; p++) {
        int i16 = (h * 8 + p) * 512 + t;
        va[p] = *(const float4*)((const float*)mem + memBase + (size_t)i16 * 4);
      }
      #pragma unroll
      for (int p = 0; p < 8; p++) {
        int i16 = (h * 8 + p) * 512 + t;
        int row = i16 >> 7;
        union { u16 hh[4]; uint2 u; } pk;
        pk.hh[0] = f2b(va[p].x); pk.hh[1] = f2b(va[p].y);
        pk.hh[2] = f2b(va[p].z); pk.hh[3] = f2b(va[p].w);
        *(uint2*)(smem + LDSWZ(row, (i16 & 127) << 3)) = pk.u;
      }
    }
  } else {
    uint4 vb[8];
    #pragma unroll
    for (int p = 0; p < 8; p++) {
      int i16 = p * 512 + t;
      vb[p] = *(const uint4*)((const u16*)mem + memBase + (size_t)i16 * 8);
    }
    #pragma unroll
    for (int p = 0; p < 8; p++) {
      int i16 = p * 512 + t;
      int row = i16 >> 6;
      *(uint4*)(smem + LDSWZ(row, (i16 & 63) << 4)) = vb[p];
    }
  }
  __syncthreads();   // B1: A_lds ready

  f32x4 acc[4][4];
  #pragma unroll
  for (int i = 0; i < 4; i++)
    #pragma unroll
    for (int j = 0; j < 4; j++) { acc[i][j][0]=0.f; acc[i][j][1]=0.f; acc[i][j][2]=0.f; acc[i][j][3]=0.f; }

  // ---- barrier-free K-loop: A from swizzled LDS, B coalesced from WTf (L2) ----
  #pragma unroll 4
  for (int ks = 0; ks < 16; ks++) {
    bf16x8 aF[4], bF[4];
    #pragma unroll
    for (int j = 0; j < 4; j++)
      bF[j] = *(const bf16x8*)(wb + j * 8192 + ks * 512);
    #pragma unroll
    for (int i = 0; i < 4; i++) {
      int row = i * 16 + l15;
      aF[i] = *(const bf16x8*)(smem + LDSWZ(row, (ks << 6) + (q << 4)));
    }
    #pragma unroll
    for (int i = 0; i < 4; i++)
      #pragma unroll
      for (int j = 0; j < 4; j++)
        acc[i][j] = __builtin_amdgcn_mfma_f32_16x16x32_bf16(aF[i], bF[j], acc[i][j], 0, 0, 0);
  }
  __syncthreads();   // B2: all A_lds reads done; epilogue overlay allowed

  // bias + relu (acc stays PRE-LN y)
  #pragma unroll
  for (int i = 0; i < 4; i++)
    #pragma unroll
    for (int j = 0; j < 4; j++)
      #pragma unroll
      for (int r = 0; r < 4; r++) {
        float v = acc[i][j][r] + binv[j];
        acc[i][j][r] = v > 0.f ? v : 0.f;
      }
  // LN stats partials (per-wave 64-col slices)
  #pragma unroll
  for (int i = 0; i < 4; i++)
    #pragma unroll
    for (int r = 0; r < 4; r++) {
      float s  = acc[i][0][r] + acc[i][1][r] + acc[i][2][r] + acc[i][3][r];
      float ss = acc[i][0][r]*acc[i][0][r] + acc[i][1][r]*acc[i][1][r]
               + acc[i][2][r]*acc[i][2][r] + acc[i][3][r]*acc[i][3][r];
      #pragma unroll
      for (int m = 1; m < 16; m <<= 1) { s += __shfl_xor(s, m); ss += __shfl_xor(ss, m); }
      if (l15 == 0) {
        int row = i * 16 + q * 4 + r;
        rowred[(w * 64 + row) * 2]     = s;
        rowred[(w * 64 + row) * 2 + 1] = ss;
      }
    }
  __syncthreads();   // B3
  if (t < 64) {
    float S = 0.f, SS = 0.f;
    for (int w2 = 0; w2 < 8; w2++) { S += rowred[(w2 * 64 + t) * 2]; SS += rowred[(w2 * 64 + t) * 2 + 1]; }
    float mu = S / 512.f;
    float var = SS / 512.f - mu * mu;
    mu_rstd[t * 2] = mu;
    mu_rstd[t * 2 + 1] = rsqrtf(var + 1e-5f);
  }
  __syncthreads();   // B4: rowred consumed; y writes may overwrite [0,65536)

  // write this wave's y-slice [64][64] bf16, XOR-swizzled
  #pragma unroll
  for (int i = 0; i < 4; i++)
    #pragma unroll
    for (int j = 0; j < 4; j++)
      #pragma unroll
      for (int r = 0; r < 4; r++) {
        int row = i * 16 + q * 4 + r;
        int byo = (row * 128 + j * 32 + l15 * 2) ^ ((row & 7) << 4);
        *(u16*)(ymine + byo) = f2b(acc[i][j][r]);
      }
  __syncthreads();   // B5

  // scores: T_partial = y_slice @ gu  (8 MFMAs per wave, K = own 64 cols)
  f32x4 Tacc[4];
  #pragma unroll
  for (int rt = 0; rt < 4; rt++) { Tacc[rt][0]=0.f; Tacc[rt][1]=0.f; Tacc[rt][2]=0.f; Tacc[rt][3]=0.f; }
  #pragma unroll
  for (int rt = 0; rt < 4; rt++) {
    int row = rt * 16 + l15;
    int sw = (row & 7) << 4;
    bf16x8 ay0 = *(const bf16x8*)(ymine + ((row * 128 + q * 16) ^ sw));
    Tacc[rt] = __builtin_amdgcn_mfma_f32_16x16x32_bf16(ay0, gfrag0, Tacc[rt], 0, 0, 0);
    bf16x8 ay1 = *(const bf16x8*)(ymine + ((row * 128 + 64 + q * 16) ^ sw));
    Tacc[rt] = __builtin_amdgcn_mfma_f32_16x16x32_bf16(ay1, gfrag1, Tacc[rt], 0, 0, 0);
  }
  // T_part [64][8] f32 overlays own slice's first 2KB (own y already consumed)
  {
    float* tp = (float*)ymine;
    if (l15 < 8) {
      #pragma unroll
      for (int rt = 0; rt < 4; rt++)
        #pragma unroll
        for (int r = 0; r < 4; r++)
          tp[(rt * 16 + q * 4 + r) * 8 + l15] = Tacc[rt][r];
    }
  }
  __syncthreads();   // B6: T_parts visible

  // a-phase: combine wave partials, deferred-LN affine, *scale*ior; A/M partials
  float am_acc, mm_acc;
  {
    int row = t >> 3, n = t & 7;
    float Tsum = 0.f;
    #pragma unroll
    for (int w2 = 0; w2 < 8; w2++)
      Tsum += ((const float*)(smem + w2 * 8192))[row * 8 + n];
    float mu = mu_rstd[row * 2], rstd = mu_rstd[row * 2 + 1];
    float spre = rstd * (Tsum - mu * Gs) + S0v;
    float aval = spre * 0.125f * iorv;
    am_acc = aval;
    mm_acc = aval * mu * rstd;
    a_lds[row * 8 + n] = aval * rstd;   // a' = a*rstd for the R contraction
  }
  __syncthreads();   // B7: a_lds ready

  // R[n][col] contribution of this tile
  float rv[4][8];
  #pragma unroll
  for (int j = 0; j < 4; j++)
    #pragma unroll
    for (int n = 0; n < 8; n++) rv[j][n] = 0.f;
  #pragma unroll
  for (int i = 0; i < 4; i++)
    #pragma unroll
    for (int r = 0; r < 4; r++) {
      int row = i * 16 + q * 4 + r;
      const float* ap = a_lds + row * 8;
      float a0=ap[0],a1=ap[1],a2=ap[2],a3=ap[3],a4=ap[4],a5=ap[5],a6=ap[6],a7=ap[7];
      #pragma unroll
      for (int j = 0; j < 4; j++) {
        float m = acc[i][j][r];
        rv[j][0] += m*a0; rv[j][1] += m*a1; rv[j][2] += m*a2; rv[j][3] += m*a3;
        rv[j][4] += m*a4; rv[j][5] += m*a5; rv[j][6] += m*a6; rv[j][7] += m*a7;
      }
    }
  #pragma unroll
  for (int j = 0; j < 4; j++)
    #pragma unroll
    for (int n = 0; n < 8; n++) {
      float v = rv[j][n];
      v += __shfl_xor(v, 16);
      v += __shfl_xor(v, 32);
      rv[j][n] = v;
    }
  if (q == 0) {
    #pragma unroll
    for (int j = 0; j < 4; j++)
      #pragma unroll
      for (int n = 0; n < 8; n++)
        atomicAdd(R_g + ((size_t)b * 8 + n) * 512 + (w * 64 + j * 16 + l15), rv[j][n]);
  }

  // ---- A/M flush ----
  am_acc += __shfl_xor(am_acc, 8);
  am_acc += __shfl_xor(am_acc, 16);
  am_acc += __shfl_xor(am_acc, 32);
  mm_acc += __shfl_xor(mm_acc, 8);
  mm_acc += __shfl_xor(mm_acc, 16);
  mm_acc += __shfl_xor(mm_acc, 32);
  if (lane < 8) {
    atomicAdd(A_g + b * 8 + lane, am_acc);
    atomicAdd(M_g + b * 8 + lane, mm_acc);
  }
}

// ---------------- kernel 5: x = r@Wv + A*bv + query ; LN -> xln ; zero y_acc ----------------
__global__ __launch_bounds__(512) void k_mid(
    const float* __restrict__ R_g, const float* __restrict__ A_g, const float* __restrict__ M_g,
    const float* __restrict__ P1, const float* __restrict__ P2,
    const void* __restrict__ Wkv, const void* __restrict__ bkv, const void* __restrict__ g_in,
    const void* __restrict__ query, const void* __restrict__ g_f, const void* __restrict__ be_f,
    float* __restrict__ xrow_ws, float* __restrict__ xln_ws, float* __restrict__ y_acc,
    const int* __restrict__ flag) {
  int isf = flag[0];
  int b = blockIdx.x, t = threadIdx.x;
  __shared__ float Rl[4096];    // g[c]*R[b][n][c]
  __shared__ float red[16];
  __shared__ float stats[2];
  #pragma unroll
  for (int k = 0; k < 8; k++) {
    int e = t + 512 * k;
    Rl[e] = R_g[(size_t)b * 4096 + e] * ldx(g_in, e & 511, isf);
  }
  __syncthreads();
  int j = t, n = t >> 6;
  float Av = A_g[b * 8 + n], Mv = M_g[b * 8 + n];
  float base = Av * ldx(bkv, 512 + j, isf) - Mv * P1[j] + Av * P2[j];
  const float* rl = Rl + n * 512;
  float a0 = 0.f, a1 = 0.f, a2 = 0.f, a3 = 0.f;
  if (isf) {
    const float* wv = (const float*)Wkv + 512 + j;
    #pragma unroll 2
    for (int c = 0; c < 512; c += 4) {
      a0 += rl[c]     * wv[(size_t)c * 1024];
      a1 += rl[c + 1] * wv[(size_t)(c + 1) * 1024];
      a2 += rl[c + 2] * wv[(size_t)(c + 2) * 1024];
      a3 += rl[c + 3] * wv[(size_t)(c + 3) * 1024];
    }
  } else {
    const u16* wv = (const u16*)Wkv + 512 + j;
    #pragma unroll 2
    for (int c = 0; c < 512; c += 4) {
      a0 += rl[c]     * b2f(wv[(size_t)c * 1024]);
      a1 += rl[c + 1] * b2f(wv[(size_t)(c + 1) * 1024]);
      a2 += rl[c + 2] * b2f(wv[(size_t)(c + 2) * 1024]);
      a3 += rl[c + 3] * b2f(wv[(size_t)(c + 3) * 1024]);
    }
  }
  float v = base + (a0 + a1) + (a2 + a3) + ldx(query, (size_t)b * 512 + t, isf);
  xrow_ws[(size_t)b * 512 + t] = v;
  y_acc[(size_t)b * 512 + t] = 0.f;   // zero here (region was overlaid by guT earlier)
  float s1 = v, s2 = v * v;
  for (int off = 32; off; off >>= 1) { s1 += __shfl_xor(s1, off); s2 += __shfl_xor(s2, off); }
  int wid = t >> 6, lane = t & 63;
  if (lane == 0) { red[wid * 2] = s1; red[wid * 2 + 1] = s2; }
  __syncthreads();
  if (t == 0) {
    float S = 0.f, SS = 0.f;
    for (int w = 0; w < 8; w++) { S += red[w * 2]; SS += red[w * 2 + 1]; }
    float mu = S / 512.f;
    float var = SS / 512.f - mu * mu;
    stats[0] = mu; stats[1] = rsqrtf(var + 1e-5f);
  }
  __syncthreads();
  xln_ws[(size_t)b * 512 + t] = (v - stats[0]) * stats[1] * ldx(g_f, t, isf) + ldx(be_f, t, isf);
}

// ---------------- kernel 6: fused FFN: hdn = gelu(xln@W1+b1) in LDS; y_acc += hdn@W2 ----------------
__global__ __launch_bounds__(512) void k_ffn12(
    const float* __restrict__ xln_ws, const void* __restrict__ W1, const void* __restrict__ b1,
    const void* __restrict__ W2, float* __restrict__ y_acc, const int* __restrict__ flag) {
  int isf = flag[0];
  int jb = blockIdx.x, b = blockIdx.y, t = threadIdx.x;
  __shared__ float xl[512];
  __shared__ float hl[512];
  xl[t] = xln_ws[(size_t)b * 512 + t];
  __syncthreads();
  int j = jb * 512 + t;
  float a0 = 0.f, a1 = 0.f, a2 = 0.f, a3 = 0.f;
  if (isf) {
    const float* wp = (const float*)W1 + j;
    #pragma unroll 2
    for (int c = 0; c < 512; c += 4) {
      a0 += xl[c]     * wp[(size_t)c * 2048];
      a1 += xl[c + 1] * wp[(size_t)(c + 1) * 2048];
      a2 += xl[c + 2] * wp[(size_t)(c + 2) * 2048];
      a3 += xl[c + 3] * wp[(size_t)(c + 3) * 2048];
    }
  } else {
    const u16* wp = (const u16*)W1 + j;
    #pragma unroll 2
    for (int c = 0; c < 512; c += 4) {
      a0 += xl[c]     * b2f(wp[(size_t)c * 2048]);
      a1 += xl[c + 1] * b2f(wp[(size_t)(c + 1) * 2048]);
      a2 += xl[c + 2] * b2f(wp[(size_t)(c + 2) * 2048]);
      a3 += xl[c + 3] * b2f(wp[(size_t)(c + 3) * 2048]);
    }
  }
  float acc = (a0 + a1) + (a2 + a3) + ldx(b1, j, isf);
  hl[t] = 0.5f * acc * (1.0f + erff(acc * 0.70710678118654752f));
  __syncthreads();
  float s0 = 0.f, s1 = 0.f, s2 = 0.f, s3 = 0.f;
  if (isf) {
    const float* wp = (const float*)W2 + (size_t)jb * 512 * 512 + t;
    #pragma unroll 2
    for (int c = 0; c < 512; c += 4) {
      s0 += hl[c]     * wp[(size_t)c * 512];
      s1 += hl[c + 1] * wp[(size_t)(c + 1) * 512];
      s2 += hl[c + 2] * wp[(size_t)(c + 2) * 512];
      s3 += hl[c + 3] * wp[(size_t)(c + 3) * 512];
    }
  } else {
    const u16* wp = (const u16*)W2 + (size_t)jb * 512 * 512 + t;
    #pragma unroll 2
    for (int c = 0; c < 512; c += 4) {
      s0 += hl[c]     * b2f(wp[(size_t)c * 512]);
      s1 += hl[c + 1] * b2f(wp[(size_t)(c + 1) * 512]);
      s2 += hl[c + 2] * b2f(wp[(size_t)(c + 2) * 512]);
      s3 += hl[c + 3] * b2f(wp[(size_t)(c + 3) * 512]);
    }
  }
  atomicAdd(y_acc + (size_t)b * 512 + t, (s0 + s1) + (s2 + s3));
}

// ---------------- kernel 7: out = cast(y_acc + b2 + xrow) ----------------
__global__ __launch_bounds__(512) void k_final(
    const float* __restrict__ y_acc, const void* __restrict__ b2v,
    const float* __restrict__ xrow_ws, void* __restrict__ out,
    const int* __restrict__ flag) {
  int isf = flag[0];
  int b = blockIdx.x, t = threadIdx.x;
  float v = y_acc[(size_t)b * 512 + t] + ldx(b2v, t, isf) + xrow_ws[(size_t)b * 512 + t];
  if (isf) ((float*)out)[b * 512 + t] = v;
  else     ((u16*)out)[b * 512 + t] = f2b(v);
}

extern "C" void kernel_launch(void* const* d_in, const int* in_sizes, int n_in,
                              void* d_out, int out_size, void* d_ws, size_t ws_size,
                              hipStream_t stream) {
  const void* query = d_in[0];
  const void* mem   = d_in[1];
  const void* ior   = d_in[2];
  const void* W_in  = d_in[3];
  const void* b_in  = d_in[4];
  const void* g_in  = d_in[5];
  const void* be_in = d_in[6];
  const void* Wq    = d_in[7];
  const void* bq    = d_in[8];
  const void* Wkv   = d_in[9];
  const void* bkv   = d_in[10];
  const void* W1    = d_in[11];
  const void* b1    = d_in[12];
  const void* W2    = d_in[13];
  const void* b2v   = d_in[14];
  const void* g_q   = d_in[15];
  const void* be_q  = d_in[16];
  const void* g_f   = d_in[17];
  const void* be_f  = d_in[18];

  // ws layout (total 1,646,848 B). Region [528640,1052928) is time-shared:
  //   guT (k_qprep_b -> k_main) overlays {y_acc, xrow, xln} which are written only
  //   after k_main completes (y_acc zeroed inside k_mid).
  char* ws = (char*)d_ws;
  int*   flag   = (int*)ws;                      // [0,256)
  float* S0_g   = (float*)(ws + 256);            // 1024
  float* Gsum_g = (float*)(ws + 1280);           // 1024
  float* A_g    = (float*)(ws + 2304);           // 1024
  float* M_g    = (float*)(ws + 3328);           // 1024
  float* R_g    = (float*)(ws + 4352);           // 524288
  u16*   guT    = (u16*)(ws + 528640);           // 524288 (overlay)
  float* y_acc  = (float*)(ws + 528640);         // 65536
  float* xrow_ws= (float*)(ws + 594176);         // 65536
  float* xln_ws = (float*)(ws + 659712);         // 65536
  u16*   WTf    = (u16*)(ws + 1052928);          // 524288 (fragment-ordered B)
  float* P1     = (float*)(ws + 1577216);        // 2048
  float* P2     = (float*)(ws + 1579264);        // 2048
  float* qr_ws  = (float*)(ws + 1581312);        // 65536

  hipMemsetAsync(ws + 256, 0, 528384, stream);   // zero S0, Gsum, A, M, R
  k_detect<<<dim3(1), dim3(64), 0, stream>>>(query, flag);
  k_makeB<<<dim3(64), dim3(256), 0, stream>>>(W_in, WTf, flag);
  k_prep2<<<dim3(16), dim3(512), 0, stream>>>(Wkv, g_in, be_in, P1, P2, flag);
  k_qprep_a<<<dim3(32, 4), dim3(256), 0, stream>>>(query, Wq, bq, g_q, be_q, qr_ws, flag);
  k_qprep_b<<<dim3(32, 4), dim3(256), 0, stream>>>(qr_ws, Wkv, bkv, g_in, be_in,
                                                   guT, Gsum_g, S0_g, flag);
  k_main<<<dim3(64, 32), dim3(512), 0, stream>>>(mem, WTf, b_in, ior, guT, Gsum_g, S0_g,
                                                 R_g, A_g, M_g, flag);
  k_mid<<<dim3(32), dim3(512), 0, stream>>>(R_g, A_g, M_g, P1, P2, Wkv, bkv, g_in,
                                            query, g_f, be_f, xrow_ws, xln_ws, y_acc, flag);
  k_ffn12<<<dim3(4, 32), dim3(512), 0, stream>>>(xln_ws, W1, b1, W2, y_acc, flag);
  k_final<<<dim3(32), dim3(512), 0, stream>>>(y_acc, b2v, xrow_ws, d_out, flag);
}

// Round 12
// 696.746 us; speedup vs baseline: 1.3471x; 1.0388x over previous
//
#include <hip/hip_runtime.h>
#include <hip/hip_bf16.h>
#include <math.h>

typedef unsigned short u16;
typedef __bf16 bf16x8 __attribute__((ext_vector_type(8)));
typedef float f32x4 __attribute__((ext_vector_type(4)));

__device__ __forceinline__ float b2f(u16 u) {
  union { unsigned int i; float f; } v; v.i = ((unsigned int)u) << 16; return v.f;
}
__device__ __forceinline__ u16 f2b(float f) {
  union { float f; unsigned int i; } v; v.f = f;
  unsigned int x = v.i;
  return (u16)((x + 0x7fffu + ((x >> 16) & 1u)) >> 16);
}
// dual-dtype scalar load: isf=1 -> f32, isf=0 -> bf16
__device__ __forceinline__ float ldx(const void* p, size_t i, int isf) {
  return isf ? ((const float*)p)[i] : b2f(((const u16*)p)[i]);
}
// per-block dtype detect (replaces the k_detect launch): wave 0 probes query[0..63]
// as f32; garbage-range values => bf16. slot = any LDS float not yet in use.
__device__ __forceinline__ int detect_isf(const void* query, int t, volatile float* slot) {
  if (t < 64) {
    float v = ((const float*)query)[t];
    int ok = (v == v && fabsf(v) < 100.f && fabsf(v) > 1e-4f) ? 1 : 0;
    unsigned long long m = __ballot(ok);
    if (t == 0) *slot = (__popcll(m) >= 32) ? 1.f : 0.f;
  }
  __syncthreads();
  return *slot != 0.f;
}

// ---------------- kernel 1: fused prep (208 blocks x 256 thr) ----------------
// blk 0..63:   W_in -> WTf (MFMA-fragment order; round-6 verified body)
// blk 64..79:  P1/P2 = g/be . Wv   (256-thr variant of round-4 k_prep2)
// blk 80..207: qr = LN(query)@Wq + bq  (round-4 k_qprep_a body, b=(blk-80)>>2, jq=&3)
__global__ __launch_bounds__(256) void k_prep(
    const void* __restrict__ query, const void* __restrict__ Win, u16* __restrict__ WTf,
    const void* __restrict__ Wkv, const void* __restrict__ g_in, const void* __restrict__ be_in,
    float* __restrict__ P1, float* __restrict__ P2,
    const void* __restrict__ Wq, const void* __restrict__ bq,
    const void* __restrict__ g_q, const void* __restrict__ be_q,
    float* __restrict__ qr_ws) {
  __shared__ __align__(16) char pb[16704];
  float* slot = (float*)(pb + 16640);
  int t = threadIdx.x;
  int isf = detect_isf(query, t, slot);
  int blk = blockIdx.x;

  if (blk < 64) {
    // ---- makeB: WTf u16 idx ((jb*16+ks)*16+l)*32 + q*8 + r ----
    float (*tile)[65] = (float(*)[65])pb;
    int bx = blk & 7, by = blk >> 3;
    int k0 = bx * 64, j0 = by * 64;
    #pragma unroll
    for (int kx = 0; kx < 16; kx++) {
      int idx = t + 256 * kx;
      int kl = idx >> 6, jl = idx & 63;
      tile[kl][jl] = ldx(Win, (size_t)(k0 + kl) * 512 + (j0 + jl), isf);
    }
    __syncthreads();
    #pragma unroll
    for (int i = 0; i < 2; i++) {
      int chunk = i * 256 + t;
      int q  = chunk & 3;
      int l  = (chunk >> 2) & 15;
      int ksL = (chunk >> 6) & 1;
      int jbL = (chunk >> 7) & 3;
      int j_local = jbL * 16 + l;
      int k_local = ksL * 32 + q * 8;
      union { u16 h[8]; uint4 u; } pk;
      #pragma unroll
      for (int r = 0; r < 8; r++) pk.h[r] = f2b(tile[k_local + r][j_local]);
      int jb = by * 4 + jbL, ks = bx * 2 + ksL;
      *(uint4*)(WTf + ((size_t)(jb * 16 + ks) * 16 + l) * 32 + q * 8) = pk.u;
    }
  } else if (blk < 80) {
    // ---- prep2 (256 thr): 16 sub-blocks x 32 j; 8 c-groups of 64 ----
    float* red = (float*)pb;
    int blk2 = blk - 64;
    int jj = t & 31, cg = t >> 5;
    int j = blk2 * 32 + jj;
    float p1 = 0.f, p2 = 0.f;
    for (int cc = 0; cc < 64; cc++) {
      int c = cg * 64 + cc;
      float wv = ldx(Wkv, (size_t)c * 1024 + 512 + j, isf);
      p1 += ldx(g_in, c, isf) * wv;
      p2 += ldx(be_in, c, isf) * wv;
    }
    red[t * 2] = p1; red[t * 2 + 1] = p2;
    __syncthreads();
    if (t < 32) {
      float s1 = 0.f, s2 = 0.f;
      for (int g2 = 0; g2 < 8; g2++) { s1 += red[(g2 * 32 + t) * 2]; s2 += red[(g2 * 32 + t) * 2 + 1]; }
      P1[blk2 * 32 + t] = s1;
      P2[blk2 * 32 + t] = s2;
    }
  } else {
    // ---- qprep_a ----
    int bb = blk - 80;
    int b = bb >> 2, jq = bb & 3;
    float* qf    = (float*)pb;            // 512 f
    float* red   = (float*)(pb + 2048);   // 8 f
    float* stats = (float*)(pb + 2080);   // 2 f
    float s = 0.f, ss = 0.f;
    for (int k = 0; k < 2; k++) {
      int c = t + 256 * k;
      float v = ldx(query, (size_t)b * 512 + c, isf);
      qf[c] = v; s += v; ss += v * v;
    }
    for (int off = 32; off; off >>= 1) { s += __shfl_xor(s, off); ss += __shfl_xor(ss, off); }
    int wid = t >> 6, lane = t & 63;
    if (lane == 0) { red[wid * 2] = s; red[wid * 2 + 1] = ss; }
    __syncthreads();
    if (t == 0) {
      float S = 0.f, SS = 0.f;
      for (int w = 0; w < 4; w++) { S += red[w * 2]; SS += red[w * 2 + 1]; }
      float mu = S / 512.f;
      float var = SS / 512.f - mu * mu;
      stats[0] = mu; stats[1] = rsqrtf(var + 1e-5f);
    }
    __syncthreads();
    float mu = stats[0], rstd = stats[1];
    for (int k = 0; k < 2; k++) {
      int c = t + 256 * k;
      qf[c] = (qf[c] - mu) * rstd * ldx(g_q, c, isf) + ldx(be_q, c, isf);
    }
    __syncthreads();
    int jl = t >> 1, half = t & 1;
    int j = jq * 128 + jl;
    const float* qh = qf + half * 256;
    float a0 = 0.f, a1 = 0.f, a2 = 0.f, a3 = 0.f;
    if (isf) {
      const float* wp = (const float*)Wq + (size_t)(half * 256) * 512 + j;
      #pragma unroll 2
      for (int cc = 0; cc < 256; cc += 4) {
        a0 += qh[cc]     * wp[(size_t)cc * 512];
        a1 += qh[cc + 1] * wp[(size_t)(cc + 1) * 512];
        a2 += qh[cc + 2] * wp[(size_t)(cc + 2) * 512];
        a3 += qh[cc + 3] * wp[(size_t)(cc + 3) * 512];
      }
    } else {
      const u16* wp = (const u16*)Wq + (size_t)(half * 256) * 512 + j;
      #pragma unroll 2
      for (int cc = 0; cc < 256; cc += 4) {
        a0 += qh[cc]     * b2f(wp[(size_t)cc * 512]);
        a1 += qh[cc + 1] * b2f(wp[(size_t)(cc + 1) * 512]);
        a2 += qh[cc + 2] * b2f(wp[(size_t)(cc + 2) * 512]);
        a3 += qh[cc + 3] * b2f(wp[(size_t)(cc + 3) * 512]);
      }
    }
    float acc = (a0 + a1) + (a2 + a3);
    acc += __shfl_xor(acc, 1);
    if (half == 0) qr_ws[(size_t)b * 512 + j] = acc + ldx(bq, j, isf);
  }
}

// ---------------- kernel 2: u -> guT (bf16 [b][16][512]), Gsum, S0 (=BeU + c0) ----------------
__global__ __launch_bounds__(256) void k_qprep_b(
    const void* __restrict__ query,
    const float* __restrict__ qr_ws, const void* __restrict__ Wkv, const void* __restrict__ bkv,
    const void* __restrict__ g_in, const void* __restrict__ be_in,
    u16* __restrict__ guT, float* __restrict__ Gsum_g, float* __restrict__ S0_g) {
  __shared__ float qrl[512];
  __shared__ float ul[1024];
  __shared__ float slot[1];
  int t = threadIdx.x;
  int isf = detect_isf(query, t, slot);
  int b = blockIdx.x, cq = blockIdx.y;
  qrl[t] = qr_ws[(size_t)b * 512 + t];
  qrl[t + 256] = qr_ws[(size_t)b * 512 + t + 256];
  __syncthreads();
  #pragma unroll
  for (int e4 = 0; e4 < 4; e4++) {
    int e = t + 256 * e4;
    int cl = e >> 3, n = e & 7;
    int c = cq * 128 + cl;
    const float* qp = qrl + n * 64;
    float acc = 0.f;
    if (isf) {
      const float* wp = (const float*)Wkv + (size_t)c * 1024 + n * 64;
      #pragma unroll 8
      for (int d = 0; d < 64; d++) acc += wp[d] * qp[d];
    } else {
      const u16* wp = (const u16*)Wkv + (size_t)c * 1024 + n * 64;
      #pragma unroll 8
      for (int d = 0; d < 64; d++) acc += b2f(wp[d]) * qp[d];
    }
    ul[cl * 8 + n] = acc;
  }
  __syncthreads();
  #pragma unroll
  for (int e4 = 0; e4 < 4; e4++) {
    int e = t + 256 * e4;
    int cl = e >> 3, n = e & 7;
    int c = cq * 128 + cl;
    guT[((size_t)b * 16 + n) * 512 + c] = f2b(ldx(g_in, c, isf) * ul[cl * 8 + n]);
    guT[((size_t)b * 16 + 8 + n) * 512 + c] = 0;
  }
  if (t < 64) {
    int n = t >> 3, seg = t & 7;
    float gs = 0.f, s0 = 0.f;
    for (int k = 0; k < 16; k++) {
      int cl = seg * 16 + k;
      int c = cq * 128 + cl;
      float uu = ul[cl * 8 + n];
      gs += ldx(g_in, c, isf) * uu;
      s0 += ldx(be_in, c, isf) * uu;
    }
    gs += __shfl_xor(gs, 1); s0 += __shfl_xor(s0, 1);
    gs += __shfl_xor(gs, 2); s0 += __shfl_xor(s0, 2);
    gs += __shfl_xor(gs, 4); s0 += __shfl_xor(s0, 4);
    if (seg == 0) {
      atomicAdd(Gsum_g + b * 8 + n, gs);
      atomicAdd(S0_g + b * 8 + n, s0);
    }
  }
  if (cq == 0 && t < 8) {
    float acc = 0.f;
    for (int d = 0; d < 64; d++) acc += ldx(bkv, t * 64 + d, isf) * qrl[t * 64 + d];
    atomicAdd(S0_g + b * 8 + t, acc);
  }
}

// ---------------- kernel 3: fused m-GEMM + relu + LN-stats + MFMA-scores + R accumulation ----------------
// v8 body verified in round 11 (283-299 us, VGPR 76, no spill). Only change:
// inline dtype detect (k_detect launch removed), flag param dropped.
#define LDSWZ(row, byte_in_row) ((((row) << 10) + (byte_in_row)) ^ (((row) & 7) << 4))
__global__ __launch_bounds__(512) void k_main(
    const void* __restrict__ query,
    const void* __restrict__ mem, const u16* __restrict__ WTf, const void* __restrict__ b_in,
    const void* __restrict__ ior, const u16* __restrict__ guT,
    const float* __restrict__ Gsum_g, const float* __restrict__ S0_g,
    float* __restrict__ R_g, float* __restrict__ A_g, float* __restrict__ M_g) {
  int blk = blockIdx.x;           // 0..63: this block's single 64-row tile
  int b   = blockIdx.y;           // 0..31
  int t = threadIdx.x;
  int w = t >> 6, lane = t & 63;
  int l15 = lane & 15, q = lane >> 4;
  int row0 = blk * 64;

  // LDS map (68096 B):
  //   K-loop:   A_lds [0,65536) = [64 rows][512 k] bf16, XOR-swizzled rows
  //   epilogue (overlays A_lds): rowred [0,4096), y slices (wave w at w*8192,
  //             [64][64] bf16 swizzled; T_part overlays first 2KB)
  //   persistent: mu_rstd [65536,66048), a_lds [66048,68096)
  __shared__ __align__(16) char smem[68096];
  float* rowred  = (float*)smem;
  float* mu_rstd = (float*)(smem + 65536);
  float* a_lds   = (float*)(smem + 66048);
  char*  ymine   = smem + w * 8192;

  int isf = detect_isf(query, t, mu_rstd);   // slot overwritten later; isf in reg

  float binv[4];
  #pragma unroll
  for (int j = 0; j < 4; j++) binv[j] = ldx(b_in, w * 64 + j * 16 + l15, isf);
  // gu B-fragments for the score MFMA
  bf16x8 gfrag0 = *(const bf16x8*)(guT + ((size_t)b * 16 + l15) * 512 + w * 64 + q * 8);
  bf16x8 gfrag1 = *(const bf16x8*)(guT + ((size_t)b * 16 + l15) * 512 + w * 64 + 32 + q * 8);
  float Gs  = Gsum_g[b * 8 + (t & 7)];
  float S0v = S0_g[b * 8 + (t & 7)];
  // ior prefetch for the a-phase (hidden under the A burst + K-loop)
  float iorv = ldx(ior, ((size_t)b * 8 + (t & 7)) * 4096 + row0 + (t >> 3), isf);
  // B fragment base: wave w owns jb = w*4..w*4+3; frag (j,ks) at wb + j*8192 + ks*512
  const u16* wb = WTf + (size_t)w * 32768 + l15 * 32 + q * 8;

  size_t memBase = ((size_t)b * 4096 + row0) * 512;

  // ---- A burst: 64x512 global -> swizzled bf16 LDS (coalesced; 2 batches f32) ----
  if (isf) {
    #pragma unroll
    for (int h = 0; h < 2; h++) {
      float4 va[8];
      #pragma unroll
      for (int p = 0; p < 8; p++) {
        int i16 = (h * 8 + p) * 512 + t;
        va[p] = *(const float4*)((const float*)mem + memBase + (size_t)i16 * 4);
      }
      #pragma unroll
      for (int p = 0; p < 8; p++) {
        int i16 = (h * 8 + p) * 512 + t;
        int row = i16 >> 7;
        union { u16 hh[4]; uint2 u; } pk;
        pk.hh[0] = f2b(va[p].x); pk.hh[1] = f2b(va[p].y);
        pk.hh[2] = f2b(va[p].z); pk.hh[3] = f2b(va[p].w);
        *(uint2*)(smem + LDSWZ(row, (i16 & 127) << 3)) = pk.u;
      }
    }
  } else {
    uint4 vb[8];
    #pragma unroll
    for (int p = 0; p < 8; p++) {
      int i16 = p * 512 + t;
      vb[p] = *(const uint4*)((const u16*)mem + memBase + (size_t)i16 * 8);
    }
    #pragma unroll
    for (int p = 0; p < 8; p++) {
      int i16 = p * 512 + t;
      int row = i16 >> 6;
      *(uint4*)(smem + LDSWZ(row, (i16 & 63) << 4)) = vb[p];
    }
  }
  __syncthreads();   // B1: A_lds ready

  f32x4 acc[4][4];
  #pragma unroll
  for (int i = 0; i < 4; i++)
    #pragma unroll
    for (int j = 0; j < 4; j++) { acc[i][j][0]=0.f; acc[i][j][1]=0.f; acc[i][j][2]=0.f; acc[i][j][3]=0.f; }

  // ---- barrier-free K-loop: A from swizzled LDS, B coalesced from WTf (L2) ----
  #pragma unroll 4
  for (int ks = 0; ks < 16; ks++) {
    bf16x8 aF[4], bF[4];
    #pragma unroll
    for (int j = 0; j < 4; j++)
      bF[j] = *(const bf16x8*)(wb + j * 8192 + ks * 512);
    #pragma unroll
    for (int i = 0; i < 4; i++) {
      int row = i * 16 + l15;
      aF[i] = *(const bf16x8*)(smem + LDSWZ(row, (ks << 6) + (q << 4)));
    }
    #pragma unroll
    for (int i = 0; i < 4; i++)
      #pragma unroll
      for (int j = 0; j < 4; j++)
        acc[i][j] = __builtin_amdgcn_mfma_f32_16x16x32_bf16(aF[i], bF[j], acc[i][j], 0, 0, 0);
  }
  __syncthreads();   // B2: all A_lds reads done; epilogue overlay allowed

  // bias + relu (acc stays PRE-LN y)
  #pragma unroll
  for (int i = 0; i < 4; i++)
    #pragma unroll
    for (int j = 0; j < 4; j++)
      #pragma unroll
      for (int r = 0; r < 4; r++) {
        float v = acc[i][j][r] + binv[j];
        acc[i][j][r] = v > 0.f ? v : 0.f;
      }
  // LN stats partials (per-wave 64-col slices)
  #pragma unroll
  for (int i = 0; i < 4; i++)
    #pragma unroll
    for (int r = 0; r < 4; r++) {
      float s  = acc[i][0][r] + acc[i][1][r] + acc[i][2][r] + acc[i][3][r];
      float ss = acc[i][0][r]*acc[i][0][r] + acc[i][1][r]*acc[i][1][r]
               + acc[i][2][r]*acc[i][2][r] + acc[i][3][r]*acc[i][3][r];
      #pragma unroll
      for (int m = 1; m < 16; m <<= 1) { s += __shfl_xor(s, m); ss += __shfl_xor(ss, m); }
      if (l15 == 0) {
        int row = i * 16 + q * 4 + r;
        rowred[(w * 64 + row) * 2]     = s;
        rowred[(w * 64 + row) * 2 + 1] = ss;
      }
    }
  __syncthreads();   // B3
  if (t < 64) {
    float S = 0.f, SS = 0.f;
    for (int w2 = 0; w2 < 8; w2++) { S += rowred[(w2 * 64 + t) * 2]; SS += rowred[(w2 * 64 + t) * 2 + 1]; }
    float mu = S / 512.f;
    float var = SS / 512.f - mu * mu;
    mu_rstd[t * 2] = mu;
    mu_rstd[t * 2 + 1] = rsqrtf(var + 1e-5f);
  }
  __syncthreads();   // B4: rowred consumed; y writes may overwrite [0,65536)

  // write this wave's y-slice [64][64] bf16, XOR-swizzled
  #pragma unroll
  for (int i = 0; i < 4; i++)
    #pragma unroll
    for (int j = 0; j < 4; j++)
      #pragma unroll
      for (int r = 0; r < 4; r++) {
        int row = i * 16 + q * 4 + r;
        int byo = (row * 128 + j * 32 + l15 * 2) ^ ((row & 7) << 4);
        *(u16*)(ymine + byo) = f2b(acc[i][j][r]);
      }
  __syncthreads();   // B5

  // scores: T_partial = y_slice @ gu  (8 MFMAs per wave, K = own 64 cols)
  f32x4 Tacc[4];
  #pragma unroll
  for (int rt = 0; rt < 4; rt++) { Tacc[rt][0]=0.f; Tacc[rt][1]=0.f; Tacc[rt][2]=0.f; Tacc[rt][3]=0.f; }
  #pragma unroll
  for (int rt = 0; rt < 4; rt++) {
    int row = rt * 16 + l15;
    int sw = (row & 7) << 4;
    bf16x8 ay0 = *(const bf16x8*)(ymine + ((row * 128 + q * 16) ^ sw));
    Tacc[rt] = __builtin_amdgcn_mfma_f32_16x16x32_bf16(ay0, gfrag0, Tacc[rt], 0, 0, 0);
    bf16x8 ay1 = *(const bf16x8*)(ymine + ((row * 128 + 64 + q * 16) ^ sw));
    Tacc[rt] = __builtin_amdgcn_mfma_f32_16x16x32_bf16(ay1, gfrag1, Tacc[rt], 0, 0, 0);
  }
  // T_part [64][8] f32 overlays own slice's first 2KB (own y already consumed)
  {
    float* tp = (float*)ymine;
    if (l15 < 8) {
      #pragma unroll
      for (int rt = 0; rt < 4; rt++)
        #pragma unroll
        for (int r = 0; r < 4; r++)
          tp[(rt * 16 + q * 4 + r) * 8 + l15] = Tacc[rt][r];
    }
  }
  __syncthreads();   // B6: T_parts visible

  // a-phase: combine wave partials, deferred-LN affine, *scale*ior; A/M partials
  float am_acc, mm_acc;
  {
    int row = t >> 3, n = t & 7;
    float Tsum = 0.f;
    #pragma unroll
    for (int w2 = 0; w2 < 8; w2++)
      Tsum += ((const float*)(smem + w2 * 8192))[row * 8 + n];
    float mu = mu_rstd[row * 2], rstd = mu_rstd[row * 2 + 1];
    float spre = rstd * (Tsum - mu * Gs) + S0v;
    float aval = spre * 0.125f * iorv;
    am_acc = aval;
    mm_acc = aval * mu * rstd;
    a_lds[row * 8 + n] = aval * rstd;   // a' = a*rstd for the R contraction
  }
  __syncthreads();   // B7: a_lds ready

  // R[n][col] contribution of this tile
  float rv[4][8];
  #pragma unroll
  for (int j = 0; j < 4; j++)
    #pragma unroll
    for (int n = 0; n < 8; n++) rv[j][n] = 0.f;
  #pragma unroll
  for (int i = 0; i < 4; i++)
    #pragma unroll
    for (int r = 0; r < 4; r++) {
      int row = i * 16 + q * 4 + r;
      const float* ap = a_lds + row * 8;
      float a0=ap[0],a1=ap[1],a2=ap[2],a3=ap[3],a4=ap[4],a5=ap[5],a6=ap[6],a7=ap[7];
      #pragma unroll
      for (int j = 0; j < 4; j++) {
        float m = acc[i][j][r];
        rv[j][0] += m*a0; rv[j][1] += m*a1; rv[j][2] += m*a2; rv[j][3] += m*a3;
        rv[j][4] += m*a4; rv[j][5] += m*a5; rv[j][6] += m*a6; rv[j][7] += m*a7;
      }
    }
  #pragma unroll
  for (int j = 0; j < 4; j++)
    #pragma unroll
    for (int n = 0; n < 8; n++) {
      float v = rv[j][n];
      v += __shfl_xor(v, 16);
      v += __shfl_xor(v, 32);
      rv[j][n] = v;
    }
  if (q == 0) {
    #pragma unroll
    for (int j = 0; j < 4; j++)
      #pragma unroll
      for (int n = 0; n < 8; n++)
        atomicAdd(R_g + ((size_t)b * 8 + n) * 512 + (w * 64 + j * 16 + l15), rv[j][n]);
  }

  // ---- A/M flush ----
  am_acc += __shfl_xor(am_acc, 8);
  am_acc += __shfl_xor(am_acc, 16);
  am_acc += __shfl_xor(am_acc, 32);
  mm_acc += __shfl_xor(mm_acc, 8);
  mm_acc += __shfl_xor(mm_acc, 16);
  mm_acc += __shfl_xor(mm_acc, 32);
  if (lane < 8) {
    atomicAdd(A_g + b * 8 + lane, am_acc);
    atomicAdd(M_g + b * 8 + lane, mm_acc);
  }
}

// ---------------- kernel 4: fused mid+FFN: x = r@Wv + A*bv + query; LN; FFN1+FFN2 ----------------
// grid (4,32): block (jb,b). Each block recomputes x[b] (4x redundant but on 128
// blocks vs k_mid's 32), keeps xln in LDS (global roundtrip deleted), then its
// 512-col slice of gelu(x@W1+b1) and the matching K-slice of @W2 -> atomicAdd y_acc.
// y_acc is pre-zeroed by the launch-time memset (no longer overlays guT).
__global__ __launch_bounds__(512) void k_midffn(
    const void* __restrict__ query,
    const float* __restrict__ R_g, const float* __restrict__ A_g, const float* __restrict__ M_g,
    const float* __restrict__ P1, const float* __restrict__ P2,
    const void* __restrict__ Wkv, const void* __restrict__ bkv, const void* __restrict__ g_in,
    const void* __restrict__ g_f, const void* __restrict__ be_f,
    const void* __restrict__ W1, const void* __restrict__ b1, const void* __restrict__ W2,
    float* __restrict__ xrow_ws, float* __restrict__ y_acc) {
  __shared__ float Rl[4096];    // g[c]*R[b][n][c]
  __shared__ float xl[512];
  __shared__ float hl[512];
  __shared__ float red[16];
  __shared__ float stats[2];
  __shared__ float slot[1];
  int t = threadIdx.x;
  int isf = detect_isf(query, t, slot);
  int jb = blockIdx.x, b = blockIdx.y;

  #pragma unroll
  for (int k = 0; k < 8; k++) {
    int e = t + 512 * k;
    Rl[e] = R_g[(size_t)b * 4096 + e] * ldx(g_in, e & 511, isf);
  }
  __syncthreads();
  // x[t] = A*bv - M*P1 + A*P2 + sum_c rl[c]*Wv[c][t] + query
  int j = t, n = t >> 6;
  float Av = A_g[b * 8 + n], Mv = M_g[b * 8 + n];
  float base = Av * ldx(bkv, 512 + j, isf) - Mv * P1[j] + Av * P2[j];
  const float* rl = Rl + n * 512;
  float a0 = 0.f, a1 = 0.f, a2 = 0.f, a3 = 0.f;
  if (isf) {
    const float* wv = (const float*)Wkv + 512 + j;
    #pragma unroll 2
    for (int c = 0; c < 512; c += 4) {
      a0 += rl[c]     * wv[(size_t)c * 1024];
      a1 += rl[c + 1] * wv[(size_t)(c + 1) * 1024];
      a2 += rl[c + 2] * wv[(size_t)(c + 2) * 1024];
      a3 += rl[c + 3] * wv[(size_t)(c + 3) * 1024];
    }
  } else {
    const u16* wv = (const u16*)Wkv + 512 + j;
    #pragma unroll 2
    for (int c = 0; c < 512; c += 4) {
      a0 += rl[c]     * b2f(wv[(size_t)c * 1024]);
      a1 += rl[c + 1] * b2f(wv[(size_t)(c + 1) * 1024]);
      a2 += rl[c + 2] * b2f(wv[(size_t)(c + 2) * 1024]);
      a3 += rl[c + 3] * b2f(wv[(size_t)(c + 3) * 1024]);
    }
  }
  float v = base + (a0 + a1) + (a2 + a3) + ldx(query, (size_t)b * 512 + t, isf);
  if (jb == 0) xrow_ws[(size_t)b * 512 + t] = v;
  // LN
  float s1 = v, s2 = v * v;
  for (int off = 32; off; off >>= 1) { s1 += __shfl_xor(s1, off); s2 += __shfl_xor(s2, off); }
  int wid = t >> 6, lane = t & 63;
  if (lane == 0) { red[wid * 2] = s1; red[wid * 2 + 1] = s2; }
  __syncthreads();
  if (t == 0) {
    float S = 0.f, SS = 0.f;
    for (int w = 0; w < 8; w++) { S += red[w * 2]; SS += red[w * 2 + 1]; }
    float mu = S / 512.f;
    float var = SS / 512.f - mu * mu;
    stats[0] = mu; stats[1] = rsqrtf(var + 1e-5f);
  }
  __syncthreads();
  xl[t] = (v - stats[0]) * stats[1] * ldx(g_f, t, isf) + ldx(be_f, t, isf);
  __syncthreads();
  // FFN1: this block's 512 hdn cols
  int j2 = jb * 512 + t;
  float b0 = 0.f, b1a = 0.f, b2a = 0.f, b3a = 0.f;
  if (isf) {
    const float* wp = (const float*)W1 + j2;
    #pragma unroll 2
    for (int c = 0; c < 512; c += 4) {
      b0  += xl[c]     * wp[(size_t)c * 2048];
      b1a += xl[c + 1] * wp[(size_t)(c + 1) * 2048];
      b2a += xl[c + 2] * wp[(size_t)(c + 2) * 2048];
      b3a += xl[c + 3] * wp[(size_t)(c + 3) * 2048];
    }
  } else {
    const u16* wp = (const u16*)W1 + j2;
    #pragma unroll 2
    for (int c = 0; c < 512; c += 4) {
      b0  += xl[c]     * b2f(wp[(size_t)c * 2048]);
      b1a += xl[c + 1] * b2f(wp[(size_t)(c + 1) * 2048]);
      b2a += xl[c + 2] * b2f(wp[(size_t)(c + 2) * 2048]);
      b3a += xl[c + 3] * b2f(wp[(size_t)(c + 3) * 2048]);
    }
  }
  float hacc = (b0 + b1a) + (b2a + b3a) + ldx(b1, j2, isf);
  hl[t] = 0.5f * hacc * (1.0f + erff(hacc * 0.70710678118654752f));
  __syncthreads();
  // FFN2: K-slice [jb*512, jb*512+512) against all 512 outputs
  float s0 = 0.f, s1b = 0.f, s2b = 0.f, s3b = 0.f;
  if (isf) {
    const float* wp = (const float*)W2 + (size_t)jb * 512 * 512 + t;
    #pragma unroll 2
    for (int c = 0; c < 512; c += 4) {
      s0  += hl[c]     * wp[(size_t)c * 512];
      s1b += hl[c + 1] * wp[(size_t)(c + 1) * 512];
      s2b += hl[c + 2] * wp[(size_t)(c + 2) * 512];
      s3b += hl[c + 3] * wp[(size_t)(c + 3) * 512];
    }
  } else {
    const u16* wp = (const u16*)W2 + (size_t)jb * 512 * 512 + t;
    #pragma unroll 2
    for (int c = 0; c < 512; c += 4) {
      s0  += hl[c]     * b2f(wp[(size_t)c * 512]);
      s1b += hl[c + 1] * b2f(wp[(size_t)(c + 1) * 512]);
      s2b += hl[c + 2] * b2f(wp[(size_t)(c + 2) * 512]);
      s3b += hl[c + 3] * b2f(wp[(size_t)(c + 3) * 512]);
    }
  }
  atomicAdd(y_acc + (size_t)b * 512 + t, (s0 + s1b) + (s2b + s3b));
}

// ---------------- kernel 5: out = cast(y_acc + b2 + xrow) ----------------
__global__ __launch_bounds__(512) void k_final(
    const void* __restrict__ query,
    const float* __restrict__ y_acc, const void* __restrict__ b2v,
    const float* __restrict__ xrow_ws, void* __restrict__ out) {
  __shared__ float slot[1];
  int t = threadIdx.x;
  int isf = detect_isf(query, t, slot);
  int b = blockIdx.x;
  float v = y_acc[(size_t)b * 512 + t] + ldx(b2v, t, isf) + xrow_ws[(size_t)b * 512 + t];
  if (isf) ((float*)out)[b * 512 + t] = v;
  else     ((u16*)out)[b * 512 + t] = f2b(v);
}

extern "C" void kernel_launch(void* const* d_in, const int* in_sizes, int n_in,
                              void* d_out, int out_size, void* d_ws, size_t ws_size,
                              hipStream_t stream) {
  const void* query = d_in[0];
  const void* mem   = d_in[1];
  const void* ior   = d_in[2];
  const void* W_in  = d_in[3];
  const void* b_in  = d_in[4];
  const void* g_in  = d_in[5];
  const void* be_in = d_in[6];
  const void* Wq    = d_in[7];
  const void* bq    = d_in[8];
  const void* Wkv   = d_in[9];
  const void* bkv   = d_in[10];
  const void* W1    = d_in[11];
  const void* b1    = d_in[12];
  const void* W2    = d_in[13];
  const void* b2v   = d_in[14];
  const void* g_q   = d_in[15];
  const void* be_q  = d_in[16];
  const void* g_f   = d_in[17];
  const void* be_f  = d_in[18];

  // ws layout (total 1,777,664 B). No overlays: y_acc now lives in the memset
  // region (zeroed at launch), guT is standalone.
  char* ws = (char*)d_ws;
  float* S0_g   = (float*)(ws + 0);              // 1024
  float* Gsum_g = (float*)(ws + 1024);           // 1024
  float* A_g    = (float*)(ws + 2048);           // 1024
  float* M_g    = (float*)(ws + 3072);           // 1024
  float* R_g    = (float*)(ws + 4096);           // 524288
  float* y_acc  = (float*)(ws + 528384);         // 65536   [memset 0..593920)
  u16*   guT    = (u16*)(ws + 593920);           // 524288
  float* xrow_ws= (float*)(ws + 1118208);        // 65536
  u16*   WTf    = (u16*)(ws + 1183744);          // 524288 (fragment-ordered B)
  float* P1     = (float*)(ws + 1708032);        // 2048
  float* P2     = (float*)(ws + 1710080);        // 2048
  float* qr_ws  = (float*)(ws + 1712128);        // 65536

  hipMemsetAsync(ws, 0, 593920, stream);   // zero S0, Gsum, A, M, R, y_acc
  k_prep<<<dim3(208), dim3(256), 0, stream>>>(query, W_in, WTf, Wkv, g_in, be_in,
                                              P1, P2, Wq, bq, g_q, be_q, qr_ws);
  k_qprep_b<<<dim3(32, 4), dim3(256), 0, stream>>>(query, qr_ws, Wkv, bkv, g_in, be_in,
                                                   guT, Gsum_g, S0_g);
  k_main<<<dim3(64, 32), dim3(512), 0, stream>>>(query, mem, WTf, b_in, ior, guT,
                                                 Gsum_g, S0_g, R_g, A_g, M_g);
  k_midffn<<<dim3(4, 32), dim3(512), 0, stream>>>(query, R_g, A_g, M_g, P1, P2,
                                                  Wkv, bkv, g_in, g_f, be_f,
                                                  W1, b1, W2, xrow_ws, y_acc);
  k_final<<<dim3(32), dim3(512), 0, stream>>>(query, y_acc, b2v, xrow_ws, d_out);
}

// Round 14
// 658.697 us; speedup vs baseline: 1.4250x; 1.0578x over previous
//
#include <hip/hip_runtime.h>
#include <hip/hip_bf16.h>
#include <math.h>

typedef unsigned short u16;
typedef __bf16 bf16x8 __attribute__((ext_vector_type(8)));
typedef float f32x4 __attribute__((ext_vector_type(4)));

__device__ __forceinline__ float b2f(u16 u) {
  union { unsigned int i; float f; } v; v.i = ((unsigned int)u) << 16; return v.f;
}
__device__ __forceinline__ u16 f2b(float f) {
  union { float f; unsigned int i; } v; v.f = f;
  unsigned int x = v.i;
  return (u16)((x + 0x7fffu + ((x >> 16) & 1u)) >> 16);
}
// dual-dtype scalar load: isf=1 -> f32, isf=0 -> bf16
__device__ __forceinline__ float ldx(const void* p, size_t i, int isf) {
  return isf ? ((const float*)p)[i] : b2f(((const u16*)p)[i]);
}
// per-block dtype detect: wave 0 probes query[0..63] as f32; garbage => bf16.
__device__ __forceinline__ int detect_isf(const void* query, int t, volatile float* slot) {
  if (t < 64) {
    float v = ((const float*)query)[t];
    int ok = (v == v && fabsf(v) < 100.f && fabsf(v) > 1e-4f) ? 1 : 0;
    unsigned long long m = __ballot(ok);
    if (t == 0) *slot = (__popcll(m) >= 32) ? 1.f : 0.f;
  }
  __syncthreads();
  return *slot != 0.f;
}

// ---------------- kernel 1: fused prep (336 blocks x 256 thr) ----------------
// blk 0..63:   W_in -> WTf (MFMA-fragment order; round-6 verified body)
// blk 64..79:  P1/P2 = g/be . Wv
// blk 80..335: qr = LN(query)@Wq + bq  (widened: 8 j-slices of 64, 4 thr/j)
__global__ __launch_bounds__(256) void k_prep(
    const void* __restrict__ query, const void* __restrict__ Win, u16* __restrict__ WTf,
    const void* __restrict__ Wkv, const void* __restrict__ g_in, const void* __restrict__ be_in,
    float* __restrict__ P1, float* __restrict__ P2,
    const void* __restrict__ Wq, const void* __restrict__ bq,
    const void* __restrict__ g_q, const void* __restrict__ be_q,
    float* __restrict__ qr_ws) {
  __shared__ __align__(16) char pb[16704];
  float* slot = (float*)(pb + 16640);
  int t = threadIdx.x;
  int isf = detect_isf(query, t, slot);
  int blk = blockIdx.x;

  if (blk < 64) {
    // ---- makeB: WTf u16 idx ((jb*16+ks)*16+l)*32 + q*8 + r ----
    float (*tile)[65] = (float(*)[65])pb;
    int bx = blk & 7, by = blk >> 3;
    int k0 = bx * 64, j0 = by * 64;
    #pragma unroll
    for (int kx = 0; kx < 16; kx++) {
      int idx = t + 256 * kx;
      int kl = idx >> 6, jl = idx & 63;
      tile[kl][jl] = ldx(Win, (size_t)(k0 + kl) * 512 + (j0 + jl), isf);
    }
    __syncthreads();
    #pragma unroll
    for (int i = 0; i < 2; i++) {
      int chunk = i * 256 + t;
      int q  = chunk & 3;
      int l  = (chunk >> 2) & 15;
      int ksL = (chunk >> 6) & 1;
      int jbL = (chunk >> 7) & 3;
      int j_local = jbL * 16 + l;
      int k_local = ksL * 32 + q * 8;
      union { u16 h[8]; uint4 u; } pk;
      #pragma unroll
      for (int r = 0; r < 8; r++) pk.h[r] = f2b(tile[k_local + r][j_local]);
      int jb = by * 4 + jbL, ks = bx * 2 + ksL;
      *(uint4*)(WTf + ((size_t)(jb * 16 + ks) * 16 + l) * 32 + q * 8) = pk.u;
    }
  } else if (blk < 80) {
    // ---- prep2 (256 thr): 16 sub-blocks x 32 j; 8 c-groups of 64 ----
    float* red = (float*)pb;
    int blk2 = blk - 64;
    int jj = t & 31, cg = t >> 5;
    int j = blk2 * 32 + jj;
    float p1 = 0.f, p2 = 0.f;
    for (int cc = 0; cc < 64; cc++) {
      int c = cg * 64 + cc;
      float wv = ldx(Wkv, (size_t)c * 1024 + 512 + j, isf);
      p1 += ldx(g_in, c, isf) * wv;
      p2 += ldx(be_in, c, isf) * wv;
    }
    red[t * 2] = p1; red[t * 2 + 1] = p2;
    __syncthreads();
    if (t < 32) {
      float s1 = 0.f, s2 = 0.f;
      for (int g2 = 0; g2 < 8; g2++) { s1 += red[(g2 * 32 + t) * 2]; s2 += red[(g2 * 32 + t) * 2 + 1]; }
      P1[blk2 * 32 + t] = s1;
      P2[blk2 * 32 + t] = s2;
    }
  } else {
    // ---- qprep_a (widened): 256 blocks, b = bb>>3, jq = bb&7 (64 j each) ----
    int bb = blk - 80;
    int b = bb >> 3, jq = bb & 7;
    float* qf    = (float*)pb;            // 512 f
    float* red   = (float*)(pb + 2048);   // 8 f
    float* stats = (float*)(pb + 2080);   // 2 f
    float s = 0.f, ss = 0.f;
    for (int k = 0; k < 2; k++) {
      int c = t + 256 * k;
      float v = ldx(query, (size_t)b * 512 + c, isf);
      qf[c] = v; s += v; ss += v * v;
    }
    for (int off = 32; off; off >>= 1) { s += __shfl_xor(s, off); ss += __shfl_xor(ss, off); }
    int wid = t >> 6, lane = t & 63;
    if (lane == 0) { red[wid * 2] = s; red[wid * 2 + 1] = ss; }
    __syncthreads();
    if (t == 0) {
      float S = 0.f, SS = 0.f;
      for (int w = 0; w < 4; w++) { S += red[w * 2]; SS += red[w * 2 + 1]; }
      float mu = S / 512.f;
      float var = SS / 512.f - mu * mu;
      stats[0] = mu; stats[1] = rsqrtf(var + 1e-5f);
    }
    __syncthreads();
    float mu = stats[0], rstd = stats[1];
    for (int k = 0; k < 2; k++) {
      int c = t + 256 * k;
      qf[c] = (qf[c] - mu) * rstd * ldx(g_q, c, isf) + ldx(be_q, c, isf);
    }
    __syncthreads();
    int jl = t >> 2, quarter = t & 3;       // 64 j, 4 threads per j
    int j = jq * 64 + jl;
    const float* qh = qf + quarter * 128;
    float a0 = 0.f, a1 = 0.f, a2 = 0.f, a3 = 0.f;
    if (isf) {
      const float* wp = (const float*)Wq + (size_t)(quarter * 128) * 512 + j;
      #pragma unroll 2
      for (int cc = 0; cc < 128; cc += 4) {
        a0 += qh[cc]     * wp[(size_t)cc * 512];
        a1 += qh[cc + 1] * wp[(size_t)(cc + 1) * 512];
        a2 += qh[cc + 2] * wp[(size_t)(cc + 2) * 512];
        a3 += qh[cc + 3] * wp[(size_t)(cc + 3) * 512];
      }
    } else {
      const u16* wp = (const u16*)Wq + (size_t)(quarter * 128) * 512 + j;
      #pragma unroll 2
      for (int cc = 0; cc < 128; cc += 4) {
        a0 += qh[cc]     * b2f(wp[(size_t)cc * 512]);
        a1 += qh[cc + 1] * b2f(wp[(size_t)(cc + 1) * 512]);
        a2 += qh[cc + 2] * b2f(wp[(size_t)(cc + 2) * 512]);
        a3 += qh[cc + 3] * b2f(wp[(size_t)(cc + 3) * 512]);
      }
    }
    float acc = (a0 + a1) + (a2 + a3);
    acc += __shfl_xor(acc, 1);
    acc += __shfl_xor(acc, 2);
    if (quarter == 0) qr_ws[(size_t)b * 512 + j] = acc + ldx(bq, j, isf);
  }
}

// ---------------- kernel 2: u -> guT (bf16 [b][16][512]), Gsum, S0 (=BeU + c0) ----------------
__global__ __launch_bounds__(256) void k_qprep_b(
    const void* __restrict__ query,
    const float* __restrict__ qr_ws, const void* __restrict__ Wkv, const void* __restrict__ bkv,
    const void* __restrict__ g_in, const void* __restrict__ be_in,
    u16* __restrict__ guT, float* __restrict__ Gsum_g, float* __restrict__ S0_g) {
  __shared__ float qrl[512];
  __shared__ float ul[1024];
  __shared__ float slot[1];
  int t = threadIdx.x;
  int isf = detect_isf(query, t, slot);
  int b = blockIdx.x, cq = blockIdx.y;
  qrl[t] = qr_ws[(size_t)b * 512 + t];
  qrl[t + 256] = qr_ws[(size_t)b * 512 + t + 256];
  __syncthreads();
  #pragma unroll
  for (int e4 = 0; e4 < 4; e4++) {
    int e = t + 256 * e4;
    int cl = e >> 3, n = e & 7;
    int c = cq * 128 + cl;
    const float* qp = qrl + n * 64;
    float acc = 0.f;
    if (isf) {
      const float* wp = (const float*)Wkv + (size_t)c * 1024 + n * 64;
      #pragma unroll 8
      for (int d = 0; d < 64; d++) acc += wp[d] * qp[d];
    } else {
      const u16* wp = (const u16*)Wkv + (size_t)c * 1024 + n * 64;
      #pragma unroll 8
      for (int d = 0; d < 64; d++) acc += b2f(wp[d]) * qp[d];
    }
    ul[cl * 8 + n] = acc;
  }
  __syncthreads();
  #pragma unroll
  for (int e4 = 0; e4 < 4; e4++) {
    int e = t + 256 * e4;
    int cl = e >> 3, n = e & 7;
    int c = cq * 128 + cl;
    guT[((size_t)b * 16 + n) * 512 + c] = f2b(ldx(g_in, c, isf) * ul[cl * 8 + n]);
    guT[((size_t)b * 16 + 8 + n) * 512 + c] = 0;
  }
  if (t < 64) {
    int n = t >> 3, seg = t & 7;
    float gs = 0.f, s0 = 0.f;
    for (int k = 0; k < 16; k++) {
      int cl = seg * 16 + k;
      int c = cq * 128 + cl;
      float uu = ul[cl * 8 + n];
      gs += ldx(g_in, c, isf) * uu;
      s0 += ldx(be_in, c, isf) * uu;
    }
    gs += __shfl_xor(gs, 1); s0 += __shfl_xor(s0, 1);
    gs += __shfl_xor(gs, 2); s0 += __shfl_xor(s0, 2);
    gs += __shfl_xor(gs, 4); s0 += __shfl_xor(s0, 4);
    if (seg == 0) {
      atomicAdd(Gsum_g + b * 8 + n, gs);
      atomicAdd(S0_g + b * 8 + n, s0);
    }
  }
  if (cq == 0 && t < 8) {
    float acc = 0.f;
    for (int d = 0; d < 64; d++) acc += ldx(bkv, t * 64 + d, isf) * qrl[t * 64 + d];
    atomicAdd(S0_g + b * 8 + t, acc);
  }
}

// ---------------- kernel 3: fused m-GEMM + relu + LN-stats + MFMA-scores + R accumulation ----------------
// v8 body verified (273-282 us, VGPR 76, no spill). Unchanged.
#define LDSWZ(row, byte_in_row) ((((row) << 10) + (byte_in_row)) ^ (((row) & 7) << 4))
__global__ __launch_bounds__(512) void k_main(
    const void* __restrict__ query,
    const void* __restrict__ mem, const u16* __restrict__ WTf, const void* __restrict__ b_in,
    const void* __restrict__ ior, const u16* __restrict__ guT,
    const float* __restrict__ Gsum_g, const float* __restrict__ S0_g,
    float* __restrict__ R_g, float* __restrict__ A_g, float* __restrict__ M_g) {
  int blk = blockIdx.x;           // 0..63: this block's single 64-row tile
  int b   = blockIdx.y;           // 0..31
  int t = threadIdx.x;
  int w = t >> 6, lane = t & 63;
  int l15 = lane & 15, q = lane >> 4;
  int row0 = blk * 64;

  __shared__ __align__(16) char smem[68096];
  float* rowred  = (float*)smem;
  float* mu_rstd = (float*)(smem + 65536);
  float* a_lds   = (float*)(smem + 66048);
  char*  ymine   = smem + w * 8192;

  int isf = detect_isf(query, t, mu_rstd);   // slot overwritten later; isf in reg

  float binv[4];
  #pragma unroll
  for (int j = 0; j < 4; j++) binv[j] = ldx(b_in, w * 64 + j * 16 + l15, isf);
  bf16x8 gfrag0 = *(const bf16x8*)(guT + ((size_t)b * 16 + l15) * 512 + w * 64 + q * 8);
  bf16x8 gfrag1 = *(const bf16x8*)(guT + ((size_t)b * 16 + l15) * 512 + w * 64 + 32 + q * 8);
  float Gs  = Gsum_g[b * 8 + (t & 7)];
  float S0v = S0_g[b * 8 + (t & 7)];
  float iorv = ldx(ior, ((size_t)b * 8 + (t & 7)) * 4096 + row0 + (t >> 3), isf);
  const u16* wb = WTf + (size_t)w * 32768 + l15 * 32 + q * 8;

  size_t memBase = ((size_t)b * 4096 + row0) * 512;

  // ---- A burst: 64x512 global -> swizzled bf16 LDS ----
  if (isf) {
    #pragma unroll
    for (int h = 0; h < 2; h++) {
      float4 va[8];
      #pragma unroll
      for (int p = 0; p < 8; p++) {
        int i16 = (h * 8 + p) * 512 + t;
        va[p] = *(const float4*)((const float*)mem + memBase + (size_t)i16 * 4);
      }
      #pragma unroll
      for (int p = 0; p < 8; p++) {
        int i16 = (h * 8 + p) * 512 + t;
        int row = i16 >> 7;
        union { u16 hh[4]; uint2 u; } pk;
        pk.hh[0] = f2b(va[p].x); pk.hh[1] = f2b(va[p].y);
        pk.hh[2] = f2b(va[p].z); pk.hh[3] = f2b(va[p].w);
        *(uint2*)(smem + LDSWZ(row, (i16 & 127) << 3)) = pk.u;
      }
    }
  } else {
    uint4 vb[8];
    #pragma unroll
    for (int p = 0; p < 8; p++) {
      int i16 = p * 512 + t;
      vb[p] = *(const uint4*)((const u16*)mem + memBase + (size_t)i16 * 8);
    }
    #pragma unroll
    for (int p = 0; p < 8; p++) {
      int i16 = p * 512 + t;
      int row = i16 >> 6;
      *(uint4*)(smem + LDSWZ(row, (i16 & 63) << 4)) = vb[p];
    }
  }
  __syncthreads();   // B1: A_lds ready

  f32x4 acc[4][4];
  #pragma unroll
  for (int i = 0; i < 4; i++)
    #pragma unroll
    for (int j = 0; j < 4; j++) { acc[i][j][0]=0.f; acc[i][j][1]=0.f; acc[i][j][2]=0.f; acc[i][j][3]=0.f; }

  // ---- barrier-free K-loop ----
  #pragma unroll 4
  for (int ks = 0; ks < 16; ks++) {
    bf16x8 aF[4], bF[4];
    #pragma unroll
    for (int j = 0; j < 4; j++)
      bF[j] = *(const bf16x8*)(wb + j * 8192 + ks * 512);
    #pragma unroll
    for (int i = 0; i < 4; i++) {
      int row = i * 16 + l15;
      aF[i] = *(const bf16x8*)(smem + LDSWZ(row, (ks << 6) + (q << 4)));
    }
    #pragma unroll
    for (int i = 0; i < 4; i++)
      #pragma unroll
      for (int j = 0; j < 4; j++)
        acc[i][j] = __builtin_amdgcn_mfma_f32_16x16x32_bf16(aF[i], bF[j], acc[i][j], 0, 0, 0);
  }
  __syncthreads();   // B2

  // bias + relu
  #pragma unroll
  for (int i = 0; i < 4; i++)
    #pragma unroll
    for (int j = 0; j < 4; j++)
      #pragma unroll
      for (int r = 0; r < 4; r++) {
        float v = acc[i][j][r] + binv[j];
        acc[i][j][r] = v > 0.f ? v : 0.f;
      }
  // LN stats partials
  #pragma unroll
  for (int i = 0; i < 4; i++)
    #pragma unroll
    for (int r = 0; r < 4; r++) {
      float s  = acc[i][0][r] + acc[i][1][r] + acc[i][2][r] + acc[i][3][r];
      float ss = acc[i][0][r]*acc[i][0][r] + acc[i][1][r]*acc[i][1][r]
               + acc[i][2][r]*acc[i][2][r] + acc[i][3][r]*acc[i][3][r];
      #pragma unroll
      for (int m = 1; m < 16; m <<= 1) { s += __shfl_xor(s, m); ss += __shfl_xor(ss, m); }
      if (l15 == 0) {
        int row = i * 16 + q * 4 + r;
        rowred[(w * 64 + row) * 2]     = s;
        rowred[(w * 64 + row) * 2 + 1] = ss;
      }
    }
  __syncthreads();   // B3
  if (t < 64) {
    float S = 0.f, SS = 0.f;
    for (int w2 = 0; w2 < 8; w2++) { S += rowred[(w2 * 64 + t) * 2]; SS += rowred[(w2 * 64 + t) * 2 + 1]; }
    float mu = S / 512.f;
    float var = SS / 512.f - mu * mu;
    mu_rstd[t * 2] = mu;
    mu_rstd[t * 2 + 1] = rsqrtf(var + 1e-5f);
  }
  __syncthreads();   // B4

  // y-slice write (XOR-swizzled)
  #pragma unroll
  for (int i = 0; i < 4; i++)
    #pragma unroll
    for (int j = 0; j < 4; j++)
      #pragma unroll
      for (int r = 0; r < 4; r++) {
        int row = i * 16 + q * 4 + r;
        int byo = (row * 128 + j * 32 + l15 * 2) ^ ((row & 7) << 4);
        *(u16*)(ymine + byo) = f2b(acc[i][j][r]);
      }
  __syncthreads();   // B5

  // scores: T_partial = y_slice @ gu
  f32x4 Tacc[4];
  #pragma unroll
  for (int rt = 0; rt < 4; rt++) { Tacc[rt][0]=0.f; Tacc[rt][1]=0.f; Tacc[rt][2]=0.f; Tacc[rt][3]=0.f; }
  #pragma unroll
  for (int rt = 0; rt < 4; rt++) {
    int row = rt * 16 + l15;
    int sw = (row & 7) << 4;
    bf16x8 ay0 = *(const bf16x8*)(ymine + ((row * 128 + q * 16) ^ sw));
    Tacc[rt] = __builtin_amdgcn_mfma_f32_16x16x32_bf16(ay0, gfrag0, Tacc[rt], 0, 0, 0);
    bf16x8 ay1 = *(const bf16x8*)(ymine + ((row * 128 + 64 + q * 16) ^ sw));
    Tacc[rt] = __builtin_amdgcn_mfma_f32_16x16x32_bf16(ay1, gfrag1, Tacc[rt], 0, 0, 0);
  }
  {
    float* tp = (float*)ymine;
    if (l15 < 8) {
      #pragma unroll
      for (int rt = 0; rt < 4; rt++)
        #pragma unroll
        for (int r = 0; r < 4; r++)
          tp[(rt * 16 + q * 4 + r) * 8 + l15] = Tacc[rt][r];
    }
  }
  __syncthreads();   // B6

  // a-phase
  float am_acc, mm_acc;
  {
    int row = t >> 3, n = t & 7;
    float Tsum = 0.f;
    #pragma unroll
    for (int w2 = 0; w2 < 8; w2++)
      Tsum += ((const float*)(smem + w2 * 8192))[row * 8 + n];
    float mu = mu_rstd[row * 2], rstd = mu_rstd[row * 2 + 1];
    float spre = rstd * (Tsum - mu * Gs) + S0v;
    float aval = spre * 0.125f * iorv;
    am_acc = aval;
    mm_acc = aval * mu * rstd;
    a_lds[row * 8 + n] = aval * rstd;
  }
  __syncthreads();   // B7

  // R accumulation
  float rv[4][8];
  #pragma unroll
  for (int j = 0; j < 4; j++)
    #pragma unroll
    for (int n = 0; n < 8; n++) rv[j][n] = 0.f;
  #pragma unroll
  for (int i = 0; i < 4; i++)
    #pragma unroll
    for (int r = 0; r < 4; r++) {
      int row = i * 16 + q * 4 + r;
      const float* ap = a_lds + row * 8;
      float a0=ap[0],a1=ap[1],a2=ap[2],a3=ap[3],a4=ap[4],a5=ap[5],a6=ap[6],a7=ap[7];
      #pragma unroll
      for (int j = 0; j < 4; j++) {
        float m = acc[i][j][r];
        rv[j][0] += m*a0; rv[j][1] += m*a1; rv[j][2] += m*a2; rv[j][3] += m*a3;
        rv[j][4] += m*a4; rv[j][5] += m*a5; rv[j][6] += m*a6; rv[j][7] += m*a7;
      }
    }
  #pragma unroll
  for (int j = 0; j < 4; j++)
    #pragma unroll
    for (int n = 0; n < 8; n++) {
      float v = rv[j][n];
      v += __shfl_xor(v, 16);
      v += __shfl_xor(v, 32);
      rv[j][n] = v;
    }
  if (q == 0) {
    #pragma unroll
    for (int j = 0; j < 4; j++)
      #pragma unroll
      for (int n = 0; n < 8; n++)
        atomicAdd(R_g + ((size_t)b * 8 + n) * 512 + (w * 64 + j * 16 + l15), rv[j][n]);
  }

  // A/M flush
  am_acc += __shfl_xor(am_acc, 8);
  am_acc += __shfl_xor(am_acc, 16);
  am_acc += __shfl_xor(am_acc, 32);
  mm_acc += __shfl_xor(mm_acc, 8);
  mm_acc += __shfl_xor(mm_acc, 16);
  mm_acc += __shfl_xor(mm_acc, 32);
  if (lane < 8) {
    atomicAdd(A_g + b * 8 + lane, am_acc);
    atomicAdd(M_g + b * 8 + lane, mm_acc);
  }
}

// ---------------- kernel 4: fused mid+FFN (widened to grid (8,32)) ----------------
// Each block: recompute x[b] (8x redundant), LN in LDS, 256 hdn cols via 2 thr/col
// half-dots, FFN2 over its 256-K slice -> atomicAdd y_acc.
__global__ __launch_bounds__(512) void k_midffn(
    const void* __restrict__ query,
    const float* __restrict__ R_g, const float* __restrict__ A_g, const float* __restrict__ M_g,
    const float* __restrict__ P1, const float* __restrict__ P2,
    const void* __restrict__ Wkv, const void* __restrict__ bkv, const void* __restrict__ g_in,
    const void* __restrict__ g_f, const void* __restrict__ be_f,
    const void* __restrict__ W1, const void* __restrict__ b1, const void* __restrict__ W2,
    float* __restrict__ xrow_ws, float* __restrict__ y_acc) {
  __shared__ float Rl[4096];    // g[c]*R[b][n][c]
  __shared__ float xl[512];
  __shared__ float hl[256];
  __shared__ float red[16];
  __shared__ float stats[2];
  __shared__ float slot[1];
  int t = threadIdx.x;
  int isf = detect_isf(query, t, slot);
  int jb = blockIdx.x, b = blockIdx.y;   // jb: 0..7 (256 hdn cols each)

  #pragma unroll
  for (int k = 0; k < 8; k++) {
    int e = t + 512 * k;
    Rl[e] = R_g[(size_t)b * 4096 + e] * ldx(g_in, e & 511, isf);
  }
  __syncthreads();
  // x[t] = A*bv - M*P1 + A*P2 + sum_c rl[c]*Wv[c][t] + query
  int j = t, n = t >> 6;
  float Av = A_g[b * 8 + n], Mv = M_g[b * 8 + n];
  float base = Av * ldx(bkv, 512 + j, isf) - Mv * P1[j] + Av * P2[j];
  const float* rl = Rl + n * 512;
  float a0 = 0.f, a1 = 0.f, a2 = 0.f, a3 = 0.f;
  if (isf) {
    const float* wv = (const float*)Wkv + 512 + j;
    #pragma unroll 2
    for (int c = 0; c < 512; c += 4) {
      a0 += rl[c]     * wv[(size_t)c * 1024];
      a1 += rl[c + 1] * wv[(size_t)(c + 1) * 1024];
      a2 += rl[c + 2] * wv[(size_t)(c + 2) * 1024];
      a3 += rl[c + 3] * wv[(size_t)(c + 3) * 1024];
    }
  } else {
    const u16* wv = (const u16*)Wkv + 512 + j;
    #pragma unroll 2
    for (int c = 0; c < 512; c += 4) {
      a0 += rl[c]     * b2f(wv[(size_t)c * 1024]);
      a1 += rl[c + 1] * b2f(wv[(size_t)(c + 1) * 1024]);
      a2 += rl[c + 2] * b2f(wv[(size_t)(c + 2) * 1024]);
      a3 += rl[c + 3] * b2f(wv[(size_t)(c + 3) * 1024]);
    }
  }
  float v = base + (a0 + a1) + (a2 + a3) + ldx(query, (size_t)b * 512 + t, isf);
  if (jb == 0) xrow_ws[(size_t)b * 512 + t] = v;
  // LN
  float s1 = v, s2 = v * v;
  for (int off = 32; off; off >>= 1) { s1 += __shfl_xor(s1, off); s2 += __shfl_xor(s2, off); }
  int wid = t >> 6, lane = t & 63;
  if (lane == 0) { red[wid * 2] = s1; red[wid * 2 + 1] = s2; }
  __syncthreads();
  if (t == 0) {
    float S = 0.f, SS = 0.f;
    for (int w = 0; w < 8; w++) { S += red[w * 2]; SS += red[w * 2 + 1]; }
    float mu = S / 512.f;
    float var = SS / 512.f - mu * mu;
    stats[0] = mu; stats[1] = rsqrtf(var + 1e-5f);
  }
  __syncthreads();
  xl[t] = (v - stats[0]) * stats[1] * ldx(g_f, t, isf) + ldx(be_f, t, isf);
  __syncthreads();
  // FFN1: 256 cols, 2 threads/col (half-range dots), shfl-combine
  {
    int jl = t >> 1, half = t & 1;
    int j2 = jb * 256 + jl;
    const float* xh = xl + half * 256;
    float c0a = 0.f, c1a = 0.f, c2a = 0.f, c3a = 0.f;
    if (isf) {
      const float* wp = (const float*)W1 + (size_t)(half * 256) * 2048 + j2;
      #pragma unroll 2
      for (int c = 0; c < 256; c += 4) {
        c0a += xh[c]     * wp[(size_t)c * 2048];
        c1a += xh[c + 1] * wp[(size_t)(c + 1) * 2048];
        c2a += xh[c + 2] * wp[(size_t)(c + 2) * 2048];
        c3a += xh[c + 3] * wp[(size_t)(c + 3) * 2048];
      }
    } else {
      const u16* wp = (const u16*)W1 + (size_t)(half * 256) * 2048 + j2;
      #pragma unroll 2
      for (int c = 0; c < 256; c += 4) {
        c0a += xh[c]     * b2f(wp[(size_t)c * 2048]);
        c1a += xh[c + 1] * b2f(wp[(size_t)(c + 1) * 2048]);
        c2a += xh[c + 2] * b2f(wp[(size_t)(c + 2) * 2048]);
        c3a += xh[c + 3] * b2f(wp[(size_t)(c + 3) * 2048]);
      }
    }
    float hacc = (c0a + c1a) + (c2a + c3a);
    hacc += __shfl_xor(hacc, 1);
    if (half == 0) {
      hacc += ldx(b1, j2, isf);
      hl[jl] = 0.5f * hacc * (1.0f + erff(hacc * 0.70710678118654752f));
    }
  }
  __syncthreads();
  // FFN2: K-slice [jb*256, jb*256+256) against all 512 outputs
  float s0 = 0.f, s1b = 0.f, s2b = 0.f, s3b = 0.f;
  if (isf) {
    const float* wp = (const float*)W2 + (size_t)jb * 256 * 512 + t;
    #pragma unroll 2
    for (int c = 0; c < 256; c += 4) {
      s0  += hl[c]     * wp[(size_t)c * 512];
      s1b += hl[c + 1] * wp[(size_t)(c + 1) * 512];
      s2b += hl[c + 2] * wp[(size_t)(c + 2) * 512];
      s3b += hl[c + 3] * wp[(size_t)(c + 3) * 512];
    }
  } else {
    const u16* wp = (const u16*)W2 + (size_t)jb * 256 * 512 + t;
    #pragma unroll 2
    for (int c = 0; c < 256; c += 4) {
      s0  += hl[c]     * b2f(wp[(size_t)c * 512]);
      s1b += hl[c + 1] * b2f(wp[(size_t)(c + 1) * 512]);
      s2b += hl[c + 2] * b2f(wp[(size_t)(c + 2) * 512]);
      s3b += hl[c + 3] * b2f(wp[(size_t)(c + 3) * 512]);
    }
  }
  atomicAdd(y_acc + (size_t)b * 512 + t, (s0 + s1b) + (s2b + s3b));
}

// ---------------- kernel 5: out = cast(y_acc + b2 + xrow) ----------------
__global__ __launch_bounds__(512) void k_final(
    const void* __restrict__ query,
    const float* __restrict__ y_acc, const void* __restrict__ b2v,
    const float* __restrict__ xrow_ws, void* __restrict__ out) {
  __shared__ float slot[1];
  int t = threadIdx.x;
  int isf = detect_isf(query, t, slot);
  int b = blockIdx.x;
  float v = y_acc[(size_t)b * 512 + t] + ldx(b2v, t, isf) + xrow_ws[(size_t)b * 512 + t];
  if (isf) ((float*)out)[b * 512 + t] = v;
  else     ((u16*)out)[b * 512 + t] = f2b(v);
}

extern "C" void kernel_launch(void* const* d_in, const int* in_sizes, int n_in,
                              void* d_out, int out_size, void* d_ws, size_t ws_size,
                              hipStream_t stream) {
  const void* query = d_in[0];
  const void* mem   = d_in[1];
  const void* ior   = d_in[2];
  const void* W_in  = d_in[3];
  const void* b_in  = d_in[4];
  const void* g_in  = d_in[5];
  const void* be_in = d_in[6];
  const void* Wq    = d_in[7];
  const void* bq    = d_in[8];
  const void* Wkv   = d_in[9];
  const void* bkv   = d_in[10];
  const void* W1    = d_in[11];
  const void* b1    = d_in[12];
  const void* W2    = d_in[13];
  const void* b2v   = d_in[14];
  const void* g_q   = d_in[15];
  const void* be_q  = d_in[16];
  const void* g_f   = d_in[17];
  const void* be_f  = d_in[18];

  // ws layout (total 1,777,664 B). No overlays.
  char* ws = (char*)d_ws;
  float* S0_g   = (float*)(ws + 0);              // 1024
  float* Gsum_g = (float*)(ws + 1024);           // 1024
  float* A_g    = (float*)(ws + 2048);           // 1024
  float* M_g    = (float*)(ws + 3072);           // 1024
  float* R_g    = (float*)(ws + 4096);           // 524288
  float* y_acc  = (float*)(ws + 528384);         // 65536   [memset 0..593920)
  u16*   guT    = (u16*)(ws + 593920);           // 524288
  float* xrow_ws= (float*)(ws + 1118208);        // 65536
  u16*   WTf    = (u16*)(ws + 1183744);          // 524288 (fragment-ordered B)
  float* P1     = (float*)(ws + 1708032);        // 2048
  float* P2     = (float*)(ws + 1710080);        // 2048
  float* qr_ws  = (float*)(ws + 1712128);        // 65536

  hipMemsetAsync(ws, 0, 593920, stream);   // zero S0, Gsum, A, M, R, y_acc
  k_prep<<<dim3(336), dim3(256), 0, stream>>>(query, W_in, WTf, Wkv, g_in, be_in,
                                              P1, P2, Wq, bq, g_q, be_q, qr_ws);
  k_qprep_b<<<dim3(32, 4), dim3(256), 0, stream>>>(query, qr_ws, Wkv, bkv, g_in, be_in,
                                                   guT, Gsum_g, S0_g);
  k_main<<<dim3(64, 32), dim3(512), 0, stream>>>(query, mem, WTf, b_in, ior, guT,
                                                 Gsum_g, S0_g, R_g, A_g, M_g);
  k_midffn<<<dim3(8, 32), dim3(512), 0, stream>>>(query, R_g, A_g, M_g, P1, P2,
                                                  Wkv, bkv, g_in, g_f, be_f,
                                                  W1, b1, W2, xrow_ws, y_acc);
  k_final<<<dim3(32), dim3(512), 0, stream>>>(query, y_acc, b2v, xrow_ws, d_out);
}